// Round 2
// baseline (12852.591 us; speedup 1.0000x reference)
//
#include <hip/hip_runtime.h>
#include <cstddef>
#include <cstdint>

// ---------------------------------------------------------------------------
// HGT forward for MI355X. Sizes fixed per the reference:
//   C=128, H=8, D=16, OUT=64, L=2
//   NN = {30000, 60000, 6000}, NE = {200000, 300000, 200000, 100000}
//   ETS = {(0,1),(1,1),(1,2),(2,0)}
// Key algebraic move: fold a_rel/m_rel into the K/V projection weights so the
// per-edge einsum becomes a node-level GEMM:
//   ka[n,h,f] = sum_d k[n,h,d] a_rel[h,d,f]  ==  xs @ (kw @ a_rel) + (kb @ a_rel)
// NOTE: edge_num applies the softmax weight (alpha/den) per edge type, so
// `num` already holds the fully-normalized aggregate -> the node-update GEMM
// applies gelu ONLY (round-1 bug was a second, stale division by den).
// ---------------------------------------------------------------------------

__device__ __forceinline__ float gelu_tanh(float x) {
    // JAX default: approximate=True (tanh form)
    const float c = 0.7978845608028654f;
    float t = tanhf(c * (x + 0.044715f * x * x * x));
    return 0.5f * x * (1.0f + t);
}

// order-preserving float<->uint encoding for atomicMax on signed floats
__device__ __forceinline__ unsigned fenc(float f) {
    unsigned u = __float_as_uint(f);
    return (u & 0x80000000u) ? ~u : (u | 0x80000000u);
}
__device__ __forceinline__ float fdec(unsigned u) {
    return (u & 0x80000000u) ? __uint_as_float(u & 0x7fffffffu) : __uint_as_float(~u);
}

#define BM 64
#define BN 64
#define BK 16

// EPI: 0 = bias only, 1 = bias+relu, 2 = skip-combine (+relu). GIN: gelu on A-load.
template<int EPI, bool GIN>
__global__ __launch_bounds__(256) void gemm_k128(
    const float* __restrict__ A,
    const float* __restrict__ W, const float* __restrict__ bias,
    const float* __restrict__ xold, const float* __restrict__ skipp,
    float* __restrict__ out, int ldw, int ldo, int N)
{
    __shared__ float As[BK][BM + 4];  // +4 pad: keeps 16B alignment, breaks bank conflicts
    __shared__ float Bs[BK][BN + 4];
    const int tid = threadIdx.x;
    const int tx = tid & 15, ty = tid >> 4;
    const int rowBase = blockIdx.x * BM;
    const int colBase = blockIdx.y * BN;
    const int la_row = tid >> 2;         // 0..63
    const int la_k4  = (tid & 3) << 2;   // 0,4,8,12
    const int lb_k   = tid >> 4;         // 0..15
    const int lb_c   = (tid & 15) << 2;  // 0..60
    float acc[4][4] = {};
    for (int k0 = 0; k0 < 128; k0 += BK) {
        int gr = rowBase + la_row;
        float4 av = make_float4(0.f, 0.f, 0.f, 0.f);
        if (gr < N) {
            av = *(const float4*)(A + (size_t)gr * 128 + k0 + la_k4);
            if (GIN) {
                // num already softmax-normalized per edge type in edge_num;
                // apply gelu only.
                av.x = gelu_tanh(av.x);
                av.y = gelu_tanh(av.y);
                av.z = gelu_tanh(av.z);
                av.w = gelu_tanh(av.w);
            }
        }
        As[la_k4 + 0][la_row] = av.x;
        As[la_k4 + 1][la_row] = av.y;
        As[la_k4 + 2][la_row] = av.z;
        As[la_k4 + 3][la_row] = av.w;
        *(float4*)&Bs[lb_k][lb_c] =
            *(const float4*)(W + (size_t)(k0 + lb_k) * ldw + colBase + lb_c);
        __syncthreads();
        #pragma unroll
        for (int kk = 0; kk < BK; ++kk) {
            float4 a4 = *(const float4*)&As[kk][ty << 2];
            float4 b4 = *(const float4*)&Bs[kk][tx << 2];
            float ar[4] = {a4.x, a4.y, a4.z, a4.w};
            float br[4] = {b4.x, b4.y, b4.z, b4.w};
            #pragma unroll
            for (int i = 0; i < 4; ++i)
                #pragma unroll
                for (int j = 0; j < 4; ++j)
                    acc[i][j] = fmaf(ar[i], br[j], acc[i][j]);
        }
        __syncthreads();
    }
    float beta = 0.f, omb = 0.f;
    if (EPI == 2) { beta = 1.0f / (1.0f + __expf(-skipp[0])); omb = 1.0f - beta; }
    #pragma unroll
    for (int i = 0; i < 4; ++i) {
        int r = rowBase + (ty << 2) + i;
        if (r < N) {
            #pragma unroll
            for (int j = 0; j < 4; ++j) {
                int c = colBase + (tx << 2) + j;
                float o = acc[i][j] + bias[c];
                if (EPI == 1) o = fmaxf(o, 0.f);
                if (EPI == 2) { o = beta * o + omb * xold[(size_t)r * 128 + c]; o = fmaxf(o, 0.f); }
                out[(size_t)r * ldo + c] = o;
            }
        }
    }
}

// Fold relation matrices into projection weights:
//   Wka[c, h*16+f] = sum_d kw[c, h*16+d] * a_rel[h,d,f];  bka likewise from kb.
__global__ __launch_bounds__(128) void fold_rel(
    const float* __restrict__ kw, const float* __restrict__ kb,
    const float* __restrict__ vw, const float* __restrict__ vb,
    const float* __restrict__ arel, const float* __restrict__ mrel,
    float* __restrict__ Wka, float* __restrict__ bka,
    float* __restrict__ Wmv, float* __restrict__ bmv)
{
    int hf = threadIdx.x;          // 0..127
    int h = hf >> 4, f = hf & 15;
    int c = blockIdx.x;            // 0..127
    float sk = 0.f, sv = 0.f;
    #pragma unroll
    for (int d = 0; d < 16; ++d) {
        float ar = arel[(h * 16 + d) * 16 + f];
        float mr = mrel[(h * 16 + d) * 16 + f];
        sk = fmaf(kw[c * 128 + h * 16 + d], ar, sk);
        sv = fmaf(vw[c * 128 + h * 16 + d], mr, sv);
    }
    Wka[c * 128 + hf] = sk;
    Wmv[c * 128 + hf] = sv;
    if (c == 0) {
        float bk = 0.f, bv = 0.f;
        #pragma unroll
        for (int d = 0; d < 16; ++d) {
            bk = fmaf(kb[h * 16 + d], arel[(h * 16 + d) * 16 + f], bk);
            bv = fmaf(vb[h * 16 + d], mrel[(h * 16 + d) * 16 + f], bv);
        }
        bka[hf] = bk;
        bmv[hf] = bv;
    }
}

// Pass 1: alpha[e,h] = (q[dst,h,:] . ka[src,h,:]) * p_rel[h] * 0.25; segment max via atomicMax
__global__ __launch_bounds__(256) void edge_alpha(
    const int* __restrict__ src, const int* __restrict__ dst,
    const float* __restrict__ ka, const float* __restrict__ q,
    const float* __restrict__ prel, float* __restrict__ alpha,
    unsigned* __restrict__ amax, int E, int dstOff)
{
    int idx = blockIdx.x * 256 + threadIdx.x;
    if (idx >= E * 8) return;
    int e = idx >> 3, h = idx & 7;
    int s = src[e], d = dst[e];
    const float4* kr = (const float4*)(ka + (size_t)s * 128 + h * 16);
    const float4* qr = (const float4*)(q + ((size_t)(dstOff + d)) * 128 + h * 16);
    float acc = 0.f;
    #pragma unroll
    for (int j = 0; j < 4; ++j) {
        float4 a = kr[j], b = qr[j];
        acc += a.x * b.x + a.y * b.y + a.z * b.z + a.w * b.w;
    }
    float al = acc * prel[h] * 0.25f;   // scale = 1/sqrt(D) = 0.25
    alpha[idx] = al;
    atomicMax(&amax[(size_t)(dstOff + d) * 8 + h], fenc(al));
}

// Pass 2: ex = exp(alpha - amax); den += ex  (ex overwrites alpha)
__global__ __launch_bounds__(256) void edge_den(
    const int* __restrict__ dst, float* __restrict__ alpha,
    const unsigned* __restrict__ amax, float* __restrict__ den,
    int E, int dstOff)
{
    int idx = blockIdx.x * 256 + threadIdx.x;
    if (idx >= E * 8) return;
    int e = idx >> 3, h = idx & 7;
    int d = dst[e];
    float m = fdec(amax[(size_t)(dstOff + d) * 8 + h]);
    float ex = __expf(alpha[idx] - m);
    alpha[idx] = ex;
    __hip_atomic_fetch_add(&den[(size_t)(dstOff + d) * 8 + h], ex,
                           __ATOMIC_RELAXED, __HIP_MEMORY_SCOPE_AGENT);
}

// Pass 3: num[dst,h,:] += (ex / (den+1e-16)) * mv[src,h,:]
__global__ __launch_bounds__(256) void edge_num(
    const int* __restrict__ src, const int* __restrict__ dst,
    const float* __restrict__ mv, const float* __restrict__ alpha,
    const float* __restrict__ den, float* __restrict__ num,
    int E, int dstOff)
{
    int idx = blockIdx.x * 256 + threadIdx.x;
    if (idx >= E * 8) return;
    int e = idx >> 3, h = idx & 7;
    int s = src[e], d = dst[e];
    float w = alpha[idx] / (den[(size_t)(dstOff + d) * 8 + h] + 1e-16f);
    const float4* mr = (const float4*)(mv + (size_t)s * 128 + h * 16);
    float* np = num + (size_t)(dstOff + d) * 128 + h * 16;
    #pragma unroll
    for (int j = 0; j < 4; ++j) {
        float4 v = mr[j];
        __hip_atomic_fetch_add(np + 4 * j + 0, w * v.x, __ATOMIC_RELAXED, __HIP_MEMORY_SCOPE_AGENT);
        __hip_atomic_fetch_add(np + 4 * j + 1, w * v.y, __ATOMIC_RELAXED, __HIP_MEMORY_SCOPE_AGENT);
        __hip_atomic_fetch_add(np + 4 * j + 2, w * v.z, __ATOMIC_RELAXED, __HIP_MEMORY_SCOPE_AGENT);
        __hip_atomic_fetch_add(np + 4 * j + 3, w * v.w, __ATOMIC_RELAXED, __HIP_MEMORY_SCOPE_AGENT);
    }
}

extern "C" void kernel_launch(void* const* d_in, const int* in_sizes, int n_in,
                              void* d_out, int out_size, void* d_ws, size_t ws_size,
                              hipStream_t stream)
{
    (void)in_sizes; (void)n_in; (void)out_size; (void)ws_size;

    const float* xin[3] = {(const float*)d_in[0], (const float*)d_in[1], (const float*)d_in[2]};
    const int* esrc[4] = {(const int*)d_in[3], (const int*)d_in[5], (const int*)d_in[7], (const int*)d_in[9]};
    const int* edst[4] = {(const int*)d_in[4], (const int*)d_in[6], (const int*)d_in[8], (const int*)d_in[10]};
    const float* lin_w = (const float*)d_in[11];
    const float* lin_b = (const float*)d_in[12];
    const float* kw = (const float*)d_in[13];
    const float* qw = (const float*)d_in[14];
    const float* vw = (const float*)d_in[15];
    const float* aw = (const float*)d_in[16];
    const float* kb = (const float*)d_in[17];
    const float* qb = (const float*)d_in[18];
    const float* vb = (const float*)d_in[19];
    const float* ab = (const float*)d_in[20];
    const float* a_rel = (const float*)d_in[21];
    const float* m_rel = (const float*)d_in[22];
    const float* p_rel = (const float*)d_in[23];
    const float* skip  = (const float*)d_in[24];
    const float* out_w = (const float*)d_in[25];
    const float* out_b = (const float*)d_in[26];

    // workspace layout (floats); total ~56.2M floats = ~225 MB
    float* ws = (float*)d_ws;
    float*    xs    = ws;                       // 96000*128
    float*    q     = ws + 12288000;            // 96000*128
    float*    num   = ws + 24576000;            // 96000*128
    float*    den   = ws + 36864000;            // 96000*8
    unsigned* amax  = (unsigned*)(ws + 37632000); // 96000*8
    float*    ka    = ws + 38400000;            // 60000*128 (max src count)
    float*    mv    = ws + 46080000;            // 60000*128
    float*    alpha = ws + 53760000;            // 300000*8 (max E)
    float*    Wka   = ws + 56160000;            // 128*128
    float*    Wmv   = Wka + 16384;
    float*    bka   = Wmv + 16384;
    float*    bmv   = bka + 128;

    const int NNv[3] = {30000, 60000, 6000};
    const int OFF[3] = {0, 30000, 90000};
    const int NEv[4] = {200000, 300000, 200000, 100000};
    const int SI[4] = {0, 1, 1, 2};
    const int DI[4] = {1, 1, 2, 0};
    const size_t OUTOFF[3] = {0, (size_t)30000 * 64, (size_t)90000 * 64};

    dim3 blk(256);

    // input linear + relu -> xs
    for (int i = 0; i < 3; ++i) {
        dim3 g((NNv[i] + BM - 1) / BM, 2);
        gemm_k128<1, false><<<g, blk, 0, stream>>>(
            xin[i], lin_w + (size_t)i * 16384, lin_b + i * 128,
            nullptr, nullptr, xs + (size_t)OFF[i] * 128, 128, 128, NNv[i]);
    }

    for (int l = 0; l < 2; ++l) {
        // zero agg numerator for this layer
        hipMemsetAsync(num, 0, (size_t)12288000 * 4, stream);

        // Q projection per node type
        for (int i = 0; i < 3; ++i) {
            dim3 g((NNv[i] + BM - 1) / BM, 2);
            gemm_k128<0, false><<<g, blk, 0, stream>>>(
                xs + (size_t)OFF[i] * 128,
                qw + (size_t)(l * 3 + i) * 16384, qb + (l * 3 + i) * 128,
                nullptr, nullptr, q + (size_t)OFF[i] * 128, 128, 128, NNv[i]);
        }

        for (int et = 0; et < 4; ++et) {
            int si = SI[et], di = DI[et], E = NEv[et];
            // per-edge-type softmax state reset (softmax is per edge type!)
            hipMemsetAsync(den  + (size_t)OFF[di] * 8, 0, (size_t)NNv[di] * 8 * 4, stream);
            hipMemsetAsync(amax + (size_t)OFF[di] * 8, 0, (size_t)NNv[di] * 8 * 4, stream);

            fold_rel<<<dim3(128), dim3(128), 0, stream>>>(
                kw + (size_t)(l * 3 + si) * 16384, kb + (l * 3 + si) * 128,
                vw + (size_t)(l * 3 + si) * 16384, vb + (l * 3 + si) * 128,
                a_rel + (size_t)(l * 4 + et) * 2048, m_rel + (size_t)(l * 4 + et) * 2048,
                Wka, bka, Wmv, bmv);

            dim3 gs((NNv[si] + BM - 1) / BM, 2);
            gemm_k128<0, false><<<gs, blk, 0, stream>>>(
                xs + (size_t)OFF[si] * 128, Wka, bka,
                nullptr, nullptr, ka, 128, 128, NNv[si]);
            gemm_k128<0, false><<<gs, blk, 0, stream>>>(
                xs + (size_t)OFF[si] * 128, Wmv, bmv,
                nullptr, nullptr, mv, 128, 128, NNv[si]);

            int nthr = E * 8;
            dim3 ge((nthr + 255) / 256);
            edge_alpha<<<ge, blk, 0, stream>>>(esrc[et], edst[et], ka, q,
                                               p_rel + (size_t)(l * 4 + et) * 8,
                                               alpha, amax, E, OFF[di]);
            edge_den<<<ge, blk, 0, stream>>>(edst[et], alpha, amax, den, E, OFF[di]);
            edge_num<<<ge, blk, 0, stream>>>(esrc[et], edst[et], mv, alpha, den, num, E, OFF[di]);
        }

        // node update: xs = relu(beta * (gelu(num) @ aw + ab) + (1-beta) * xs)
        for (int i = 0; i < 3; ++i) {
            dim3 g((NNv[i] + BM - 1) / BM, 2);
            gemm_k128<2, true><<<g, blk, 0, stream>>>(
                num + (size_t)OFF[i] * 128,
                aw + (size_t)(l * 3 + i) * 16384, ab + (l * 3 + i) * 128,
                xs + (size_t)OFF[i] * 128, skip + (l * 3 + i),
                xs + (size_t)OFF[i] * 128, 128, 128, NNv[i]);
        }
    }

    // output projection (C=128 -> OUT=64), concatenated outputs
    float* out = (float*)d_out;
    for (int i = 0; i < 3; ++i) {
        dim3 g((NNv[i] + BM - 1) / BM, 1);
        gemm_k128<0, false><<<g, blk, 0, stream>>>(
            xs + (size_t)OFF[i] * 128, out_w, out_b,
            nullptr, nullptr, out + OUTOFF[i], 64, 64, NNv[i]);
    }
}

// Round 3
// 1633.691 us; speedup vs baseline: 7.8672x; 7.8672x over previous
//
#include <hip/hip_runtime.h>
#include <cstddef>
#include <cstdint>

// ---------------------------------------------------------------------------
// HGT forward for MI355X. C=128, H=8, D=16, OUT=64, L=2
//   NN = {30000, 60000, 6000}, NE = {200000, 300000, 200000, 100000}
//   ETS = {(0,1),(1,1),(1,2),(2,0)}
// Round-2 changes:
//  * Build dst-sorted CSR per edge type ONCE per launch (edges are static),
//    reuse across both layers.
//  * Replace the 3 scatter-atomic edge kernels with one gather-side fused
//    online-softmax aggregation kernel: thread = (dst node, head), flash-style
//    running (max, sum, O[16]) over the neighbor list, single non-atomic
//    num += write. Removes ~1.2 GB of atomic writes per dispatch.
//  * ka/mv projections fused into one 128x256 folded-weight GEMM.
// ---------------------------------------------------------------------------

__device__ __forceinline__ float gelu_tanh(float x) {
    const float c = 0.7978845608028654f;
    float t = tanhf(c * (x + 0.044715f * x * x * x));
    return 0.5f * x * (1.0f + t);
}

#define BM 64
#define BN 64
#define BK 16

// EPI: 0 = bias only, 1 = bias+relu, 2 = skip-combine (+relu). GIN: gelu on A-load.
template<int EPI, bool GIN>
__global__ __launch_bounds__(256) void gemm_k128(
    const float* __restrict__ A,
    const float* __restrict__ W, const float* __restrict__ bias,
    const float* __restrict__ xold, const float* __restrict__ skipp,
    float* __restrict__ out, int ldw, int ldo, int N)
{
    __shared__ float As[BK][BM + 4];
    __shared__ float Bs[BK][BN + 4];
    const int tid = threadIdx.x;
    const int tx = tid & 15, ty = tid >> 4;
    const int rowBase = blockIdx.x * BM;
    const int colBase = blockIdx.y * BN;
    const int la_row = tid >> 2;         // 0..63
    const int la_k4  = (tid & 3) << 2;   // 0,4,8,12
    const int lb_k   = tid >> 4;         // 0..15
    const int lb_c   = (tid & 15) << 2;  // 0..60
    float acc[4][4] = {};
    for (int k0 = 0; k0 < 128; k0 += BK) {
        int gr = rowBase + la_row;
        float4 av = make_float4(0.f, 0.f, 0.f, 0.f);
        if (gr < N) {
            av = *(const float4*)(A + (size_t)gr * 128 + k0 + la_k4);
            if (GIN) {
                av.x = gelu_tanh(av.x);
                av.y = gelu_tanh(av.y);
                av.z = gelu_tanh(av.z);
                av.w = gelu_tanh(av.w);
            }
        }
        As[la_k4 + 0][la_row] = av.x;
        As[la_k4 + 1][la_row] = av.y;
        As[la_k4 + 2][la_row] = av.z;
        As[la_k4 + 3][la_row] = av.w;
        *(float4*)&Bs[lb_k][lb_c] =
            *(const float4*)(W + (size_t)(k0 + lb_k) * ldw + colBase + lb_c);
        __syncthreads();
        #pragma unroll
        for (int kk = 0; kk < BK; ++kk) {
            float4 a4 = *(const float4*)&As[kk][ty << 2];
            float4 b4 = *(const float4*)&Bs[kk][tx << 2];
            float ar[4] = {a4.x, a4.y, a4.z, a4.w};
            float br[4] = {b4.x, b4.y, b4.z, b4.w};
            #pragma unroll
            for (int i = 0; i < 4; ++i)
                #pragma unroll
                for (int j = 0; j < 4; ++j)
                    acc[i][j] = fmaf(ar[i], br[j], acc[i][j]);
        }
        __syncthreads();
    }
    float beta = 0.f, omb = 0.f;
    if (EPI == 2) { beta = 1.0f / (1.0f + __expf(-skipp[0])); omb = 1.0f - beta; }
    #pragma unroll
    for (int i = 0; i < 4; ++i) {
        int r = rowBase + (ty << 2) + i;
        if (r < N) {
            #pragma unroll
            for (int j = 0; j < 4; ++j) {
                int c = colBase + (tx << 2) + j;
                float o = acc[i][j] + bias[c];
                if (EPI == 1) o = fmaxf(o, 0.f);
                if (EPI == 2) { o = beta * o + omb * xold[(size_t)r * 128 + c]; o = fmaxf(o, 0.f); }
                out[(size_t)r * ldo + c] = o;
            }
        }
    }
}

// Fold relation matrices into one combined [128][256] weight:
//   cols 0..127  = kw @ a_rel  (ka),  cols 128..255 = vw @ m_rel (mv)
__global__ __launch_bounds__(128) void fold_rel(
    const float* __restrict__ kw, const float* __restrict__ kb,
    const float* __restrict__ vw, const float* __restrict__ vb,
    const float* __restrict__ arel, const float* __restrict__ mrel,
    float* __restrict__ Wkamv, float* __restrict__ bkamv)
{
    int hf = threadIdx.x;          // 0..127
    int h = hf >> 4, f = hf & 15;
    int c = blockIdx.x;            // 0..127
    float sk = 0.f, sv = 0.f;
    #pragma unroll
    for (int d = 0; d < 16; ++d) {
        float ar = arel[(h * 16 + d) * 16 + f];
        float mr = mrel[(h * 16 + d) * 16 + f];
        sk = fmaf(kw[c * 128 + h * 16 + d], ar, sk);
        sv = fmaf(vw[c * 128 + h * 16 + d], mr, sv);
    }
    Wkamv[c * 256 + hf]       = sk;
    Wkamv[c * 256 + 128 + hf] = sv;
    if (c == 0) {
        float bk = 0.f, bv = 0.f;
        #pragma unroll
        for (int d = 0; d < 16; ++d) {
            bk = fmaf(kb[h * 16 + d], arel[(h * 16 + d) * 16 + f], bk);
            bv = fmaf(vb[h * 16 + d], mrel[(h * 16 + d) * 16 + f], bv);
        }
        bkamv[hf]       = bk;
        bkamv[128 + hf] = bv;
    }
}

// ------------------------- CSR build (once per launch) ----------------------
__global__ __launch_bounds__(256) void hist_dst(const int* __restrict__ dst,
                                                int* __restrict__ deg, int E)
{
    int e = blockIdx.x * 256 + threadIdx.x;
    if (e < E) atomicAdd(&deg[dst[e]], 1);
}

// single-workgroup exclusive scan: thread t owns a contiguous chunk
__global__ __launch_bounds__(1024) void scan_excl(const int* __restrict__ deg,
                                                  int* __restrict__ rowptr, int n)
{
    __shared__ int sums[1024];
    const int tid = threadIdx.x;
    const int chunk = (n + 1023) >> 10;
    const int beg = tid * chunk;
    const int end = min(beg + chunk, n);
    int s = 0;
    for (int i = beg; i < end; ++i) s += deg[i];
    sums[tid] = s;
    __syncthreads();
    #pragma unroll
    for (int off = 1; off < 1024; off <<= 1) {
        int t = (tid >= off) ? sums[tid - off] : 0;
        __syncthreads();
        sums[tid] += t;
        __syncthreads();
    }
    int excl = sums[tid] - s;   // prefix before this chunk
    for (int i = beg; i < end; ++i) { rowptr[i] = excl; excl += deg[i]; }
    if (tid == 1023) rowptr[n] = excl;
}

__global__ __launch_bounds__(256) void fill_csr(const int* __restrict__ src,
                                                const int* __restrict__ dst,
                                                const int* __restrict__ rowptr,
                                                int* __restrict__ cur,
                                                int* __restrict__ csr_src, int E)
{
    int e = blockIdx.x * 256 + threadIdx.x;
    if (e >= E) return;
    int d = dst[e];
    int pos = atomicAdd(&cur[d], 1);
    csr_src[rowptr[d] + pos] = src[e];
}

// --------------- fused gather-side attention aggregation --------------------
// thread = (dst node, head). Online softmax over the CSR neighbor list.
// kamv: [Nsrc][256] = {ka[0:128], mv[128:256]} per src node.
__global__ __launch_bounds__(256) void agg_attn(
    const int* __restrict__ rowptr, const int* __restrict__ csr_src,
    const float* __restrict__ kamv, const float* __restrict__ q,
    const float* __restrict__ prel, float* __restrict__ num,
    int Ndst, int dstOff)
{
    int t = blockIdx.x * 256 + threadIdx.x;
    if (t >= Ndst * 8) return;
    int node = t >> 3, h = t & 7;
    int beg = rowptr[node], end = rowptr[node + 1];
    if (beg == end) return;
    const float4* qp = (const float4*)(q + ((size_t)(dstOff + node)) * 128 + h * 16);
    float4 q0 = qp[0], q1 = qp[1], q2 = qp[2], q3 = qp[3];
    float ph = prel[h] * 0.25f;          // scale = 1/sqrt(16)
    float m = -INFINITY, l = 0.f;
    float4 o0 = make_float4(0,0,0,0), o1 = o0, o2 = o0, o3 = o0;
    for (int j = beg; j < end; ++j) {
        int s = csr_src[j];
        const float4* kp = (const float4*)(kamv + (size_t)s * 256 + h * 16);
        float4 k0 = kp[0], k1 = kp[1], k2 = kp[2], k3 = kp[3];
        float a = q0.x*k0.x + q0.y*k0.y + q0.z*k0.z + q0.w*k0.w
                + q1.x*k1.x + q1.y*k1.y + q1.z*k1.z + q1.w*k1.w
                + q2.x*k2.x + q2.y*k2.y + q2.z*k2.z + q2.w*k2.w
                + q3.x*k3.x + q3.y*k3.y + q3.z*k3.z + q3.w*k3.w;
        a *= ph;
        float mn = fmaxf(m, a);
        float sc = __expf(m - mn);       // first iter: exp(-inf)=0
        float w  = __expf(a - mn);
        l = l * sc + w;
        const float4* vp = (const float4*)(kamv + (size_t)s * 256 + 128 + h * 16);
        float4 v0 = vp[0], v1 = vp[1], v2 = vp[2], v3 = vp[3];
        o0.x = o0.x*sc + w*v0.x; o0.y = o0.y*sc + w*v0.y; o0.z = o0.z*sc + w*v0.z; o0.w = o0.w*sc + w*v0.w;
        o1.x = o1.x*sc + w*v1.x; o1.y = o1.y*sc + w*v1.y; o1.z = o1.z*sc + w*v1.z; o1.w = o1.w*sc + w*v1.w;
        o2.x = o2.x*sc + w*v2.x; o2.y = o2.y*sc + w*v2.y; o2.z = o2.z*sc + w*v2.z; o2.w = o2.w*sc + w*v2.w;
        o3.x = o3.x*sc + w*v3.x; o3.y = o3.y*sc + w*v3.y; o3.z = o3.z*sc + w*v3.z; o3.w = o3.w*sc + w*v3.w;
        m = mn;
    }
    float inv = 1.f / (l + 1e-16f);
    float4* np = (float4*)(num + ((size_t)(dstOff + node)) * 128 + h * 16);
    float4 n0 = np[0], n1 = np[1], n2 = np[2], n3 = np[3];
    n0.x += inv*o0.x; n0.y += inv*o0.y; n0.z += inv*o0.z; n0.w += inv*o0.w;
    n1.x += inv*o1.x; n1.y += inv*o1.y; n1.z += inv*o1.z; n1.w += inv*o1.w;
    n2.x += inv*o2.x; n2.y += inv*o2.y; n2.z += inv*o2.z; n2.w += inv*o2.w;
    n3.x += inv*o3.x; n3.y += inv*o3.y; n3.z += inv*o3.z; n3.w += inv*o3.w;
    np[0] = n0; np[1] = n1; np[2] = n2; np[3] = n3;
}

extern "C" void kernel_launch(void* const* d_in, const int* in_sizes, int n_in,
                              void* d_out, int out_size, void* d_ws, size_t ws_size,
                              hipStream_t stream)
{
    (void)in_sizes; (void)n_in; (void)out_size; (void)ws_size;

    const float* xin[3] = {(const float*)d_in[0], (const float*)d_in[1], (const float*)d_in[2]};
    const int* esrc[4] = {(const int*)d_in[3], (const int*)d_in[5], (const int*)d_in[7], (const int*)d_in[9]};
    const int* edst[4] = {(const int*)d_in[4], (const int*)d_in[6], (const int*)d_in[8], (const int*)d_in[10]};
    const float* lin_w = (const float*)d_in[11];
    const float* lin_b = (const float*)d_in[12];
    const float* kw = (const float*)d_in[13];
    const float* qw = (const float*)d_in[14];
    const float* vw = (const float*)d_in[15];
    const float* aw = (const float*)d_in[16];
    const float* kb = (const float*)d_in[17];
    const float* qb = (const float*)d_in[18];
    const float* vb = (const float*)d_in[19];
    const float* ab = (const float*)d_in[20];
    const float* a_rel = (const float*)d_in[21];
    const float* m_rel = (const float*)d_in[22];
    const float* p_rel = (const float*)d_in[23];
    const float* skip  = (const float*)d_in[24];
    const float* out_w = (const float*)d_in[25];
    const float* out_b = (const float*)d_in[26];

    // workspace layout (float offsets); total ~53.3M floats ≈ 213 MB
    float* ws = (float*)d_ws;
    float* xs    = ws;                       // 96000*128 = 12,288,000
    float* q     = ws + 12288000;            // 12,288,000
    float* num   = ws + 24576000;            // 12,288,000
    float* kamv  = ws + 36864000;            // 60000*256 = 15,360,000
    float* Wkamv = ws + 52224000;            // 128*256 = 32,768
    float* bkamv = ws + 52256768;            // 256
    int*   deg   = (int*)(ws + 52257024);    // 60,000 (also reused as fill cursor)
    int*   rp[4];
    rp[0] = (int*)(ws + 52317024);           // 60,001
    rp[1] = (int*)(ws + 52377025);           // 60,001
    rp[2] = (int*)(ws + 52437026);           // 6,001
    rp[3] = (int*)(ws + 52443027);           // 30,001
    int*   cs[4];
    cs[0] = (int*)(ws + 52473028);           // 200,000
    cs[1] = (int*)(ws + 52673028);           // 300,000
    cs[2] = (int*)(ws + 52973028);           // 200,000
    cs[3] = (int*)(ws + 53173028);           // 100,000

    const int NNv[3] = {30000, 60000, 6000};
    const int OFF[3] = {0, 30000, 90000};
    const int NEv[4] = {200000, 300000, 200000, 100000};
    const int SI[4] = {0, 1, 1, 2};
    const int DI[4] = {1, 1, 2, 0};
    const size_t OUTOFF[3] = {0, (size_t)30000 * 64, (size_t)90000 * 64};

    dim3 blk(256);

    // ---- build CSR per edge type (edges static; reused across both layers) ----
    for (int et = 0; et < 4; ++et) {
        int di = DI[et], E = NEv[et], Nd = NNv[di];
        hipMemsetAsync(deg, 0, (size_t)Nd * 4, stream);
        hist_dst<<<dim3((E + 255) / 256), blk, 0, stream>>>(edst[et], deg, E);
        scan_excl<<<dim3(1), dim3(1024), 0, stream>>>(deg, rp[et], Nd);
        hipMemsetAsync(deg, 0, (size_t)Nd * 4, stream);   // reuse as cursor
        fill_csr<<<dim3((E + 255) / 256), blk, 0, stream>>>(esrc[et], edst[et], rp[et], deg, cs[et], E);
    }

    // ---- input linear + relu -> xs ----
    for (int i = 0; i < 3; ++i) {
        dim3 g((NNv[i] + BM - 1) / BM, 2);
        gemm_k128<1, false><<<g, blk, 0, stream>>>(
            xin[i], lin_w + (size_t)i * 16384, lin_b + i * 128,
            nullptr, nullptr, xs + (size_t)OFF[i] * 128, 128, 128, NNv[i]);
    }

    for (int l = 0; l < 2; ++l) {
        hipMemsetAsync(num, 0, (size_t)12288000 * 4, stream);

        // Q projection per node type
        for (int i = 0; i < 3; ++i) {
            dim3 g((NNv[i] + BM - 1) / BM, 2);
            gemm_k128<0, false><<<g, blk, 0, stream>>>(
                xs + (size_t)OFF[i] * 128,
                qw + (size_t)(l * 3 + i) * 16384, qb + (l * 3 + i) * 128,
                nullptr, nullptr, q + (size_t)OFF[i] * 128, 128, 128, NNv[i]);
        }

        for (int et = 0; et < 4; ++et) {
            int si = SI[et], di = DI[et];
            fold_rel<<<dim3(128), dim3(128), 0, stream>>>(
                kw + (size_t)(l * 3 + si) * 16384, kb + (l * 3 + si) * 128,
                vw + (size_t)(l * 3 + si) * 16384, vb + (l * 3 + si) * 128,
                a_rel + (size_t)(l * 4 + et) * 2048, m_rel + (size_t)(l * 4 + et) * 2048,
                Wkamv, bkamv);

            // combined ka|mv projection: [Nsrc,128] @ [128,256]
            dim3 gs((NNv[si] + BM - 1) / BM, 4);
            gemm_k128<0, false><<<gs, blk, 0, stream>>>(
                xs + (size_t)OFF[si] * 128, Wkamv, bkamv,
                nullptr, nullptr, kamv, 256, 256, NNv[si]);

            dim3 ga((NNv[di] * 8 + 255) / 256);
            agg_attn<<<ga, blk, 0, stream>>>(
                rp[et], cs[et], kamv, q,
                p_rel + (size_t)(l * 4 + et) * 8, num, NNv[di], OFF[di]);
        }

        // node update: xs = relu(beta * (gelu(num) @ aw + ab) + (1-beta) * xs)
        for (int i = 0; i < 3; ++i) {
            dim3 g((NNv[i] + BM - 1) / BM, 2);
            gemm_k128<2, true><<<g, blk, 0, stream>>>(
                num + (size_t)OFF[i] * 128,
                aw + (size_t)(l * 3 + i) * 16384, ab + (l * 3 + i) * 128,
                xs + (size_t)OFF[i] * 128, skip + (l * 3 + i),
                xs + (size_t)OFF[i] * 128, 128, 128, NNv[i]);
        }
    }

    // ---- output projection (C=128 -> OUT=64) ----
    float* out = (float*)d_out;
    for (int i = 0; i < 3; ++i) {
        dim3 g((NNv[i] + BM - 1) / BM, 1);
        gemm_k128<0, false><<<g, blk, 0, stream>>>(
            xs + (size_t)OFF[i] * 128, out_w, out_b,
            nullptr, nullptr, out + OUTOFF[i], 64, 64, NNv[i]);
    }
}

// Round 4
// 1345.668 us; speedup vs baseline: 9.5511x; 1.2140x over previous
//
#include <hip/hip_runtime.h>
#include <cstddef>
#include <cstdint>

// ---------------------------------------------------------------------------
// HGT forward for MI355X. C=128, H=8, D=16, OUT=64, L=2
//   NN = {30000, 60000, 6000}, NE = {200000, 300000, 200000, 100000}
//   ETS = {(0,1),(1,1),(1,2),(2,0)}
// Round-3 changes:
//  * Multi-block 3-phase CSR scan (was: 95us single-workgroup serial scan x4)
//  * agg_attn templated ACCUM: first edge type per dst type WRITES (zeros for
//    empty nodes) -> num memsets removed
//  * GEMM grid swapped (x=col tile, y=row tile) so consecutive blocks share
//    the A row-tile (A read ~once from HBM instead of once per col tile)
//  * fold_rel batched across {layer, edge type} into one launch
// ---------------------------------------------------------------------------

__device__ __forceinline__ float gelu_tanh(float x) {
    const float c = 0.7978845608028654f;
    float t = tanhf(c * (x + 0.044715f * x * x * x));
    return 0.5f * x * (1.0f + t);
}

#define BM 64
#define BN 64
#define BK 16

// EPI: 0 = bias only, 1 = bias+relu, 2 = skip-combine (+relu). GIN: gelu on A-load.
template<int EPI, bool GIN>
__global__ __launch_bounds__(256) void gemm_k128(
    const float* __restrict__ A,
    const float* __restrict__ W, const float* __restrict__ bias,
    const float* __restrict__ xold, const float* __restrict__ skipp,
    float* __restrict__ out, int ldw, int ldo, int N)
{
    __shared__ float As[BK][BM + 4];
    __shared__ float Bs[BK][BN + 4];
    const int tid = threadIdx.x;
    const int tx = tid & 15, ty = tid >> 4;
    const int rowBase = blockIdx.y * BM;   // y = row tile (A reuse across consecutive x blocks)
    const int colBase = blockIdx.x * BN;   // x = col tile
    const int la_row = tid >> 2;         // 0..63
    const int la_k4  = (tid & 3) << 2;   // 0,4,8,12
    const int lb_k   = tid >> 4;         // 0..15
    const int lb_c   = (tid & 15) << 2;  // 0..60
    float acc[4][4] = {};
    for (int k0 = 0; k0 < 128; k0 += BK) {
        int gr = rowBase + la_row;
        float4 av = make_float4(0.f, 0.f, 0.f, 0.f);
        if (gr < N) {
            av = *(const float4*)(A + (size_t)gr * 128 + k0 + la_k4);
            if (GIN) {
                av.x = gelu_tanh(av.x);
                av.y = gelu_tanh(av.y);
                av.z = gelu_tanh(av.z);
                av.w = gelu_tanh(av.w);
            }
        }
        As[la_k4 + 0][la_row] = av.x;
        As[la_k4 + 1][la_row] = av.y;
        As[la_k4 + 2][la_row] = av.z;
        As[la_k4 + 3][la_row] = av.w;
        *(float4*)&Bs[lb_k][lb_c] =
            *(const float4*)(W + (size_t)(k0 + lb_k) * ldw + colBase + lb_c);
        __syncthreads();
        #pragma unroll
        for (int kk = 0; kk < BK; ++kk) {
            float4 a4 = *(const float4*)&As[kk][ty << 2];
            float4 b4 = *(const float4*)&Bs[kk][tx << 2];
            float ar[4] = {a4.x, a4.y, a4.z, a4.w};
            float br[4] = {b4.x, b4.y, b4.z, b4.w};
            #pragma unroll
            for (int i = 0; i < 4; ++i)
                #pragma unroll
                for (int j = 0; j < 4; ++j)
                    acc[i][j] = fmaf(ar[i], br[j], acc[i][j]);
        }
        __syncthreads();
    }
    float beta = 0.f, omb = 0.f;
    if (EPI == 2) { beta = 1.0f / (1.0f + __expf(-skipp[0])); omb = 1.0f - beta; }
    #pragma unroll
    for (int i = 0; i < 4; ++i) {
        int r = rowBase + (ty << 2) + i;
        if (r < N) {
            #pragma unroll
            for (int j = 0; j < 4; ++j) {
                int c = colBase + (tx << 2) + j;
                float o = acc[i][j] + bias[c];
                if (EPI == 1) o = fmaxf(o, 0.f);
                if (EPI == 2) { o = beta * o + omb * xold[(size_t)r * 128 + c]; o = fmaxf(o, 0.f); }
                out[(size_t)r * ldo + c] = o;
            }
        }
    }
}

// Fold relation matrices for ALL (layer, edge type) pairs in one launch.
// Wall[(l*4+et)][c][0:128]=kw@a_rel, [128:256]=vw@m_rel; ball likewise.
__global__ __launch_bounds__(128) void fold_rel_all(
    const float* __restrict__ kw, const float* __restrict__ kb,
    const float* __restrict__ vw, const float* __restrict__ vb,
    const float* __restrict__ a_rel, const float* __restrict__ m_rel,
    float* __restrict__ Wall, float* __restrict__ ball)
{
    const int SIv[4] = {0, 1, 1, 2};
    int hf = threadIdx.x;          // 0..127
    int h = hf >> 4, f = hf & 15;
    int c  = blockIdx.x;           // 0..127
    int et = blockIdx.y;           // 0..3
    int l  = blockIdx.z;           // 0..1
    int si = SIv[et];
    const float* kwp  = kw + (size_t)(l * 3 + si) * 16384;
    const float* vwp  = vw + (size_t)(l * 3 + si) * 16384;
    const float* kbp  = kb + (size_t)(l * 3 + si) * 128;
    const float* vbp  = vb + (size_t)(l * 3 + si) * 128;
    const float* arel = a_rel + (size_t)(l * 4 + et) * 2048;
    const float* mrel = m_rel + (size_t)(l * 4 + et) * 2048;
    float sk = 0.f, sv = 0.f;
    #pragma unroll
    for (int d = 0; d < 16; ++d) {
        float ar = arel[(h * 16 + d) * 16 + f];
        float mr = mrel[(h * 16 + d) * 16 + f];
        sk = fmaf(kwp[c * 128 + h * 16 + d], ar, sk);
        sv = fmaf(vwp[c * 128 + h * 16 + d], mr, sv);
    }
    float* W = Wall + (size_t)(l * 4 + et) * 32768;
    W[c * 256 + hf]       = sk;
    W[c * 256 + 128 + hf] = sv;
    if (c == 0) {
        float bk = 0.f, bv = 0.f;
        #pragma unroll
        for (int d = 0; d < 16; ++d) {
            bk = fmaf(kbp[h * 16 + d], arel[(h * 16 + d) * 16 + f], bk);
            bv = fmaf(vbp[h * 16 + d], mrel[(h * 16 + d) * 16 + f], bv);
        }
        float* b = ball + (size_t)(l * 4 + et) * 256;
        b[hf]       = bk;
        b[128 + hf] = bv;
    }
}

// ------------------------- CSR build (once per launch) ----------------------
__global__ __launch_bounds__(256) void hist_dst(const int* __restrict__ dst,
                                                int* __restrict__ deg, int E)
{
    int e = blockIdx.x * 256 + threadIdx.x;
    if (e < E) atomicAdd(&deg[dst[e]], 1);
}

// phase 1: per-block exclusive scan of 1024-element tiles (256 thr x 4 elems)
__global__ __launch_bounds__(256) void scan_tile(
    const int* __restrict__ deg, int* __restrict__ rowptr,
    int* __restrict__ tileSum, int n)
{
    __shared__ int ls[256];
    int b = blockIdx.x, tid = threadIdx.x;
    int base = b * 1024 + tid * 4;
    int v0 = 0, v1 = 0, v2 = 0, v3 = 0;
    if (base + 3 < n) {
        int4 t = *(const int4*)(deg + base);
        v0 = t.x; v1 = t.y; v2 = t.z; v3 = t.w;
    } else {
        if (base + 0 < n) v0 = deg[base + 0];
        if (base + 1 < n) v1 = deg[base + 1];
        if (base + 2 < n) v2 = deg[base + 2];
        if (base + 3 < n) v3 = deg[base + 3];
    }
    int s = v0 + v1 + v2 + v3;
    ls[tid] = s;
    __syncthreads();
    #pragma unroll
    for (int off = 1; off < 256; off <<= 1) {
        int t = (tid >= off) ? ls[tid - off] : 0;
        __syncthreads();
        ls[tid] += t;
        __syncthreads();
    }
    int run = ls[tid] - s;   // exclusive prefix within tile
    int o0 = run; run += v0;
    int o1 = run; run += v1;
    int o2 = run; run += v2;
    int o3 = run;
    if (base + 3 < n) {
        *(int4*)(rowptr + base) = make_int4(o0, o1, o2, o3);
    } else {
        if (base + 0 < n) rowptr[base + 0] = o0;
        if (base + 1 < n) rowptr[base + 1] = o1;
        if (base + 2 < n) rowptr[base + 2] = o2;
    }
    if (tid == 255) tileSum[b] = ls[255];
}

// phase 2: one wave scans tile sums (nt <= 64 always here), writes total
__global__ __launch_bounds__(64) void scan_tsum(
    int* __restrict__ tileSum, int nt, int* __restrict__ totalOut)
{
    int tid = threadIdx.x;
    int v = (tid < nt) ? tileSum[tid] : 0;
    int orig = v;
    #pragma unroll
    for (int off = 1; off < 64; off <<= 1) {
        int t = __shfl_up(v, off);
        if (tid >= off) v += t;
    }
    if (tid < nt) tileSum[tid] = v - orig;   // exclusive
    if (tid == nt - 1) *totalOut = v;        // rowptr[n]
}

// phase 3: add tile offsets
__global__ __launch_bounds__(256) void scan_add(
    int* __restrict__ rowptr, const int* __restrict__ tileSum, int n)
{
    int i = blockIdx.x * 256 + threadIdx.x;
    if (i < n) rowptr[i] += tileSum[i >> 10];
}

__global__ __launch_bounds__(256) void fill_csr(const int* __restrict__ src,
                                                const int* __restrict__ dst,
                                                const int* __restrict__ rowptr,
                                                int* __restrict__ cur,
                                                int* __restrict__ csr_src, int E)
{
    int e = blockIdx.x * 256 + threadIdx.x;
    if (e >= E) return;
    int d = dst[e];
    int pos = atomicAdd(&cur[d], 1);
    csr_src[rowptr[d] + pos] = src[e];
}

// --------------- fused gather-side attention aggregation --------------------
// thread = (dst node, head). Online softmax over the CSR neighbor list.
// kamv: [Nsrc][256] = {ka[0:128], mv[128:256]} per src node.
// ACCUM=false: overwrite num (zeros for empty nodes). ACCUM=true: num +=.
template<bool ACCUM>
__global__ __launch_bounds__(256) void agg_attn(
    const int* __restrict__ rowptr, const int* __restrict__ csr_src,
    const float* __restrict__ kamv, const float* __restrict__ q,
    const float* __restrict__ prel, float* __restrict__ num,
    int Ndst, int dstOff)
{
    int t = blockIdx.x * 256 + threadIdx.x;
    if (t >= Ndst * 8) return;
    int node = t >> 3, h = t & 7;
    int beg = rowptr[node], end = rowptr[node + 1];
    float m = -INFINITY, l = 0.f;
    float4 o0 = make_float4(0,0,0,0), o1 = o0, o2 = o0, o3 = o0;
    if (beg < end) {
        const float4* qp = (const float4*)(q + ((size_t)(dstOff + node)) * 128 + h * 16);
        float4 q0 = qp[0], q1 = qp[1], q2 = qp[2], q3 = qp[3];
        float ph = prel[h] * 0.25f;          // scale = 1/sqrt(16)
        for (int j = beg; j < end; ++j) {
            int s = csr_src[j];
            const float4* kp = (const float4*)(kamv + (size_t)s * 256 + h * 16);
            float4 k0 = kp[0], k1 = kp[1], k2 = kp[2], k3 = kp[3];
            float a = q0.x*k0.x + q0.y*k0.y + q0.z*k0.z + q0.w*k0.w
                    + q1.x*k1.x + q1.y*k1.y + q1.z*k1.z + q1.w*k1.w
                    + q2.x*k2.x + q2.y*k2.y + q2.z*k2.z + q2.w*k2.w
                    + q3.x*k3.x + q3.y*k3.y + q3.z*k3.z + q3.w*k3.w;
            a *= ph;
            float mn = fmaxf(m, a);
            float sc = __expf(m - mn);       // first iter: exp(-inf)=0
            float w  = __expf(a - mn);
            l = l * sc + w;
            const float4* vp = (const float4*)(kamv + (size_t)s * 256 + 128 + h * 16);
            float4 v0 = vp[0], v1 = vp[1], v2 = vp[2], v3 = vp[3];
            o0.x = o0.x*sc + w*v0.x; o0.y = o0.y*sc + w*v0.y; o0.z = o0.z*sc + w*v0.z; o0.w = o0.w*sc + w*v0.w;
            o1.x = o1.x*sc + w*v1.x; o1.y = o1.y*sc + w*v1.y; o1.z = o1.z*sc + w*v1.z; o1.w = o1.w*sc + w*v1.w;
            o2.x = o2.x*sc + w*v2.x; o2.y = o2.y*sc + w*v2.y; o2.z = o2.z*sc + w*v2.z; o2.w = o2.w*sc + w*v2.w;
            o3.x = o3.x*sc + w*v3.x; o3.y = o3.y*sc + w*v3.y; o3.z = o3.z*sc + w*v3.z; o3.w = o3.w*sc + w*v3.w;
            m = mn;
        }
    } else if (ACCUM) {
        return;   // nothing to add
    }
    float inv = 1.f / (l + 1e-16f);
    float4* np = (float4*)(num + ((size_t)(dstOff + node)) * 128 + h * 16);
    if (ACCUM) {
        float4 n0 = np[0], n1 = np[1], n2 = np[2], n3 = np[3];
        n0.x += inv*o0.x; n0.y += inv*o0.y; n0.z += inv*o0.z; n0.w += inv*o0.w;
        n1.x += inv*o1.x; n1.y += inv*o1.y; n1.z += inv*o1.z; n1.w += inv*o1.w;
        n2.x += inv*o2.x; n2.y += inv*o2.y; n2.z += inv*o2.z; n2.w += inv*o2.w;
        n3.x += inv*o3.x; n3.y += inv*o3.y; n3.z += inv*o3.z; n3.w += inv*o3.w;
        np[0] = n0; np[1] = n1; np[2] = n2; np[3] = n3;
    } else {
        np[0] = make_float4(inv*o0.x, inv*o0.y, inv*o0.z, inv*o0.w);
        np[1] = make_float4(inv*o1.x, inv*o1.y, inv*o1.z, inv*o1.w);
        np[2] = make_float4(inv*o2.x, inv*o2.y, inv*o2.z, inv*o2.w);
        np[3] = make_float4(inv*o3.x, inv*o3.y, inv*o3.z, inv*o3.w);
    }
}

extern "C" void kernel_launch(void* const* d_in, const int* in_sizes, int n_in,
                              void* d_out, int out_size, void* d_ws, size_t ws_size,
                              hipStream_t stream)
{
    (void)in_sizes; (void)n_in; (void)out_size; (void)ws_size;

    const float* xin[3] = {(const float*)d_in[0], (const float*)d_in[1], (const float*)d_in[2]};
    const int* esrc[4] = {(const int*)d_in[3], (const int*)d_in[5], (const int*)d_in[7], (const int*)d_in[9]};
    const int* edst[4] = {(const int*)d_in[4], (const int*)d_in[6], (const int*)d_in[8], (const int*)d_in[10]};
    const float* lin_w = (const float*)d_in[11];
    const float* lin_b = (const float*)d_in[12];
    const float* kw = (const float*)d_in[13];
    const float* qw = (const float*)d_in[14];
    const float* vw = (const float*)d_in[15];
    const float* aw = (const float*)d_in[16];
    const float* kb = (const float*)d_in[17];
    const float* qb = (const float*)d_in[18];
    const float* vb = (const float*)d_in[19];
    const float* ab = (const float*)d_in[20];
    const float* a_rel = (const float*)d_in[21];
    const float* m_rel = (const float*)d_in[22];
    const float* p_rel = (const float*)d_in[23];
    const float* skip  = (const float*)d_in[24];
    const float* out_w = (const float*)d_in[25];
    const float* out_b = (const float*)d_in[26];

    // workspace layout (float indices, all 16B-aligned); total ~53.5M floats = 214 MB
    float* ws = (float*)d_ws;
    float* xs    = ws;                         // 12,288,000
    float* q     = ws + 12288000;              // 12,288,000
    float* num   = ws + 24576000;              // 12,288,000
    float* kamv  = ws + 36864000;              // 15,360,000
    float* Wall  = ws + 52224000;              // 8*32768 = 262,144
    float* ball  = ws + 52486144;              // 8*256 = 2,048
    int*   deg   = (int*)(ws + 52488192);      // 60,000 (also fill cursor)
    int*   tsum  = (int*)(ws + 52548192);      // 64
    int*   rp[4];
    rp[0] = (int*)(ws + 52548256);             // 60,004
    rp[1] = (int*)(ws + 52608260);             // 60,004
    rp[2] = (int*)(ws + 52668264);             // 6,004
    rp[3] = (int*)(ws + 52674268);             // 30,004
    int*   cs[4];
    cs[0] = (int*)(ws + 52704272);             // 200,000
    cs[1] = (int*)(ws + 52904272);             // 300,000
    cs[2] = (int*)(ws + 53204272);             // 200,000
    cs[3] = (int*)(ws + 53404272);             // 100,000

    const int NNv[3] = {30000, 60000, 6000};
    const int OFF[3] = {0, 30000, 90000};
    const int NEv[4] = {200000, 300000, 200000, 100000};
    const int SI[4] = {0, 1, 1, 2};
    const int DI[4] = {1, 1, 2, 0};
    const size_t OUTOFF[3] = {0, (size_t)30000 * 64, (size_t)90000 * 64};

    dim3 blk(256);

    // ---- build CSR per edge type (edges static; reused across both layers) ----
    for (int et = 0; et < 4; ++et) {
        int di = DI[et], E = NEv[et], Nd = NNv[di];
        int nt = (Nd + 1023) / 1024;
        hipMemsetAsync(deg, 0, (size_t)Nd * 4, stream);
        hist_dst<<<dim3((E + 255) / 256), blk, 0, stream>>>(edst[et], deg, E);
        scan_tile<<<dim3(nt), blk, 0, stream>>>(deg, rp[et], tsum, Nd);
        scan_tsum<<<dim3(1), dim3(64), 0, stream>>>(tsum, nt, rp[et] + Nd);
        scan_add<<<dim3((Nd + 255) / 256), blk, 0, stream>>>(rp[et], tsum, Nd);
        hipMemsetAsync(deg, 0, (size_t)Nd * 4, stream);   // reuse as cursor
        fill_csr<<<dim3((E + 255) / 256), blk, 0, stream>>>(esrc[et], edst[et], rp[et], deg, cs[et], E);
    }

    // ---- fold all relation weights (both layers, all edge types) ----
    fold_rel_all<<<dim3(128, 4, 2), dim3(128), 0, stream>>>(
        kw, kb, vw, vb, a_rel, m_rel, Wall, ball);

    // ---- input linear + relu -> xs ----
    for (int i = 0; i < 3; ++i) {
        dim3 g(2, (NNv[i] + BM - 1) / BM);
        gemm_k128<1, false><<<g, blk, 0, stream>>>(
            xin[i], lin_w + (size_t)i * 16384, lin_b + i * 128,
            nullptr, nullptr, xs + (size_t)OFF[i] * 128, 128, 128, NNv[i]);
    }

    for (int l = 0; l < 2; ++l) {
        // Q projection per node type
        for (int i = 0; i < 3; ++i) {
            dim3 g(2, (NNv[i] + BM - 1) / BM);
            gemm_k128<0, false><<<g, blk, 0, stream>>>(
                xs + (size_t)OFF[i] * 128,
                qw + (size_t)(l * 3 + i) * 16384, qb + (l * 3 + i) * 128,
                nullptr, nullptr, q + (size_t)OFF[i] * 128, 128, 128, NNv[i]);
        }

        for (int et = 0; et < 4; ++et) {
            int si = SI[et], di = DI[et];

            // combined ka|mv projection: [Nsrc,128] @ [128,256]
            dim3 gs(4, (NNv[si] + BM - 1) / BM);
            gemm_k128<0, false><<<gs, blk, 0, stream>>>(
                xs + (size_t)OFF[si] * 128,
                Wall + (size_t)(l * 4 + et) * 32768, ball + (size_t)(l * 4 + et) * 256,
                nullptr, nullptr, kamv, 256, 256, NNv[si]);

            dim3 ga((NNv[di] * 8 + 255) / 256);
            if (et == 1) {   // road accumulates on top of et0
                agg_attn<true><<<ga, blk, 0, stream>>>(
                    rp[et], cs[et], kamv, q,
                    p_rel + (size_t)(l * 4 + et) * 8, num, NNv[di], OFF[di]);
            } else {         // first (only) writer for this dst type
                agg_attn<false><<<ga, blk, 0, stream>>>(
                    rp[et], cs[et], kamv, q,
                    p_rel + (size_t)(l * 4 + et) * 8, num, NNv[di], OFF[di]);
            }
        }

        // node update: xs = relu(beta * (gelu(num) @ aw + ab) + (1-beta) * xs)
        for (int i = 0; i < 3; ++i) {
            dim3 g(2, (NNv[i] + BM - 1) / BM);
            gemm_k128<2, true><<<g, blk, 0, stream>>>(
                num + (size_t)OFF[i] * 128,
                aw + (size_t)(l * 3 + i) * 16384, ab + (l * 3 + i) * 128,
                xs + (size_t)OFF[i] * 128, skip + (l * 3 + i),
                xs + (size_t)OFF[i] * 128, 128, 128, NNv[i]);
        }
    }

    // ---- output projection (C=128 -> OUT=64) ----
    float* out = (float*)d_out;
    for (int i = 0; i < 3; ++i) {
        dim3 g(1, (NNv[i] + BM - 1) / BM);
        gemm_k128<0, false><<<g, blk, 0, stream>>>(
            xs + (size_t)OFF[i] * 128, out_w, out_b,
            nullptr, nullptr, out + OUTOFF[i], 64, 64, NNv[i]);
    }
}

// Round 5
// 1119.245 us; speedup vs baseline: 11.4833x; 1.2023x over previous
//
#include <hip/hip_runtime.h>
#include <cstddef>
#include <cstdint>

// ---------------------------------------------------------------------------
// HGT forward for MI355X. C=128, H=8, D=16, OUT=64, L=2
//   NN = {30000, 60000, 6000}, NE = {200000, 300000, 200000, 100000}
//   ETS = {(0,1),(1,1),(1,2),(2,0)}
// Round-4 changes:
//  * kamv + q gather tables stored bf16 (halves agg_attn's 182MB/dispatch fetch)
//  * kamv & Q projections -> no-LDS MFMA bf16 GEMM (16x16x32), weights
//    pre-transposed to [n][k] bf16 (fold_rel_all / prep_qw)
//  * node-state GEMMs stay fp32; epilogues emit bf16 xs copy for MFMA inputs
// ---------------------------------------------------------------------------

typedef __attribute__((ext_vector_type(8))) short short8;   // 8 x bf16 (4 VGPR)
typedef __attribute__((ext_vector_type(4))) float floatx4;

__device__ __forceinline__ float gelu_tanh(float x) {
    const float c = 0.7978845608028654f;
    float t = tanhf(c * (x + 0.044715f * x * x * x));
    return 0.5f * x * (1.0f + t);
}

__device__ __forceinline__ unsigned short f2bf(float f) {   // RNE fp32->bf16
    unsigned u = __float_as_uint(f);
    u += 0x7fffu + ((u >> 16) & 1);
    return (unsigned short)(u >> 16);
}

__device__ __forceinline__ void up8(uint4 u, float* f) {    // 8 bf16 -> 8 fp32
    f[0] = __uint_as_float(u.x << 16); f[1] = __uint_as_float(u.x & 0xffff0000u);
    f[2] = __uint_as_float(u.y << 16); f[3] = __uint_as_float(u.y & 0xffff0000u);
    f[4] = __uint_as_float(u.z << 16); f[5] = __uint_as_float(u.z & 0xffff0000u);
    f[6] = __uint_as_float(u.w << 16); f[7] = __uint_as_float(u.w & 0xffff0000u);
}

#define BM 64
#define BN 64
#define BK 16

// ------------------- fp32 GEMM (node-state path) ---------------------------
// EPI: 0 bias, 1 bias+relu, 2 skip-combine+relu. GIN: gelu on A. WBF: also
// write bf16 copy of the output (ld 128) for the MFMA consumers.
template<int EPI, bool GIN, bool WBF>
__global__ __launch_bounds__(256) void gemm_k128(
    const float* __restrict__ A,
    const float* __restrict__ W, const float* __restrict__ bias,
    const float* __restrict__ xold, const float* __restrict__ skipp,
    float* __restrict__ out, unsigned short* __restrict__ out_bf,
    int ldw, int ldo, int N)
{
    __shared__ float As[BK][BM + 4];
    __shared__ float Bs[BK][BN + 4];
    const int tid = threadIdx.x;
    const int tx = tid & 15, ty = tid >> 4;
    const int rowBase = blockIdx.y * BM;
    const int colBase = blockIdx.x * BN;
    const int la_row = tid >> 2;
    const int la_k4  = (tid & 3) << 2;
    const int lb_k   = tid >> 4;
    const int lb_c   = (tid & 15) << 2;
    float acc[4][4] = {};
    for (int k0 = 0; k0 < 128; k0 += BK) {
        int gr = rowBase + la_row;
        float4 av = make_float4(0.f, 0.f, 0.f, 0.f);
        if (gr < N) {
            av = *(const float4*)(A + (size_t)gr * 128 + k0 + la_k4);
            if (GIN) {
                av.x = gelu_tanh(av.x);
                av.y = gelu_tanh(av.y);
                av.z = gelu_tanh(av.z);
                av.w = gelu_tanh(av.w);
            }
        }
        As[la_k4 + 0][la_row] = av.x;
        As[la_k4 + 1][la_row] = av.y;
        As[la_k4 + 2][la_row] = av.z;
        As[la_k4 + 3][la_row] = av.w;
        *(float4*)&Bs[lb_k][lb_c] =
            *(const float4*)(W + (size_t)(k0 + lb_k) * ldw + colBase + lb_c);
        __syncthreads();
        #pragma unroll
        for (int kk = 0; kk < BK; ++kk) {
            float4 a4 = *(const float4*)&As[kk][ty << 2];
            float4 b4 = *(const float4*)&Bs[kk][tx << 2];
            float ar[4] = {a4.x, a4.y, a4.z, a4.w};
            float br[4] = {b4.x, b4.y, b4.z, b4.w};
            #pragma unroll
            for (int i = 0; i < 4; ++i)
                #pragma unroll
                for (int j = 0; j < 4; ++j)
                    acc[i][j] = fmaf(ar[i], br[j], acc[i][j]);
        }
        __syncthreads();
    }
    float beta = 0.f, omb = 0.f;
    if (EPI == 2) { beta = 1.0f / (1.0f + __expf(-skipp[0])); omb = 1.0f - beta; }
    #pragma unroll
    for (int i = 0; i < 4; ++i) {
        int r = rowBase + (ty << 2) + i;
        if (r < N) {
            #pragma unroll
            for (int j = 0; j < 4; ++j) {
                int c = colBase + (tx << 2) + j;
                float o = acc[i][j] + bias[c];
                if (EPI == 1) o = fmaxf(o, 0.f);
                if (EPI == 2) { o = beta * o + omb * xold[(size_t)r * 128 + c]; o = fmaxf(o, 0.f); }
                out[(size_t)r * ldo + c] = o;
                if (WBF) out_bf[(size_t)r * 128 + c] = f2bf(o);
            }
        }
    }
}

// ------------------- MFMA bf16 GEMM (attention path) -----------------------
// A: [Nrows][128] bf16 row-major. Wt: [NcolsTot][128] bf16 (W transposed).
// out: bf16 [Nrows][ldo], bias fp32. No LDS: A/B frags loaded straight from
// global (B is tiny & L2-hot; A rows re-read per col-tile hit L2).
// Frag layouts (verified m89/m120): A[m=lane&15][k=quad*8+j],
// B[k=quad*8+j][n=lane&15], D[row=quad*4+reg][col=lane&15].
__global__ __launch_bounds__(256) void gemm_mfma(
    const unsigned short* __restrict__ Abf,
    const unsigned short* __restrict__ Wt,
    const float* __restrict__ bias,
    unsigned short* __restrict__ outbf, int ldo, int Nrows)
{
    const int tid = threadIdx.x;
    const int wave = tid >> 6, lane = tid & 63;
    const int quad = lane >> 4, l16 = lane & 15;
    const int rowBase = blockIdx.y * 64 + wave * 16;
    const int colBase = blockIdx.x * 64;
    int m = rowBase + l16;
    size_t arow = (size_t)((m < Nrows) ? m : 0) * 128;   // clamp; bad rows masked on store
    const unsigned short* ap = Abf + arow + quad * 8;
    const unsigned short* wp = Wt + (size_t)(colBase + l16) * 128 + quad * 8;
    floatx4 acc[4] = {{0,0,0,0},{0,0,0,0},{0,0,0,0},{0,0,0,0}};
    #pragma unroll
    for (int k0 = 0; k0 < 128; k0 += 32) {
        short8 a = *(const short8*)(ap + k0);
        #pragma unroll
        for (int c = 0; c < 4; ++c) {
            short8 b = *(const short8*)(wp + (size_t)c * 16 * 128 + k0);
            acc[c] = __builtin_amdgcn_mfma_f32_16x16x32_bf16(a, b, acc[c], 0, 0, 0);
        }
    }
    int row0 = rowBase + quad * 4;
    #pragma unroll
    for (int c = 0; c < 4; ++c) {
        int col = colBase + c * 16 + l16;
        float bv = bias[col];
        #pragma unroll
        for (int r = 0; r < 4; ++r) {
            int row = row0 + r;
            if (row < Nrows)
                outbf[(size_t)row * ldo + col] = f2bf(acc[c][r] + bv);
        }
    }
}

// Fold relation matrices for ALL (layer, edge type): write TRANSPOSED bf16
// Wt[(l*4+et)][n][k]: n in [0,128) = kw@a_rel cols, n in [128,256) = vw@m_rel.
__global__ __launch_bounds__(128) void fold_rel_all(
    const float* __restrict__ kw, const float* __restrict__ kb,
    const float* __restrict__ vw, const float* __restrict__ vb,
    const float* __restrict__ a_rel, const float* __restrict__ m_rel,
    unsigned short* __restrict__ Wt, float* __restrict__ ball)
{
    const int SIv[4] = {0, 1, 1, 2};
    int hf = threadIdx.x;          // 0..127 (n)
    int h = hf >> 4, f = hf & 15;
    int c  = blockIdx.x;           // 0..127 (k)
    int et = blockIdx.y;
    int l  = blockIdx.z;
    int si = SIv[et];
    const float* kwp  = kw + (size_t)(l * 3 + si) * 16384;
    const float* vwp  = vw + (size_t)(l * 3 + si) * 16384;
    const float* kbp  = kb + (size_t)(l * 3 + si) * 128;
    const float* vbp  = vb + (size_t)(l * 3 + si) * 128;
    const float* arel = a_rel + (size_t)(l * 4 + et) * 2048;
    const float* mrel = m_rel + (size_t)(l * 4 + et) * 2048;
    float sk = 0.f, sv = 0.f;
    #pragma unroll
    for (int d = 0; d < 16; ++d) {
        float ar = arel[(h * 16 + d) * 16 + f];
        float mr = mrel[(h * 16 + d) * 16 + f];
        sk = fmaf(kwp[c * 128 + h * 16 + d], ar, sk);
        sv = fmaf(vwp[c * 128 + h * 16 + d], mr, sv);
    }
    unsigned short* W = Wt + (size_t)(l * 4 + et) * 32768;
    W[(size_t)hf * 128 + c]         = f2bf(sk);
    W[(size_t)(128 + hf) * 128 + c] = f2bf(sv);
    if (c == 0) {
        float bk = 0.f, bv = 0.f;
        #pragma unroll
        for (int d = 0; d < 16; ++d) {
            bk = fmaf(kbp[h * 16 + d], arel[(h * 16 + d) * 16 + f], bk);
            bv = fmaf(vbp[h * 16 + d], mrel[(h * 16 + d) * 16 + f], bv);
        }
        float* b = ball + (size_t)(l * 4 + et) * 256;
        b[hf]       = bk;
        b[128 + hf] = bv;
    }
}

// transpose+bf16 qw for all (l,i): qwt[li][n][k] = bf16(qw[li][k][n])
__global__ __launch_bounds__(128) void prep_qw(
    const float* __restrict__ qw, unsigned short* __restrict__ qwt)
{
    int n  = threadIdx.x;    // coalesced read along n
    int k  = blockIdx.x;
    int li = blockIdx.y;
    qwt[(size_t)li * 16384 + (size_t)n * 128 + k] =
        f2bf(qw[(size_t)li * 16384 + (size_t)k * 128 + n]);
}

// ------------------------- CSR build (once per launch) ----------------------
__global__ __launch_bounds__(256) void hist_dst(const int* __restrict__ dst,
                                                int* __restrict__ deg, int E)
{
    int e = blockIdx.x * 256 + threadIdx.x;
    if (e < E) atomicAdd(&deg[dst[e]], 1);
}

__global__ __launch_bounds__(256) void scan_tile(
    const int* __restrict__ deg, int* __restrict__ rowptr,
    int* __restrict__ tileSum, int n)
{
    __shared__ int ls[256];
    int b = blockIdx.x, tid = threadIdx.x;
    int base = b * 1024 + tid * 4;
    int v0 = 0, v1 = 0, v2 = 0, v3 = 0;
    if (base + 3 < n) {
        int4 t = *(const int4*)(deg + base);
        v0 = t.x; v1 = t.y; v2 = t.z; v3 = t.w;
    } else {
        if (base + 0 < n) v0 = deg[base + 0];
        if (base + 1 < n) v1 = deg[base + 1];
        if (base + 2 < n) v2 = deg[base + 2];
        if (base + 3 < n) v3 = deg[base + 3];
    }
    int s = v0 + v1 + v2 + v3;
    ls[tid] = s;
    __syncthreads();
    #pragma unroll
    for (int off = 1; off < 256; off <<= 1) {
        int t = (tid >= off) ? ls[tid - off] : 0;
        __syncthreads();
        ls[tid] += t;
        __syncthreads();
    }
    int run = ls[tid] - s;
    int o0 = run; run += v0;
    int o1 = run; run += v1;
    int o2 = run; run += v2;
    int o3 = run;
    if (base + 3 < n) {
        *(int4*)(rowptr + base) = make_int4(o0, o1, o2, o3);
    } else {
        if (base + 0 < n) rowptr[base + 0] = o0;
        if (base + 1 < n) rowptr[base + 1] = o1;
        if (base + 2 < n) rowptr[base + 2] = o2;
    }
    if (tid == 255) tileSum[b] = ls[255];
}

__global__ __launch_bounds__(64) void scan_tsum(
    int* __restrict__ tileSum, int nt, int* __restrict__ totalOut)
{
    int tid = threadIdx.x;
    int v = (tid < nt) ? tileSum[tid] : 0;
    int orig = v;
    #pragma unroll
    for (int off = 1; off < 64; off <<= 1) {
        int t = __shfl_up(v, off);
        if (tid >= off) v += t;
    }
    if (tid < nt) tileSum[tid] = v - orig;
    if (tid == nt - 1) *totalOut = v;
}

__global__ __launch_bounds__(256) void scan_add(
    int* __restrict__ rowptr, const int* __restrict__ tileSum, int n)
{
    int i = blockIdx.x * 256 + threadIdx.x;
    if (i < n) rowptr[i] += tileSum[i >> 10];
}

__global__ __launch_bounds__(256) void fill_csr(const int* __restrict__ src,
                                                const int* __restrict__ dst,
                                                const int* __restrict__ rowptr,
                                                int* __restrict__ cur,
                                                int* __restrict__ csr_src, int E)
{
    int e = blockIdx.x * 256 + threadIdx.x;
    if (e >= E) return;
    int d = dst[e];
    int pos = atomicAdd(&cur[d], 1);
    csr_src[rowptr[d] + pos] = src[e];
}

// --------------- fused gather-side attention aggregation (bf16 tables) ------
template<bool ACCUM>
__global__ __launch_bounds__(256) void agg_attn_bf(
    const int* __restrict__ rowptr, const int* __restrict__ csr_src,
    const unsigned short* __restrict__ kamv, const unsigned short* __restrict__ qbf,
    const float* __restrict__ prel, float* __restrict__ num,
    int Ndst, int dstOff)
{
    int t = blockIdx.x * 256 + threadIdx.x;
    if (t >= Ndst * 8) return;
    int node = t >> 3, h = t & 7;
    int beg = rowptr[node], end = rowptr[node + 1];
    float m = -INFINITY, l = 0.f;
    float o[16];
    #pragma unroll
    for (int i = 0; i < 16; ++i) o[i] = 0.f;
    if (beg < end) {
        const uint4* qp = (const uint4*)(qbf + (size_t)(dstOff + node) * 128 + h * 16);
        float qf[16];
        up8(qp[0], qf); up8(qp[1], qf + 8);
        float ph = prel[h] * 0.25f;
        int s = csr_src[beg];
        for (int j = beg; j < end; ++j) {
            int sn = (j + 1 < end) ? csr_src[j + 1] : 0;   // prefetch next index
            const uint4* kp = (const uint4*)(kamv + (size_t)s * 256 + h * 16);
            uint4 ku0 = kp[0], ku1 = kp[1];
            uint4 vu0 = kp[16], vu1 = kp[17];   // mv at +128 ushorts = +16 uint4
            float kf[16], vf[16];
            up8(ku0, kf); up8(ku1, kf + 8);
            up8(vu0, vf); up8(vu1, vf + 8);
            float a = 0.f;
            #pragma unroll
            for (int i = 0; i < 16; ++i) a = fmaf(qf[i], kf[i], a);
            a *= ph;
            float mn = fmaxf(m, a);
            float sc = __expf(m - mn);
            float w  = __expf(a - mn);
            l = l * sc + w;
            #pragma unroll
            for (int i = 0; i < 16; ++i) o[i] = o[i] * sc + w * vf[i];
            m = mn; s = sn;
        }
    } else if (ACCUM) {
        return;
    }
    float inv = 1.f / (l + 1e-16f);
    float4* np = (float4*)(num + (size_t)(dstOff + node) * 128 + h * 16);
    #pragma unroll
    for (int jj = 0; jj < 4; ++jj) {
        float4 n;
        if (ACCUM) {
            n = np[jj];
            n.x += inv * o[4*jj+0]; n.y += inv * o[4*jj+1];
            n.z += inv * o[4*jj+2]; n.w += inv * o[4*jj+3];
        } else {
            n = make_float4(inv*o[4*jj+0], inv*o[4*jj+1], inv*o[4*jj+2], inv*o[4*jj+3]);
        }
        np[jj] = n;
    }
}

extern "C" void kernel_launch(void* const* d_in, const int* in_sizes, int n_in,
                              void* d_out, int out_size, void* d_ws, size_t ws_size,
                              hipStream_t stream)
{
    (void)in_sizes; (void)n_in; (void)out_size; (void)ws_size;

    const float* xin[3] = {(const float*)d_in[0], (const float*)d_in[1], (const float*)d_in[2]};
    const int* esrc[4] = {(const int*)d_in[3], (const int*)d_in[5], (const int*)d_in[7], (const int*)d_in[9]};
    const int* edst[4] = {(const int*)d_in[4], (const int*)d_in[6], (const int*)d_in[8], (const int*)d_in[10]};
    const float* lin_w = (const float*)d_in[11];
    const float* lin_b = (const float*)d_in[12];
    const float* kw = (const float*)d_in[13];
    const float* qw = (const float*)d_in[14];
    const float* vw = (const float*)d_in[15];
    const float* aw = (const float*)d_in[16];
    const float* kb = (const float*)d_in[17];
    const float* qb = (const float*)d_in[18];
    const float* vb = (const float*)d_in[19];
    const float* ab = (const float*)d_in[20];
    const float* a_rel = (const float*)d_in[21];
    const float* m_rel = (const float*)d_in[22];
    const float* p_rel = (const float*)d_in[23];
    const float* skip  = (const float*)d_in[24];
    const float* out_w = (const float*)d_in[25];
    const float* out_b = (const float*)d_in[26];

    // workspace (float-index units; ~45.75M floats = 183 MB)
    float* ws = (float*)d_ws;
    float*          xs      = ws;                                   // 12,288,000 f
    float*          num     = ws + 12288000;                        // 12,288,000 f
    unsigned short* xs_bf   = (unsigned short*)(ws + 24576000);     // 12,288,000 h
    unsigned short* q_bf    = (unsigned short*)(ws + 30720000);     // 12,288,000 h
    unsigned short* kamv    = (unsigned short*)(ws + 36864000);     // 15,360,000 h
    unsigned short* Wt      = (unsigned short*)(ws + 44544000);     // 262,144 h
    unsigned short* qwt     = (unsigned short*)(ws + 44675072);     // 98,304 h
    float*          ball    = ws + 44724224;                        // 2,048 f
    int*            deg     = (int*)(ws + 44726272);                // 60,000
    int*            tsum    = (int*)(ws + 44786272);                // 64
    int* rp[4];
    rp[0] = (int*)(ws + 44786336);                                  // 60,004
    rp[1] = (int*)(ws + 44846340);                                  // 60,004
    rp[2] = (int*)(ws + 44906344);                                  // 6,004
    rp[3] = (int*)(ws + 44912348);                                  // 30,004
    int* cs[4];
    cs[0] = (int*)(ws + 44942352);                                  // 200,000
    cs[1] = (int*)(ws + 45142352);                                  // 300,000
    cs[2] = (int*)(ws + 45442352);                                  // 200,000
    cs[3] = (int*)(ws + 45642352);                                  // 100,000

    const int NNv[3] = {30000, 60000, 6000};
    const int OFF[3] = {0, 30000, 90000};
    const int NEv[4] = {200000, 300000, 200000, 100000};
    const int SI[4] = {0, 1, 1, 2};
    const int DI[4] = {1, 1, 2, 0};
    const size_t OUTOFF[3] = {0, (size_t)30000 * 64, (size_t)90000 * 64};

    dim3 blk(256);

    // ---- CSR per edge type (static; reused across layers) ----
    for (int et = 0; et < 4; ++et) {
        int di = DI[et], E = NEv[et], Nd = NNv[di];
        int nt = (Nd + 1023) / 1024;
        hipMemsetAsync(deg, 0, (size_t)Nd * 4, stream);
        hist_dst<<<dim3((E + 255) / 256), blk, 0, stream>>>(edst[et], deg, E);
        scan_tile<<<dim3(nt), blk, 0, stream>>>(deg, rp[et], tsum, Nd);
        scan_tsum<<<dim3(1), dim3(64), 0, stream>>>(tsum, nt, rp[et] + Nd);
        scan_add<<<dim3((Nd + 255) / 256), blk, 0, stream>>>(rp[et], tsum, Nd);
        hipMemsetAsync(deg, 0, (size_t)Nd * 4, stream);
        fill_csr<<<dim3((E + 255) / 256), blk, 0, stream>>>(esrc[et], edst[et], rp[et], deg, cs[et], E);
    }

    // ---- weight prep: folded relation weights (transposed bf16) + qw^T bf16 ----
    fold_rel_all<<<dim3(128, 4, 2), dim3(128), 0, stream>>>(
        kw, kb, vw, vb, a_rel, m_rel, Wt, ball);
    prep_qw<<<dim3(128, 6), dim3(128), 0, stream>>>(qw, qwt);

    // ---- input linear + relu -> xs (fp32) + xs_bf ----
    for (int i = 0; i < 3; ++i) {
        dim3 g(2, (NNv[i] + BM - 1) / BM);
        gemm_k128<1, false, true><<<g, blk, 0, stream>>>(
            xin[i], lin_w + (size_t)i * 16384, lin_b + i * 128,
            nullptr, nullptr, xs + (size_t)OFF[i] * 128,
            xs_bf + (size_t)OFF[i] * 128, 128, 128, NNv[i]);
    }

    for (int l = 0; l < 2; ++l) {
        // Q projection per node type (MFMA, bf16 out)
        for (int i = 0; i < 3; ++i) {
            dim3 g(2, (NNv[i] + 63) / 64);
            gemm_mfma<<<g, blk, 0, stream>>>(
                xs_bf + (size_t)OFF[i] * 128,
                qwt + (size_t)(l * 3 + i) * 16384, qb + (l * 3 + i) * 128,
                q_bf + (size_t)OFF[i] * 128, 128, NNv[i]);
        }

        for (int et = 0; et < 4; ++et) {
            int si = SI[et], di = DI[et];

            // combined ka|mv projection (MFMA, bf16 out): [Nsrc,128] @ [128,256]
            dim3 gs(4, (NNv[si] + 63) / 64);
            gemm_mfma<<<gs, blk, 0, stream>>>(
                xs_bf + (size_t)OFF[si] * 128,
                Wt + (size_t)(l * 4 + et) * 32768, ball + (size_t)(l * 4 + et) * 256,
                kamv, 256, NNv[si]);

            dim3 ga((NNv[di] * 8 + 255) / 256);
            if (et == 1) {
                agg_attn_bf<true><<<ga, blk, 0, stream>>>(
                    rp[et], cs[et], kamv, q_bf,
                    p_rel + (size_t)(l * 4 + et) * 8, num, NNv[di], OFF[di]);
            } else {
                agg_attn_bf<false><<<ga, blk, 0, stream>>>(
                    rp[et], cs[et], kamv, q_bf,
                    p_rel + (size_t)(l * 4 + et) * 8, num, NNv[di], OFF[di]);
            }
        }

        // node update: xs = relu(beta*(gelu(num)@aw+ab) + (1-beta)*xs), + xs_bf
        for (int i = 0; i < 3; ++i) {
            dim3 g(2, (NNv[i] + BM - 1) / BM);
            gemm_k128<2, true, true><<<g, blk, 0, stream>>>(
                num + (size_t)OFF[i] * 128,
                aw + (size_t)(l * 3 + i) * 16384, ab + (l * 3 + i) * 128,
                xs + (size_t)OFF[i] * 128, skip + (l * 3 + i),
                xs + (size_t)OFF[i] * 128, xs_bf + (size_t)OFF[i] * 128,
                128, 128, NNv[i]);
        }
    }

    // ---- output projection (C=128 -> OUT=64, fp32) ----
    float* out = (float*)d_out;
    for (int i = 0; i < 3; ++i) {
        dim3 g(1, (NNv[i] + BM - 1) / BM);
        gemm_k128<0, false, false><<<g, blk, 0, stream>>>(
            xs + (size_t)OFF[i] * 128, out_w, out_b,
            nullptr, nullptr, out + OUTOFF[i], nullptr, 64, 64, NNv[i]);
    }
}

// Round 6
// 1103.128 us; speedup vs baseline: 11.6510x; 1.0146x over previous
//
#include <hip/hip_runtime.h>
#include <cstddef>
#include <cstdint>

// ---------------------------------------------------------------------------
// HGT forward for MI355X. C=128, H=8, D=16, OUT=64, L=2
//   NN = {30000, 60000, 6000}, NE = {200000, 300000, 200000, 100000}
//   ETS = {(0,1),(1,1),(1,2),(2,0)}
// Round-5 changes:
//  * input linear + node-update GEMMs -> no-LDS bf16 MFMA (fp32 A loaded,
//    optional gelu, RNE->bf16 frags; fp32 accumulate; fp32 epilogue).
//    Was: fp32 vector GEMM at 38 TF / 51.7us for road. Output proj stays fp32.
//  * lin_w / aw pre-transposed to bf16 [n][k] alongside qw.
// ---------------------------------------------------------------------------

typedef __attribute__((ext_vector_type(8))) short short8;   // 8 x bf16 (4 VGPR)
typedef __attribute__((ext_vector_type(4))) float floatx4;

__device__ __forceinline__ float gelu_tanh(float x) {
    const float c = 0.7978845608028654f;
    float t = tanhf(c * (x + 0.044715f * x * x * x));
    return 0.5f * x * (1.0f + t);
}

__device__ __forceinline__ unsigned short f2bf(float f) {   // RNE fp32->bf16
    unsigned u = __float_as_uint(f);
    u += 0x7fffu + ((u >> 16) & 1);
    return (unsigned short)(u >> 16);
}

__device__ __forceinline__ void up8(uint4 u, float* f) {    // 8 bf16 -> 8 fp32
    f[0] = __uint_as_float(u.x << 16); f[1] = __uint_as_float(u.x & 0xffff0000u);
    f[2] = __uint_as_float(u.y << 16); f[3] = __uint_as_float(u.y & 0xffff0000u);
    f[4] = __uint_as_float(u.z << 16); f[5] = __uint_as_float(u.z & 0xffff0000u);
    f[6] = __uint_as_float(u.w << 16); f[7] = __uint_as_float(u.w & 0xffff0000u);
}

#define BM 64
#define BN 64
#define BK 16

// ------------------- fp32 GEMM (output projection only) --------------------
__global__ __launch_bounds__(256) void gemm_k128(
    const float* __restrict__ A,
    const float* __restrict__ W, const float* __restrict__ bias,
    float* __restrict__ out, int ldw, int ldo, int N)
{
    __shared__ float As[BK][BM + 4];
    __shared__ float Bs[BK][BN + 4];
    const int tid = threadIdx.x;
    const int tx = tid & 15, ty = tid >> 4;
    const int rowBase = blockIdx.y * BM;
    const int colBase = blockIdx.x * BN;
    const int la_row = tid >> 2;
    const int la_k4  = (tid & 3) << 2;
    const int lb_k   = tid >> 4;
    const int lb_c   = (tid & 15) << 2;
    float acc[4][4] = {};
    for (int k0 = 0; k0 < 128; k0 += BK) {
        int gr = rowBase + la_row;
        float4 av = make_float4(0.f, 0.f, 0.f, 0.f);
        if (gr < N) av = *(const float4*)(A + (size_t)gr * 128 + k0 + la_k4);
        As[la_k4 + 0][la_row] = av.x;
        As[la_k4 + 1][la_row] = av.y;
        As[la_k4 + 2][la_row] = av.z;
        As[la_k4 + 3][la_row] = av.w;
        *(float4*)&Bs[lb_k][lb_c] =
            *(const float4*)(W + (size_t)(k0 + lb_k) * ldw + colBase + lb_c);
        __syncthreads();
        #pragma unroll
        for (int kk = 0; kk < BK; ++kk) {
            float4 a4 = *(const float4*)&As[kk][ty << 2];
            float4 b4 = *(const float4*)&Bs[kk][tx << 2];
            float ar[4] = {a4.x, a4.y, a4.z, a4.w};
            float br[4] = {b4.x, b4.y, b4.z, b4.w};
            #pragma unroll
            for (int i = 0; i < 4; ++i)
                #pragma unroll
                for (int j = 0; j < 4; ++j)
                    acc[i][j] = fmaf(ar[i], br[j], acc[i][j]);
        }
        __syncthreads();
    }
    #pragma unroll
    for (int i = 0; i < 4; ++i) {
        int r = rowBase + (ty << 2) + i;
        if (r < N) {
            #pragma unroll
            for (int j = 0; j < 4; ++j) {
                int c = colBase + (tx << 2) + j;
                out[(size_t)r * ldo + c] = acc[i][j] + bias[c];
            }
        }
    }
}

// ------------------- MFMA bf16 GEMM, bf16 A (attention path) ---------------
// Frag layouts (verified m89/m120): A[m=lane&15][k=quad*8+j],
// B[k=quad*8+j][n=lane&15], D[row=quad*4+reg][col=lane&15].
__global__ __launch_bounds__(256) void gemm_mfma(
    const unsigned short* __restrict__ Abf,
    const unsigned short* __restrict__ Wt,
    const float* __restrict__ bias,
    unsigned short* __restrict__ outbf, int ldo, int Nrows)
{
    const int tid = threadIdx.x;
    const int wave = tid >> 6, lane = tid & 63;
    const int quad = lane >> 4, l16 = lane & 15;
    const int rowBase = blockIdx.y * 64 + wave * 16;
    const int colBase = blockIdx.x * 64;
    int m = rowBase + l16;
    size_t arow = (size_t)((m < Nrows) ? m : 0) * 128;
    const unsigned short* ap = Abf + arow + quad * 8;
    const unsigned short* wp = Wt + (size_t)(colBase + l16) * 128 + quad * 8;
    floatx4 acc[4] = {{0,0,0,0},{0,0,0,0},{0,0,0,0},{0,0,0,0}};
    #pragma unroll
    for (int k0 = 0; k0 < 128; k0 += 32) {
        short8 a = *(const short8*)(ap + k0);
        #pragma unroll
        for (int c = 0; c < 4; ++c) {
            short8 b = *(const short8*)(wp + (size_t)c * 16 * 128 + k0);
            acc[c] = __builtin_amdgcn_mfma_f32_16x16x32_bf16(a, b, acc[c], 0, 0, 0);
        }
    }
    int row0 = rowBase + quad * 4;
    #pragma unroll
    for (int c = 0; c < 4; ++c) {
        int col = colBase + c * 16 + l16;
        float bv = bias[col];
        #pragma unroll
        for (int r = 0; r < 4; ++r) {
            int row = row0 + r;
            if (row < Nrows)
                outbf[(size_t)row * ldo + col] = f2bf(acc[c][r] + bv);
        }
    }
}

// ------------------- MFMA bf16 GEMM, fp32 A (node-state path) --------------
// GIN: gelu(A) before rounding. SKIP: o = beta*o + (1-beta)*xold. relu always.
// Writes fp32 out (ld 128) + bf16 copy (ld 128).
template<bool GIN, bool SKIP>
__global__ __launch_bounds__(256) void gemm_mfma_af32(
    const float* __restrict__ A,
    const unsigned short* __restrict__ Wt,
    const float* __restrict__ bias,
    const float* __restrict__ xold, const float* __restrict__ skipp,
    float* __restrict__ outf, unsigned short* __restrict__ outbf, int Nrows)
{
    const int tid = threadIdx.x;
    const int wave = tid >> 6, lane = tid & 63;
    const int quad = lane >> 4, l16 = lane & 15;
    const int rowBase = blockIdx.y * 64 + wave * 16;
    const int colBase = blockIdx.x * 64;
    int m = rowBase + l16;
    size_t arow = (size_t)((m < Nrows) ? m : 0) * 128;
    const float* ap = A + arow + quad * 8;
    const unsigned short* wp = Wt + (size_t)(colBase + l16) * 128 + quad * 8;
    floatx4 acc[4] = {{0,0,0,0},{0,0,0,0},{0,0,0,0},{0,0,0,0}};
    #pragma unroll
    for (int k0 = 0; k0 < 128; k0 += 32) {
        float4 f0 = *(const float4*)(ap + k0);
        float4 f1 = *(const float4*)(ap + k0 + 4);
        float af[8] = {f0.x, f0.y, f0.z, f0.w, f1.x, f1.y, f1.z, f1.w};
        short8 a;
        #pragma unroll
        for (int i = 0; i < 8; ++i) {
            float v = GIN ? gelu_tanh(af[i]) : af[i];
            a[i] = (short)f2bf(v);
        }
        #pragma unroll
        for (int c = 0; c < 4; ++c) {
            short8 b = *(const short8*)(wp + (size_t)c * 16 * 128 + k0);
            acc[c] = __builtin_amdgcn_mfma_f32_16x16x32_bf16(a, b, acc[c], 0, 0, 0);
        }
    }
    float beta = 0.f, omb = 0.f;
    if (SKIP) { beta = 1.0f / (1.0f + __expf(-skipp[0])); omb = 1.0f - beta; }
    int row0 = rowBase + quad * 4;
    #pragma unroll
    for (int c = 0; c < 4; ++c) {
        int col = colBase + c * 16 + l16;
        float bv = bias[col];
        #pragma unroll
        for (int r = 0; r < 4; ++r) {
            int row = row0 + r;
            if (row < Nrows) {
                float o = acc[c][r] + bv;
                if (SKIP) o = beta * o + omb * xold[(size_t)row * 128 + col];
                o = fmaxf(o, 0.f);
                outf[(size_t)row * 128 + col]  = o;
                outbf[(size_t)row * 128 + col] = f2bf(o);
            }
        }
    }
}

// Fold relation matrices for ALL (layer, edge type): write TRANSPOSED bf16
// Wt[(l*4+et)][n][k]: n in [0,128) = kw@a_rel cols, n in [128,256) = vw@m_rel.
__global__ __launch_bounds__(128) void fold_rel_all(
    const float* __restrict__ kw, const float* __restrict__ kb,
    const float* __restrict__ vw, const float* __restrict__ vb,
    const float* __restrict__ a_rel, const float* __restrict__ m_rel,
    unsigned short* __restrict__ Wt, float* __restrict__ ball)
{
    const int SIv[4] = {0, 1, 1, 2};
    int hf = threadIdx.x;
    int h = hf >> 4, f = hf & 15;
    int c  = blockIdx.x;
    int et = blockIdx.y;
    int l  = blockIdx.z;
    int si = SIv[et];
    const float* kwp  = kw + (size_t)(l * 3 + si) * 16384;
    const float* vwp  = vw + (size_t)(l * 3 + si) * 16384;
    const float* kbp  = kb + (size_t)(l * 3 + si) * 128;
    const float* vbp  = vb + (size_t)(l * 3 + si) * 128;
    const float* arel = a_rel + (size_t)(l * 4 + et) * 2048;
    const float* mrel = m_rel + (size_t)(l * 4 + et) * 2048;
    float sk = 0.f, sv = 0.f;
    #pragma unroll
    for (int d = 0; d < 16; ++d) {
        float ar = arel[(h * 16 + d) * 16 + f];
        float mr = mrel[(h * 16 + d) * 16 + f];
        sk = fmaf(kwp[c * 128 + h * 16 + d], ar, sk);
        sv = fmaf(vwp[c * 128 + h * 16 + d], mr, sv);
    }
    unsigned short* W = Wt + (size_t)(l * 4 + et) * 32768;
    W[(size_t)hf * 128 + c]         = f2bf(sk);
    W[(size_t)(128 + hf) * 128 + c] = f2bf(sv);
    if (c == 0) {
        float bk = 0.f, bv = 0.f;
        #pragma unroll
        for (int d = 0; d < 16; ++d) {
            bk = fmaf(kbp[h * 16 + d], arel[(h * 16 + d) * 16 + f], bk);
            bv = fmaf(vbp[h * 16 + d], mrel[(h * 16 + d) * 16 + f], bv);
        }
        float* b = ball + (size_t)(l * 4 + et) * 256;
        b[hf]       = bk;
        b[128 + hf] = bv;
    }
}

// transpose+bf16 a [nmats][128][128] weight family: wt[mi][n][k] = bf16(w[mi][k][n])
__global__ __launch_bounds__(128) void prep_w(
    const float* __restrict__ w, unsigned short* __restrict__ wt)
{
    int n  = threadIdx.x;
    int k  = blockIdx.x;
    int mi = blockIdx.y;
    wt[(size_t)mi * 16384 + (size_t)n * 128 + k] =
        f2bf(w[(size_t)mi * 16384 + (size_t)k * 128 + n]);
}

// ------------------------- CSR build (once per launch) ----------------------
__global__ __launch_bounds__(256) void hist_dst(const int* __restrict__ dst,
                                                int* __restrict__ deg, int E)
{
    int e = blockIdx.x * 256 + threadIdx.x;
    if (e < E) atomicAdd(&deg[dst[e]], 1);
}

__global__ __launch_bounds__(256) void scan_tile(
    const int* __restrict__ deg, int* __restrict__ rowptr,
    int* __restrict__ tileSum, int n)
{
    __shared__ int ls[256];
    int b = blockIdx.x, tid = threadIdx.x;
    int base = b * 1024 + tid * 4;
    int v0 = 0, v1 = 0, v2 = 0, v3 = 0;
    if (base + 3 < n) {
        int4 t = *(const int4*)(deg + base);
        v0 = t.x; v1 = t.y; v2 = t.z; v3 = t.w;
    } else {
        if (base + 0 < n) v0 = deg[base + 0];
        if (base + 1 < n) v1 = deg[base + 1];
        if (base + 2 < n) v2 = deg[base + 2];
        if (base + 3 < n) v3 = deg[base + 3];
    }
    int s = v0 + v1 + v2 + v3;
    ls[tid] = s;
    __syncthreads();
    #pragma unroll
    for (int off = 1; off < 256; off <<= 1) {
        int t = (tid >= off) ? ls[tid - off] : 0;
        __syncthreads();
        ls[tid] += t;
        __syncthreads();
    }
    int run = ls[tid] - s;
    int o0 = run; run += v0;
    int o1 = run; run += v1;
    int o2 = run; run += v2;
    int o3 = run;
    if (base + 3 < n) {
        *(int4*)(rowptr + base) = make_int4(o0, o1, o2, o3);
    } else {
        if (base + 0 < n) rowptr[base + 0] = o0;
        if (base + 1 < n) rowptr[base + 1] = o1;
        if (base + 2 < n) rowptr[base + 2] = o2;
    }
    if (tid == 255) tileSum[b] = ls[255];
}

__global__ __launch_bounds__(64) void scan_tsum(
    int* __restrict__ tileSum, int nt, int* __restrict__ totalOut)
{
    int tid = threadIdx.x;
    int v = (tid < nt) ? tileSum[tid] : 0;
    int orig = v;
    #pragma unroll
    for (int off = 1; off < 64; off <<= 1) {
        int t = __shfl_up(v, off);
        if (tid >= off) v += t;
    }
    if (tid < nt) tileSum[tid] = v - orig;
    if (tid == nt - 1) *totalOut = v;
}

__global__ __launch_bounds__(256) void scan_add(
    int* __restrict__ rowptr, const int* __restrict__ tileSum, int n)
{
    int i = blockIdx.x * 256 + threadIdx.x;
    if (i < n) rowptr[i] += tileSum[i >> 10];
}

__global__ __launch_bounds__(256) void fill_csr(const int* __restrict__ src,
                                                const int* __restrict__ dst,
                                                const int* __restrict__ rowptr,
                                                int* __restrict__ cur,
                                                int* __restrict__ csr_src, int E)
{
    int e = blockIdx.x * 256 + threadIdx.x;
    if (e >= E) return;
    int d = dst[e];
    int pos = atomicAdd(&cur[d], 1);
    csr_src[rowptr[d] + pos] = src[e];
}

// --------------- fused gather-side attention aggregation (bf16 tables) ------
template<bool ACCUM>
__global__ __launch_bounds__(256) void agg_attn_bf(
    const int* __restrict__ rowptr, const int* __restrict__ csr_src,
    const unsigned short* __restrict__ kamv, const unsigned short* __restrict__ qbf,
    const float* __restrict__ prel, float* __restrict__ num,
    int Ndst, int dstOff)
{
    int t = blockIdx.x * 256 + threadIdx.x;
    if (t >= Ndst * 8) return;
    int node = t >> 3, h = t & 7;
    int beg = rowptr[node], end = rowptr[node + 1];
    float m = -INFINITY, l = 0.f;
    float o[16];
    #pragma unroll
    for (int i = 0; i < 16; ++i) o[i] = 0.f;
    if (beg < end) {
        const uint4* qp = (const uint4*)(qbf + (size_t)(dstOff + node) * 128 + h * 16);
        float qf[16];
        up8(qp[0], qf); up8(qp[1], qf + 8);
        float ph = prel[h] * 0.25f;
        int s = csr_src[beg];
        for (int j = beg; j < end; ++j) {
            int sn = (j + 1 < end) ? csr_src[j + 1] : 0;
            const uint4* kp = (const uint4*)(kamv + (size_t)s * 256 + h * 16);
            uint4 ku0 = kp[0], ku1 = kp[1];
            uint4 vu0 = kp[16], vu1 = kp[17];
            float kf[16], vf[16];
            up8(ku0, kf); up8(ku1, kf + 8);
            up8(vu0, vf); up8(vu1, vf + 8);
            float a = 0.f;
            #pragma unroll
            for (int i = 0; i < 16; ++i) a = fmaf(qf[i], kf[i], a);
            a *= ph;
            float mn = fmaxf(m, a);
            float sc = __expf(m - mn);
            float w  = __expf(a - mn);
            l = l * sc + w;
            #pragma unroll
            for (int i = 0; i < 16; ++i) o[i] = o[i] * sc + w * vf[i];
            m = mn; s = sn;
        }
    } else if (ACCUM) {
        return;
    }
    float inv = 1.f / (l + 1e-16f);
    float4* np = (float4*)(num + (size_t)(dstOff + node) * 128 + h * 16);
    #pragma unroll
    for (int jj = 0; jj < 4; ++jj) {
        float4 n;
        if (ACCUM) {
            n = np[jj];
            n.x += inv * o[4*jj+0]; n.y += inv * o[4*jj+1];
            n.z += inv * o[4*jj+2]; n.w += inv * o[4*jj+3];
        } else {
            n = make_float4(inv*o[4*jj+0], inv*o[4*jj+1], inv*o[4*jj+2], inv*o[4*jj+3]);
        }
        np[jj] = n;
    }
}

extern "C" void kernel_launch(void* const* d_in, const int* in_sizes, int n_in,
                              void* d_out, int out_size, void* d_ws, size_t ws_size,
                              hipStream_t stream)
{
    (void)in_sizes; (void)n_in; (void)out_size; (void)ws_size;

    const float* xin[3] = {(const float*)d_in[0], (const float*)d_in[1], (const float*)d_in[2]};
    const int* esrc[4] = {(const int*)d_in[3], (const int*)d_in[5], (const int*)d_in[7], (const int*)d_in[9]};
    const int* edst[4] = {(const int*)d_in[4], (const int*)d_in[6], (const int*)d_in[8], (const int*)d_in[10]};
    const float* lin_w = (const float*)d_in[11];
    const float* lin_b = (const float*)d_in[12];
    const float* kw = (const float*)d_in[13];
    const float* qw = (const float*)d_in[14];
    const float* vw = (const float*)d_in[15];
    const float* aw = (const float*)d_in[16];
    const float* kb = (const float*)d_in[17];
    const float* qb = (const float*)d_in[18];
    const float* vb = (const float*)d_in[19];
    const float* ab = (const float*)d_in[20];
    const float* a_rel = (const float*)d_in[21];
    const float* m_rel = (const float*)d_in[22];
    const float* p_rel = (const float*)d_in[23];
    const float* skip  = (const float*)d_in[24];
    const float* out_w = (const float*)d_in[25];
    const float* out_b = (const float*)d_in[26];

    // workspace (float-index units; ~45.9M floats = 184 MB)
    float* ws = (float*)d_ws;
    float*          xs      = ws;                                   // 12,288,000 f
    float*          num     = ws + 12288000;                        // 12,288,000 f
    unsigned short* xs_bf   = (unsigned short*)(ws + 24576000);     // 12,288,000 h
    unsigned short* q_bf    = (unsigned short*)(ws + 30720000);     // 12,288,000 h
    unsigned short* kamv    = (unsigned short*)(ws + 36864000);     // 15,360,000 h
    unsigned short* Wt      = (unsigned short*)(ws + 44544000);     // 262,144 h
    unsigned short* qwt     = (unsigned short*)(ws + 44675072);     // 98,304 h
    unsigned short* lwt     = (unsigned short*)(ws + 44724224);     // 49,152 h
    unsigned short* awt     = (unsigned short*)(ws + 44748800);     // 98,304 h
    float*          ball    = ws + 44797952;                        // 2,048 f
    int*            deg     = (int*)(ws + 44800000);                // 60,000
    int*            tsum    = (int*)(ws + 44860000);                // 64
    int* rp[4];
    rp[0] = (int*)(ws + 44860064);                                  // 60,004
    rp[1] = (int*)(ws + 44920068);                                  // 60,004
    rp[2] = (int*)(ws + 44980072);                                  // 6,004
    rp[3] = (int*)(ws + 44986076);                                  // 30,004
    int* cs[4];
    cs[0] = (int*)(ws + 45016080);                                  // 200,000
    cs[1] = (int*)(ws + 45216080);                                  // 300,000
    cs[2] = (int*)(ws + 45516080);                                  // 200,000
    cs[3] = (int*)(ws + 45716080);                                  // 100,000

    const int NNv[3] = {30000, 60000, 6000};
    const int OFF[3] = {0, 30000, 90000};
    const int NEv[4] = {200000, 300000, 200000, 100000};
    const int SI[4] = {0, 1, 1, 2};
    const int DI[4] = {1, 1, 2, 0};
    const size_t OUTOFF[3] = {0, (size_t)30000 * 64, (size_t)90000 * 64};

    dim3 blk(256);

    // ---- CSR per edge type (static; reused across layers) ----
    for (int et = 0; et < 4; ++et) {
        int di = DI[et], E = NEv[et], Nd = NNv[di];
        int nt = (Nd + 1023) / 1024;
        hipMemsetAsync(deg, 0, (size_t)Nd * 4, stream);
        hist_dst<<<dim3((E + 255) / 256), blk, 0, stream>>>(edst[et], deg, E);
        scan_tile<<<dim3(nt), blk, 0, stream>>>(deg, rp[et], tsum, Nd);
        scan_tsum<<<dim3(1), dim3(64), 0, stream>>>(tsum, nt, rp[et] + Nd);
        scan_add<<<dim3((Nd + 255) / 256), blk, 0, stream>>>(rp[et], tsum, Nd);
        hipMemsetAsync(deg, 0, (size_t)Nd * 4, stream);
        fill_csr<<<dim3((E + 255) / 256), blk, 0, stream>>>(esrc[et], edst[et], rp[et], deg, cs[et], E);
    }

    // ---- weight prep: folded rel weights (bf16^T) + qw/lin_w/aw bf16^T ----
    fold_rel_all<<<dim3(128, 4, 2), dim3(128), 0, stream>>>(
        kw, kb, vw, vb, a_rel, m_rel, Wt, ball);
    prep_w<<<dim3(128, 6), dim3(128), 0, stream>>>(qw, qwt);
    prep_w<<<dim3(128, 3), dim3(128), 0, stream>>>(lin_w, lwt);
    prep_w<<<dim3(128, 6), dim3(128), 0, stream>>>(aw, awt);

    // ---- input linear + relu -> xs (fp32) + xs_bf (MFMA) ----
    for (int i = 0; i < 3; ++i) {
        dim3 g(2, (NNv[i] + 63) / 64);
        gemm_mfma_af32<false, false><<<g, blk, 0, stream>>>(
            xin[i], lwt + (size_t)i * 16384, lin_b + i * 128,
            nullptr, nullptr,
            xs + (size_t)OFF[i] * 128, xs_bf + (size_t)OFF[i] * 128, NNv[i]);
    }

    for (int l = 0; l < 2; ++l) {
        // Q projection per node type (MFMA, bf16 out)
        for (int i = 0; i < 3; ++i) {
            dim3 g(2, (NNv[i] + 63) / 64);
            gemm_mfma<<<g, blk, 0, stream>>>(
                xs_bf + (size_t)OFF[i] * 128,
                qwt + (size_t)(l * 3 + i) * 16384, qb + (l * 3 + i) * 128,
                q_bf + (size_t)OFF[i] * 128, 128, NNv[i]);
        }

        for (int et = 0; et < 4; ++et) {
            int si = SI[et], di = DI[et];

            // combined ka|mv projection (MFMA, bf16 out): [Nsrc,128] @ [128,256]
            dim3 gs(4, (NNv[si] + 63) / 64);
            gemm_mfma<<<gs, blk, 0, stream>>>(
                xs_bf + (size_t)OFF[si] * 128,
                Wt + (size_t)(l * 4 + et) * 32768, ball + (size_t)(l * 4 + et) * 256,
                kamv, 256, NNv[si]);

            dim3 ga((NNv[di] * 8 + 255) / 256);
            if (et == 1) {
                agg_attn_bf<true><<<ga, blk, 0, stream>>>(
                    rp[et], cs[et], kamv, q_bf,
                    p_rel + (size_t)(l * 4 + et) * 8, num, NNv[di], OFF[di]);
            } else {
                agg_attn_bf<false><<<ga, blk, 0, stream>>>(
                    rp[et], cs[et], kamv, q_bf,
                    p_rel + (size_t)(l * 4 + et) * 8, num, NNv[di], OFF[di]);
            }
        }

        // node update (MFMA): xs = relu(beta*(gelu(num)@aw+ab) + (1-beta)*xs)
        for (int i = 0; i < 3; ++i) {
            dim3 g(2, (NNv[i] + 63) / 64);
            gemm_mfma_af32<true, true><<<g, blk, 0, stream>>>(
                num + (size_t)OFF[i] * 128,
                awt + (size_t)(l * 3 + i) * 16384, ab + (l * 3 + i) * 128,
                xs + (size_t)OFF[i] * 128, skip + (l * 3 + i),
                xs + (size_t)OFF[i] * 128, xs_bf + (size_t)OFF[i] * 128, NNv[i]);
        }
    }

    // ---- output projection (C=128 -> OUT=64, fp32) ----
    float* out = (float*)d_out;
    for (int i = 0; i < 3; ++i) {
        dim3 g(1, (NNv[i] + BM - 1) / BM);
        gemm_k128<<<g, blk, 0, stream>>>(
            xs + (size_t)OFF[i] * 128, out_w, out_b,
            out + OUTOFF[i], 64, 64, NNv[i]);
    }
}

// Round 7
// 914.417 us; speedup vs baseline: 14.0555x; 1.2064x over previous
//
#include <hip/hip_runtime.h>
#include <cstddef>
#include <cstdint>

// ---------------------------------------------------------------------------
// HGT forward for MI355X. C=128, H=8, D=16, OUT=64, L=2
//   NN = {30000, 60000, 6000}, NE = {200000, 300000, 200000, 100000}
//   ETS = {(0,1),(1,1),(1,2),(2,0)}
// Round-6 changes:
//  * Packed projection: per (layer, src type) ONE GEMM computes [q | ka|mv
//    per outgoing edge type] (road 640 cols, poi/region 384). 7 -> 3
//    GEMMs/layer, road A read once.
//  * B-in-registers streaming MFMA GEMM: wave holds 64col x 128K weights in
//    64 VGPRs, streams 4 row-tiles (64 MFMAs/wave, coalesced A loads).
//  * fp32 xs state dropped (all consumers read bf16); out-proj is bf16 MFMA.
//  * CSR build fused across edge types: 24 -> 7 dispatches.
// ---------------------------------------------------------------------------

typedef __attribute__((ext_vector_type(8))) short short8;   // 8 x bf16
typedef __attribute__((ext_vector_type(4))) float floatx4;

__device__ __forceinline__ float gelu_tanh(float x) {
    const float c = 0.7978845608028654f;
    float t = tanhf(c * (x + 0.044715f * x * x * x));
    return 0.5f * x * (1.0f + t);
}

__device__ __forceinline__ unsigned short f2bf(float f) {   // RNE fp32->bf16
    unsigned u = __float_as_uint(f);
    u += 0x7fffu + ((u >> 16) & 1);
    return (unsigned short)(u >> 16);
}

__device__ __forceinline__ float bf2f(unsigned short h) {
    return __uint_as_float((unsigned)h << 16);
}

__device__ __forceinline__ void up8(uint4 u, float* f) {    // 8 bf16 -> 8 fp32
    f[0] = __uint_as_float(u.x << 16); f[1] = __uint_as_float(u.x & 0xffff0000u);
    f[2] = __uint_as_float(u.y << 16); f[3] = __uint_as_float(u.y & 0xffff0000u);
    f[4] = __uint_as_float(u.z << 16); f[5] = __uint_as_float(u.z & 0xffff0000u);
    f[6] = __uint_as_float(u.w << 16); f[7] = __uint_as_float(u.w & 0xffff0000u);
}

// ------------- B-in-registers streaming MFMA GEMM (bf16 A, bf16 out) -------
// Wt: [ncols][128] bf16 (transposed). Wave: 64 cols, ROWT row-tiles of 16.
// Frag layouts (verified m89): A[m=lane&15][k=quad*8+j],
// B[k=quad*8+j][n=lane&15], D[row=quad*4+reg][col=lane&15].
template<int ROWT>
__global__ __launch_bounds__(256) void gemm_bpack_bf(
    const unsigned short* __restrict__ Abf,
    const unsigned short* __restrict__ Wt,
    const float* __restrict__ bias,
    unsigned short* __restrict__ outbf, int ldo, int Nrows)
{
    const int wave = threadIdx.x >> 6, lane = threadIdx.x & 63;
    const int quad = lane >> 4, l16 = lane & 15;
    const int colBase = blockIdx.x * 64;
    const int rowStart = (blockIdx.y * 4 + wave) * (16 * ROWT);
    const unsigned short* wp = Wt + (size_t)(colBase + l16) * 128 + quad * 8;
    short8 B[4][4];
    #pragma unroll
    for (int c = 0; c < 4; ++c)
        #pragma unroll
        for (int kc = 0; kc < 4; ++kc)
            B[c][kc] = *(const short8*)(wp + (size_t)c * 2048 + kc * 32);
    float bv[4];
    #pragma unroll
    for (int c = 0; c < 4; ++c) bv[c] = bias[colBase + c * 16 + l16];
    #pragma unroll
    for (int rt = 0; rt < ROWT; ++rt) {
        int rowBase = rowStart + rt * 16;
        if (rowBase >= Nrows) break;
        int m = rowBase + l16;
        const unsigned short* ap = Abf + (size_t)((m < Nrows) ? m : 0) * 128 + quad * 8;
        floatx4 acc[4] = {{0,0,0,0},{0,0,0,0},{0,0,0,0},{0,0,0,0}};
        #pragma unroll
        for (int kc = 0; kc < 4; ++kc) {
            short8 a = *(const short8*)(ap + kc * 32);
            #pragma unroll
            for (int c = 0; c < 4; ++c)
                acc[c] = __builtin_amdgcn_mfma_f32_16x16x32_bf16(a, B[c][kc], acc[c], 0, 0, 0);
        }
        int row0 = rowBase + quad * 4;
        #pragma unroll
        for (int c = 0; c < 4; ++c) {
            int col = colBase + c * 16 + l16;
            #pragma unroll
            for (int r = 0; r < 4; ++r) {
                int row = row0 + r;
                if (row < Nrows)
                    outbf[(size_t)row * ldo + col] = f2bf(acc[c][r] + bv[c]);
            }
        }
    }
}

// ------------- same structure, fp32 A (input linear / node update) ---------
// cols fixed 128 (grid.x = 2). GIN: gelu(A). SKIP: o=beta*o+(1-beta)*xold_bf.
// relu always. Writes bf16 only.
template<int ROWT, bool GIN, bool SKIP>
__global__ __launch_bounds__(256) void gemm_bpack_f32a(
    const float* __restrict__ A,
    const unsigned short* __restrict__ Wt,
    const float* __restrict__ bias,
    const unsigned short* __restrict__ xold_bf, const float* __restrict__ skipp,
    unsigned short* __restrict__ outbf, int Nrows)
{
    const int wave = threadIdx.x >> 6, lane = threadIdx.x & 63;
    const int quad = lane >> 4, l16 = lane & 15;
    const int colBase = blockIdx.x * 64;
    const int rowStart = (blockIdx.y * 4 + wave) * (16 * ROWT);
    const unsigned short* wp = Wt + (size_t)(colBase + l16) * 128 + quad * 8;
    short8 B[4][4];
    #pragma unroll
    for (int c = 0; c < 4; ++c)
        #pragma unroll
        for (int kc = 0; kc < 4; ++kc)
            B[c][kc] = *(const short8*)(wp + (size_t)c * 2048 + kc * 32);
    float bv[4];
    #pragma unroll
    for (int c = 0; c < 4; ++c) bv[c] = bias[colBase + c * 16 + l16];
    float beta = 0.f, omb = 0.f;
    if (SKIP) { beta = 1.0f / (1.0f + __expf(-skipp[0])); omb = 1.0f - beta; }
    #pragma unroll
    for (int rt = 0; rt < ROWT; ++rt) {
        int rowBase = rowStart + rt * 16;
        if (rowBase >= Nrows) break;
        int m = rowBase + l16;
        const float* ap = A + (size_t)((m < Nrows) ? m : 0) * 128 + quad * 8;
        floatx4 acc[4] = {{0,0,0,0},{0,0,0,0},{0,0,0,0},{0,0,0,0}};
        #pragma unroll
        for (int kc = 0; kc < 4; ++kc) {
            float4 f0 = *(const float4*)(ap + kc * 32);
            float4 f1 = *(const float4*)(ap + kc * 32 + 4);
            float af[8] = {f0.x, f0.y, f0.z, f0.w, f1.x, f1.y, f1.z, f1.w};
            short8 a;
            #pragma unroll
            for (int i = 0; i < 8; ++i) {
                float v = GIN ? gelu_tanh(af[i]) : af[i];
                a[i] = (short)f2bf(v);
            }
            #pragma unroll
            for (int c = 0; c < 4; ++c)
                acc[c] = __builtin_amdgcn_mfma_f32_16x16x32_bf16(a, B[c][kc], acc[c], 0, 0, 0);
        }
        int row0 = rowBase + quad * 4;
        #pragma unroll
        for (int c = 0; c < 4; ++c) {
            int col = colBase + c * 16 + l16;
            #pragma unroll
            for (int r = 0; r < 4; ++r) {
                int row = row0 + r;
                if (row < Nrows) {
                    float o = acc[c][r] + bv[c];
                    if (SKIP) o = beta * o + omb * bf2f(xold_bf[(size_t)row * 128 + col]);
                    o = fmaxf(o, 0.f);
                    outbf[(size_t)row * 128 + col] = f2bf(o);
                }
            }
        }
    }
}

// ------------- same structure, bf16 A, fp32 out (final projection) ---------
// cols fixed 64 (grid.x = 1), ldo = 64.
template<int ROWT>
__global__ __launch_bounds__(256) void gemm_bpack_out(
    const unsigned short* __restrict__ Abf,
    const unsigned short* __restrict__ Wt,
    const float* __restrict__ bias,
    float* __restrict__ out, int Nrows)
{
    const int wave = threadIdx.x >> 6, lane = threadIdx.x & 63;
    const int quad = lane >> 4, l16 = lane & 15;
    const int rowStart = (blockIdx.y * 4 + wave) * (16 * ROWT);
    const unsigned short* wp = Wt + (size_t)l16 * 128 + quad * 8;
    short8 B[4][4];
    #pragma unroll
    for (int c = 0; c < 4; ++c)
        #pragma unroll
        for (int kc = 0; kc < 4; ++kc)
            B[c][kc] = *(const short8*)(wp + (size_t)c * 2048 + kc * 32);
    float bv[4];
    #pragma unroll
    for (int c = 0; c < 4; ++c) bv[c] = bias[c * 16 + l16];
    #pragma unroll
    for (int rt = 0; rt < ROWT; ++rt) {
        int rowBase = rowStart + rt * 16;
        if (rowBase >= Nrows) break;
        int m = rowBase + l16;
        const unsigned short* ap = Abf + (size_t)((m < Nrows) ? m : 0) * 128 + quad * 8;
        floatx4 acc[4] = {{0,0,0,0},{0,0,0,0},{0,0,0,0},{0,0,0,0}};
        #pragma unroll
        for (int kc = 0; kc < 4; ++kc) {
            short8 a = *(const short8*)(ap + kc * 32);
            #pragma unroll
            for (int c = 0; c < 4; ++c)
                acc[c] = __builtin_amdgcn_mfma_f32_16x16x32_bf16(a, B[c][kc], acc[c], 0, 0, 0);
        }
        int row0 = rowBase + quad * 4;
        #pragma unroll
        for (int c = 0; c < 4; ++c) {
            int col = c * 16 + l16;
            #pragma unroll
            for (int r = 0; r < 4; ++r) {
                int row = row0 + r;
                if (row < Nrows)
                    out[(size_t)row * 64 + col] = acc[c][r] + bv[c];
            }
        }
    }
}

// ------------------------- weight prep -------------------------------------
// Wpack per (l, type): [ncols][128] bf16^T. cols: [q 0:128][ka|mv 256 per et].
// pre (short offsets within a layer's 180224): {0, 49152, 131072}; preB cols.
__global__ __launch_bounds__(128) void prep_qpack(
    const float* __restrict__ qw, const float* __restrict__ qb,
    unsigned short* __restrict__ Wpack, float* __restrict__ bpack)
{
    const int pre[3] = {0, 49152, 131072};
    const int preB[3] = {0, 384, 1024};
    int n = threadIdx.x, k = blockIdx.x, t = blockIdx.y, l = blockIdx.z;
    unsigned short* Wp = Wpack + (size_t)l * 180224 + pre[t];
    Wp[(size_t)n * 128 + k] = f2bf(qw[(size_t)(l * 3 + t) * 16384 + (size_t)k * 128 + n]);
    if (k == 0) bpack[l * 1408 + preB[t] + n] = qb[(l * 3 + t) * 128 + n];
}

__global__ __launch_bounds__(128) void fold_rel_pack(
    const float* __restrict__ kw, const float* __restrict__ kb,
    const float* __restrict__ vw, const float* __restrict__ vb,
    const float* __restrict__ a_rel, const float* __restrict__ m_rel,
    unsigned short* __restrict__ Wpack, float* __restrict__ bpack)
{
    const int SIv[4] = {0, 1, 1, 2};
    const int SLOT[4] = {0, 0, 1, 0};
    const int pre[3] = {0, 49152, 131072};
    const int preB[3] = {0, 384, 1024};
    int hf = threadIdx.x, h = hf >> 4, f = hf & 15;
    int c = blockIdx.x, et = blockIdx.y, l = blockIdx.z;
    int si = SIv[et];
    const float* kwp  = kw + (size_t)(l * 3 + si) * 16384;
    const float* vwp  = vw + (size_t)(l * 3 + si) * 16384;
    const float* kbp  = kb + (size_t)(l * 3 + si) * 128;
    const float* vbp  = vb + (size_t)(l * 3 + si) * 128;
    const float* arel = a_rel + (size_t)(l * 4 + et) * 2048;
    const float* mrel = m_rel + (size_t)(l * 4 + et) * 2048;
    float sk = 0.f, sv = 0.f;
    #pragma unroll
    for (int d = 0; d < 16; ++d) {
        float ar = arel[(h * 16 + d) * 16 + f];
        float mr = mrel[(h * 16 + d) * 16 + f];
        sk = fmaf(kwp[c * 128 + h * 16 + d], ar, sk);
        sv = fmaf(vwp[c * 128 + h * 16 + d], mr, sv);
    }
    int rowoff = 128 + 256 * SLOT[et];
    unsigned short* Wp = Wpack + (size_t)l * 180224 + pre[si];
    Wp[(size_t)(rowoff + hf) * 128 + c]       = f2bf(sk);
    Wp[(size_t)(rowoff + 128 + hf) * 128 + c] = f2bf(sv);
    if (c == 0) {
        float bk = 0.f, bvv = 0.f;
        #pragma unroll
        for (int d = 0; d < 16; ++d) {
            bk  = fmaf(kbp[h * 16 + d], arel[(h * 16 + d) * 16 + f], bk);
            bvv = fmaf(vbp[h * 16 + d], mrel[(h * 16 + d) * 16 + f], bvv);
        }
        float* bp = bpack + l * 1408 + preB[si];
        bp[rowoff + hf]       = bk;
        bp[rowoff + 128 + hf] = bvv;
    }
}

// transpose+bf16 [nmats][128][128] weights: wt[mi][n][k] = bf16(w[mi][k][n])
__global__ __launch_bounds__(128) void prep_w(
    const float* __restrict__ w, unsigned short* __restrict__ wt)
{
    int n = threadIdx.x, k = blockIdx.x, mi = blockIdx.y;
    wt[(size_t)mi * 16384 + (size_t)n * 128 + k] =
        f2bf(w[(size_t)mi * 16384 + (size_t)k * 128 + n]);
}

// out_w [128][64] -> owt [64][128] bf16
__global__ __launch_bounds__(64) void prep_owt(
    const float* __restrict__ ow, unsigned short* __restrict__ owt)
{
    int n = threadIdx.x, k = blockIdx.x;
    owt[(size_t)n * 128 + k] = f2bf(ow[(size_t)k * 64 + n]);
}

// ------------------------- CSR build (fused across edge types) --------------
__global__ __launch_bounds__(256) void hist_all(
    const int* __restrict__ d0, const int* __restrict__ d1,
    const int* __restrict__ d2, const int* __restrict__ d3,
    int* __restrict__ deg4)
{
    const int Ev[4] = {200000, 300000, 200000, 100000};
    int et = blockIdx.y;
    int e = blockIdx.x * 256 + threadIdx.x;
    if (e >= Ev[et]) return;
    const int* d = et == 0 ? d0 : et == 1 ? d1 : et == 2 ? d2 : d3;
    atomicAdd(&deg4[et * 60000 + d[e]], 1);
}

__global__ __launch_bounds__(256) void scan_tile_all(
    const int* __restrict__ deg4,
    int* __restrict__ r0, int* __restrict__ r1, int* __restrict__ r2, int* __restrict__ r3,
    int* __restrict__ tsum4)
{
    const int Ndv[4] = {60000, 60000, 6000, 30000};
    __shared__ int ls[256];
    int et = blockIdx.y;
    int n = Ndv[et];
    const int* deg = deg4 + et * 60000;
    int* rowptr = et == 0 ? r0 : et == 1 ? r1 : et == 2 ? r2 : r3;
    int b = blockIdx.x, tid = threadIdx.x;
    int base = b * 1024 + tid * 4;
    int v0 = 0, v1 = 0, v2 = 0, v3 = 0;
    if (base + 3 < n) {
        int4 t = *(const int4*)(deg + base);
        v0 = t.x; v1 = t.y; v2 = t.z; v3 = t.w;
    } else {
        if (base + 0 < n) v0 = deg[base + 0];
        if (base + 1 < n) v1 = deg[base + 1];
        if (base + 2 < n) v2 = deg[base + 2];
        if (base + 3 < n) v3 = deg[base + 3];
    }
    int s = v0 + v1 + v2 + v3;
    ls[tid] = s;
    __syncthreads();
    #pragma unroll
    for (int off = 1; off < 256; off <<= 1) {
        int t = (tid >= off) ? ls[tid - off] : 0;
        __syncthreads();
        ls[tid] += t;
        __syncthreads();
    }
    int run = ls[tid] - s;
    int o0 = run; run += v0;
    int o1 = run; run += v1;
    int o2 = run; run += v2;
    int o3 = run;
    if (base + 3 < n) {
        *(int4*)(rowptr + base) = make_int4(o0, o1, o2, o3);
    } else {
        if (base + 0 < n) rowptr[base + 0] = o0;
        if (base + 1 < n) rowptr[base + 1] = o1;
        if (base + 2 < n) rowptr[base + 2] = o2;
    }
    if (tid == 255) tsum4[et * 64 + b] = ls[255];
}

__global__ __launch_bounds__(64) void scan_tsum_all(
    int* __restrict__ tsum4,
    int* __restrict__ r0, int* __restrict__ r1, int* __restrict__ r2, int* __restrict__ r3)
{
    const int Ndv[4] = {60000, 60000, 6000, 30000};
    int et = blockIdx.x;
    int n = Ndv[et];
    int nt = (n + 1023) >> 10;
    int* tileSum = tsum4 + et * 64;
    int* rowptr = et == 0 ? r0 : et == 1 ? r1 : et == 2 ? r2 : r3;
    int tid = threadIdx.x;
    int v = (tid < nt) ? tileSum[tid] : 0;
    int orig = v;
    #pragma unroll
    for (int off = 1; off < 64; off <<= 1) {
        int t = __shfl_up(v, off);
        if (tid >= off) v += t;
    }
    if (tid < nt) tileSum[tid] = v - orig;
    if (tid == nt - 1) rowptr[n] = v;
}

__global__ __launch_bounds__(256) void scan_add_all(
    int* __restrict__ r0, int* __restrict__ r1, int* __restrict__ r2, int* __restrict__ r3,
    const int* __restrict__ tsum4)
{
    const int Ndv[4] = {60000, 60000, 6000, 30000};
    int et = blockIdx.y;
    int n = Ndv[et];
    int* rowptr = et == 0 ? r0 : et == 1 ? r1 : et == 2 ? r2 : r3;
    int i = blockIdx.x * 256 + threadIdx.x;
    if (i < n) rowptr[i] += tsum4[et * 64 + (i >> 10)];
}

__global__ __launch_bounds__(256) void fill_all(
    const int* __restrict__ s0, const int* __restrict__ d0,
    const int* __restrict__ s1, const int* __restrict__ d1,
    const int* __restrict__ s2, const int* __restrict__ d2,
    const int* __restrict__ s3, const int* __restrict__ d3,
    const int* __restrict__ r0, const int* __restrict__ r1,
    const int* __restrict__ r2, const int* __restrict__ r3,
    int* __restrict__ deg4,
    int* __restrict__ c0, int* __restrict__ c1, int* __restrict__ c2, int* __restrict__ c3)
{
    const int Ev[4] = {200000, 300000, 200000, 100000};
    int et = blockIdx.y;
    int e = blockIdx.x * 256 + threadIdx.x;
    if (e >= Ev[et]) return;
    const int* src = et == 0 ? s0 : et == 1 ? s1 : et == 2 ? s2 : s3;
    const int* dst = et == 0 ? d0 : et == 1 ? d1 : et == 2 ? d2 : d3;
    const int* rowptr = et == 0 ? r0 : et == 1 ? r1 : et == 2 ? r2 : r3;
    int* csr = et == 0 ? c0 : et == 1 ? c1 : et == 2 ? c2 : c3;
    int d = dst[e];
    int pos = atomicAdd(&deg4[et * 60000 + d], 1);
    csr[rowptr[d] + pos] = src[e];
}

// --------------- fused gather-side attention aggregation (bf16, packed) -----
template<bool ACCUM>
__global__ __launch_bounds__(256) void agg_attn_bf(
    const int* __restrict__ rowptr, const int* __restrict__ csr_src,
    const unsigned short* __restrict__ kamv, int ld_src,     // = P[si] + koff
    const unsigned short* __restrict__ qt, int ld_dst,       // = P[di]
    const float* __restrict__ prel, float* __restrict__ num,
    int Ndst, int dstOff)
{
    int t = blockIdx.x * 256 + threadIdx.x;
    if (t >= Ndst * 8) return;
    int node = t >> 3, h = t & 7;
    int beg = rowptr[node], end = rowptr[node + 1];
    float m = -INFINITY, l = 0.f;
    float o[16];
    #pragma unroll
    for (int i = 0; i < 16; ++i) o[i] = 0.f;
    if (beg < end) {
        const uint4* qp = (const uint4*)(qt + (size_t)node * ld_dst + h * 16);
        float qf[16];
        up8(qp[0], qf); up8(qp[1], qf + 8);
        float ph = prel[h] * 0.25f;
        int s = csr_src[beg];
        for (int j = beg; j < end; ++j) {
            int sn = (j + 1 < end) ? csr_src[j + 1] : 0;
            const uint4* kp = (const uint4*)(kamv + (size_t)s * ld_src + h * 16);
            uint4 ku0 = kp[0], ku1 = kp[1];
            uint4 vu0 = kp[16], vu1 = kp[17];   // mv at +128 shorts
            float kf[16], vf[16];
            up8(ku0, kf); up8(ku1, kf + 8);
            up8(vu0, vf); up8(vu1, vf + 8);
            float a = 0.f;
            #pragma unroll
            for (int i = 0; i < 16; ++i) a = fmaf(qf[i], kf[i], a);
            a *= ph;
            float mn = fmaxf(m, a);
            float sc = __expf(m - mn);
            float w  = __expf(a - mn);
            l = l * sc + w;
            #pragma unroll
            for (int i = 0; i < 16; ++i) o[i] = o[i] * sc + w * vf[i];
            m = mn; s = sn;
        }
    } else if (ACCUM) {
        return;
    }
    float inv = 1.f / (l + 1e-16f);
    float4* np = (float4*)(num + (size_t)(dstOff + node) * 128 + h * 16);
    #pragma unroll
    for (int jj = 0; jj < 4; ++jj) {
        float4 n;
        if (ACCUM) {
            n = np[jj];
            n.x += inv * o[4*jj+0]; n.y += inv * o[4*jj+1];
            n.z += inv * o[4*jj+2]; n.w += inv * o[4*jj+3];
        } else {
            n = make_float4(inv*o[4*jj+0], inv*o[4*jj+1], inv*o[4*jj+2], inv*o[4*jj+3]);
        }
        np[jj] = n;
    }
}

extern "C" void kernel_launch(void* const* d_in, const int* in_sizes, int n_in,
                              void* d_out, int out_size, void* d_ws, size_t ws_size,
                              hipStream_t stream)
{
    (void)in_sizes; (void)n_in; (void)out_size; (void)ws_size;

    const float* xin[3] = {(const float*)d_in[0], (const float*)d_in[1], (const float*)d_in[2]};
    const int* esrc[4] = {(const int*)d_in[3], (const int*)d_in[5], (const int*)d_in[7], (const int*)d_in[9]};
    const int* edst[4] = {(const int*)d_in[4], (const int*)d_in[6], (const int*)d_in[8], (const int*)d_in[10]};
    const float* lin_w = (const float*)d_in[11];
    const float* lin_b = (const float*)d_in[12];
    const float* kw = (const float*)d_in[13];
    const float* qw = (const float*)d_in[14];
    const float* vw = (const float*)d_in[15];
    const float* aw = (const float*)d_in[16];
    const float* kb = (const float*)d_in[17];
    const float* qb = (const float*)d_in[18];
    const float* vb = (const float*)d_in[19];
    const float* ab = (const float*)d_in[20];
    const float* a_rel = (const float*)d_in[21];
    const float* m_rel = (const float*)d_in[22];
    const float* p_rel = (const float*)d_in[23];
    const float* skip  = (const float*)d_in[24];
    const float* out_w = (const float*)d_in[25];
    const float* out_b = (const float*)d_in[26];

    // workspace (float-index units; ~46.0M floats = 184 MB)
    float* ws = (float*)d_ws;
    float*          num   = ws;                                 // 12,288,000 f
    unsigned short* xs_bf = (unsigned short*)(ws + 12288000);   // 12,288,000 h
    unsigned short* proj  = (unsigned short*)(ws + 18432000);   // 52,224,000 h
    unsigned short* Wpack = (unsigned short*)(ws + 44544000);   // 360,448 h
    unsigned short* lwt   = (unsigned short*)(ws + 44724224);   // 49,152 h
    unsigned short* awt   = (unsigned short*)(ws + 44748800);   // 98,304 h
    unsigned short* owt   = (unsigned short*)(ws + 44797952);   // 8,192 h
    float*          bpack = ws + 44802048;                      // 2,816 f
    int*            deg4  = (int*)(ws + 44804864);              // 240,000
    int*            tsum4 = (int*)(ws + 45044864);              // 256
    int* rp[4];
    rp[0] = (int*)(ws + 45045120);                              // 60,008
    rp[1] = (int*)(ws + 45105128);
    rp[2] = (int*)(ws + 45165136);                              // 6,008
    rp[3] = (int*)(ws + 45171144);                              // 30,008
    int* cs[4];
    cs[0] = (int*)(ws + 45201152);                              // 200,000
    cs[1] = (int*)(ws + 45401152);                              // 300,000
    cs[2] = (int*)(ws + 45701152);                              // 200,000
    cs[3] = (int*)(ws + 45901152);                              // 100,000

    const int NNv[3] = {30000, 60000, 6000};
    const int OFF[3] = {0, 30000, 90000};
    const int SI[4] = {0, 1, 1, 2};
    const int DI[4] = {1, 1, 2, 0};
    const int NCOLS[3] = {384, 640, 384};
    const int KOFF[4] = {128, 128, 384, 128};
    const size_t OUTOFF[3] = {0, (size_t)30000 * 64, (size_t)90000 * 64};
    // packed proj buffers per type
    unsigned short* P[3];
    P[0] = proj;
    P[1] = proj + (size_t)30000 * 384;
    P[2] = proj + (size_t)30000 * 384 + (size_t)60000 * 640;
    // packed weight offsets (shorts / floats within a layer)
    const int WPRE[3] = {0, 49152, 131072};   // unused directly; kept for doc

    dim3 blk(256);

    // ---- CSR build, fused across edge types ----
    hipMemsetAsync(deg4, 0, 960000, stream);
    hist_all<<<dim3(1172, 4), blk, 0, stream>>>(edst[0], edst[1], edst[2], edst[3], deg4);
    scan_tile_all<<<dim3(59, 4), blk, 0, stream>>>(deg4, rp[0], rp[1], rp[2], rp[3], tsum4);
    scan_tsum_all<<<dim3(4), dim3(64), 0, stream>>>(tsum4, rp[0], rp[1], rp[2], rp[3]);
    scan_add_all<<<dim3(235, 4), blk, 0, stream>>>(rp[0], rp[1], rp[2], rp[3], tsum4);
    hipMemsetAsync(deg4, 0, 960000, stream);
    fill_all<<<dim3(1172, 4), blk, 0, stream>>>(
        esrc[0], edst[0], esrc[1], edst[1], esrc[2], edst[2], esrc[3], edst[3],
        rp[0], rp[1], rp[2], rp[3], deg4, cs[0], cs[1], cs[2], cs[3]);

    // ---- weight prep ----
    prep_qpack<<<dim3(128, 3, 2), dim3(128), 0, stream>>>(qw, qb, Wpack, bpack);
    fold_rel_pack<<<dim3(128, 4, 2), dim3(128), 0, stream>>>(
        kw, kb, vw, vb, a_rel, m_rel, Wpack, bpack);
    prep_w<<<dim3(128, 3), dim3(128), 0, stream>>>(lin_w, lwt);
    prep_w<<<dim3(128, 6), dim3(128), 0, stream>>>(aw, awt);
    prep_owt<<<dim3(128), dim3(64), 0, stream>>>(out_w, owt);

    // ---- input linear + relu -> xs_bf ----
    for (int i = 0; i < 3; ++i) {
        dim3 g(2, (NNv[i] + 255) / 256);
        gemm_bpack_f32a<4, false, false><<<g, blk, 0, stream>>>(
            xin[i], lwt + (size_t)i * 16384, lin_b + i * 128,
            nullptr, nullptr, xs_bf + (size_t)OFF[i] * 128, NNv[i]);
    }

    for (int l = 0; l < 2; ++l) {
        // packed projection per node type: [q | ka|mv ...]
        for (int i = 0; i < 3; ++i) {
            dim3 g(NCOLS[i] / 64, (NNv[i] + 255) / 256);
            gemm_bpack_bf<4><<<g, blk, 0, stream>>>(
                xs_bf + (size_t)OFF[i] * 128,
                Wpack + (size_t)l * 180224 + (i == 0 ? 0 : i == 1 ? 49152 : 131072),
                bpack + l * 1408 + (i == 0 ? 0 : i == 1 ? 384 : 1024),
                P[i], NCOLS[i], NNv[i]);
        }

        for (int et = 0; et < 4; ++et) {
            int si = SI[et], di = DI[et];
            dim3 ga((NNv[di] * 8 + 255) / 256);
            if (et == 1) {
                agg_attn_bf<true><<<ga, blk, 0, stream>>>(
                    rp[et], cs[et], P[si] + KOFF[et], NCOLS[si], P[di], NCOLS[di],
                    p_rel + (size_t)(l * 4 + et) * 8, num, NNv[di], OFF[di]);
            } else {
                agg_attn_bf<false><<<ga, blk, 0, stream>>>(
                    rp[et], cs[et], P[si] + KOFF[et], NCOLS[si], P[di], NCOLS[di],
                    p_rel + (size_t)(l * 4 + et) * 8, num, NNv[di], OFF[di]);
            }
        }

        // node update: xs_bf = bf16(relu(beta*(gelu(num)@aw+ab) + (1-beta)*xs_bf))
        for (int i = 0; i < 3; ++i) {
            dim3 g(2, (NNv[i] + 255) / 256);
            gemm_bpack_f32a<4, true, true><<<g, blk, 0, stream>>>(
                num + (size_t)OFF[i] * 128,
                awt + (size_t)(l * 3 + i) * 16384, ab + (l * 3 + i) * 128,
                xs_bf + (size_t)OFF[i] * 128, skip + (l * 3 + i),
                xs_bf + (size_t)OFF[i] * 128, NNv[i]);
        }
    }

    // ---- output projection (bf16 MFMA, fp32 out) ----
    float* out = (float*)d_out;
    for (int i = 0; i < 3; ++i) {
        dim3 g(1, (NNv[i] + 255) / 256);
        gemm_bpack_out<4><<<g, blk, 0, stream>>>(
            xs_bf + (size_t)OFF[i] * 128, owt, out_b, out + OUTOFF[i], NNv[i]);
    }
    (void)WPRE;
}

// Round 8
// 769.092 us; speedup vs baseline: 16.7114x; 1.1890x over previous
//
#include <hip/hip_runtime.h>
#include <cstddef>
#include <cstdint>

// ---------------------------------------------------------------------------
// HGT forward for MI355X. C=128, H=8, D=16, OUT=64, L=2
//   NN = {30000, 60000, 6000}, NE = {200000, 300000, 200000, 100000}
//   ETS = {(0,1),(1,1),(1,2),(2,0)}
// Round-8 changes:
//  * A-resident GEMM: block owns 128-row stripe, A frags in registers ONCE,
//    loops col-tiles (was: A re-read per 64-col tile -> 61MB fetch on road).
//  * num stored bf16 (agg writes bf16; update GEMM upconverts + gelu).
//  * Fused per-type dispatches: input 3->1, update 3->1/layer, out-proj 3->1.
//  * agg et2 (region, deg 33): 2-way edge split + shuffle online-softmax merge.
// ---------------------------------------------------------------------------

typedef __attribute__((ext_vector_type(8))) short short8;   // 8 x bf16
typedef __attribute__((ext_vector_type(4))) float floatx4;

__device__ __forceinline__ float gelu_tanh(float x) {
    const float c = 0.7978845608028654f;
    float t = tanhf(c * (x + 0.044715f * x * x * x));
    return 0.5f * x * (1.0f + t);
}

__device__ __forceinline__ unsigned short f2bf(float f) {   // RNE fp32->bf16
    unsigned u = __float_as_uint(f);
    u += 0x7fffu + ((u >> 16) & 1);
    return (unsigned short)(u >> 16);
}

__device__ __forceinline__ float bf2f(unsigned short h) {
    return __uint_as_float((unsigned)h << 16);
}

__device__ __forceinline__ void up8(uint4 u, float* f) {    // 8 bf16 -> 8 fp32
    f[0] = __uint_as_float(u.x << 16); f[1] = __uint_as_float(u.x & 0xffff0000u);
    f[2] = __uint_as_float(u.y << 16); f[3] = __uint_as_float(u.y & 0xffff0000u);
    f[4] = __uint_as_float(u.z << 16); f[5] = __uint_as_float(u.z & 0xffff0000u);
    f[6] = __uint_as_float(u.w << 16); f[7] = __uint_as_float(u.w & 0xffff0000u);
}

__device__ __forceinline__ uint4 pk8(const float* f) {      // 8 fp32 -> 8 bf16
    uint4 u;
    u.x = (unsigned)f2bf(f[0]) | ((unsigned)f2bf(f[1]) << 16);
    u.y = (unsigned)f2bf(f[2]) | ((unsigned)f2bf(f[3]) << 16);
    u.z = (unsigned)f2bf(f[4]) | ((unsigned)f2bf(f[5]) << 16);
    u.w = (unsigned)f2bf(f[6]) | ((unsigned)f2bf(f[7]) << 16);
    return u;
}

// ---------------- A-resident streaming MFMA GEMM (packed proj) -------------
// Block: 4 waves x 32 rows = 128 rows. A frags loaded ONCE into regs, then
// loop over this block's col-tile share. Frag layouts (verified m89):
// A[m=lane&15][k=quad*8+j], B[k=quad*8+j][n=lane&15], D[row=quad*4+reg][col=lane&15].
__global__ __launch_bounds__(256) void gemm_proj(
    const unsigned short* __restrict__ Abf,
    const unsigned short* __restrict__ Wt,
    const float* __restrict__ bias,
    unsigned short* __restrict__ outbf, int ldo, int Nrows, int cpb, int nct)
{
    const int wave = threadIdx.x >> 6, lane = threadIdx.x & 63;
    const int quad = lane >> 4, l16 = lane & 15;
    const int rowStart = (blockIdx.y * 4 + wave) * 32;
    if (rowStart >= Nrows) return;
    short8 Afr[2][4];
    #pragma unroll
    for (int rt = 0; rt < 2; ++rt) {
        int m = rowStart + rt * 16 + l16;
        const unsigned short* ap = Abf + (size_t)((m < Nrows) ? m : 0) * 128 + quad * 8;
        #pragma unroll
        for (int kc = 0; kc < 4; ++kc)
            Afr[rt][kc] = *(const short8*)(ap + kc * 32);
    }
    int ct1 = blockIdx.x * cpb + cpb;
    if (ct1 > nct) ct1 = nct;
    for (int ct = blockIdx.x * cpb; ct < ct1; ++ct) {
        int colBase = ct * 64;
        const unsigned short* wp = Wt + (size_t)(colBase + l16) * 128 + quad * 8;
        short8 B[4][4];
        #pragma unroll
        for (int c = 0; c < 4; ++c)
            #pragma unroll
            for (int kc = 0; kc < 4; ++kc)
                B[c][kc] = *(const short8*)(wp + (size_t)c * 2048 + kc * 32);
        floatx4 acc[2][4] = {{{0,0,0,0},{0,0,0,0},{0,0,0,0},{0,0,0,0}},
                             {{0,0,0,0},{0,0,0,0},{0,0,0,0},{0,0,0,0}}};
        #pragma unroll
        for (int kc = 0; kc < 4; ++kc)
            #pragma unroll
            for (int c = 0; c < 4; ++c) {
                acc[0][c] = __builtin_amdgcn_mfma_f32_16x16x32_bf16(Afr[0][kc], B[c][kc], acc[0][c], 0, 0, 0);
                acc[1][c] = __builtin_amdgcn_mfma_f32_16x16x32_bf16(Afr[1][kc], B[c][kc], acc[1][c], 0, 0, 0);
            }
        #pragma unroll
        for (int rt = 0; rt < 2; ++rt) {
            int row0 = rowStart + rt * 16 + quad * 4;
            #pragma unroll
            for (int c = 0; c < 4; ++c) {
                int col = colBase + c * 16 + l16;
                float bv = bias[col];
                #pragma unroll
                for (int r = 0; r < 4; ++r) {
                    int row = row0 + r;
                    if (row < Nrows)
                        outbf[(size_t)row * ldo + col] = f2bf(acc[rt][c][r] + bv);
                }
            }
        }
    }
}

// ---------------- fused-by-type node GEMM (input linear / node update) -----
// 1-D grid of 751 blocks covering poi(235)/road(469)/region(47) stripes.
// ncols fixed 128. AF32: A fp32. GIN: gelu on A. SKIP: skip-combine. relu always.
template<bool AF32, bool GIN, bool SKIP>
__global__ __launch_bounds__(256) void gemm_node(
    const void* __restrict__ a0v, const void* __restrict__ a1v, const void* __restrict__ a2v,
    const unsigned short* __restrict__ WtB, const float* __restrict__ biasB,
    const unsigned short* __restrict__ xoldB, const float* __restrict__ skipB,
    unsigned short* __restrict__ outB)
{
    const int TN[3]   = {30000, 60000, 6000};
    const int TOFF[3] = {0, 30000, 90000};
    int by = blockIdx.x;
    int t  = (by < 235) ? 0 : (by < 704) ? 1 : 2;
    int lb = by - ((t == 0) ? 0 : (t == 1) ? 235 : 704);
    int Nrows = TN[t];
    const void* av = (t == 0) ? a0v : (t == 1) ? a1v : a2v;
    const unsigned short* Wt = WtB + (size_t)t * 16384;
    const float* bias = biasB + t * 128;
    const unsigned short* xold = xoldB + (size_t)TOFF[t] * 128;
    unsigned short* out = outB + (size_t)TOFF[t] * 128;
    const int wave = threadIdx.x >> 6, lane = threadIdx.x & 63;
    const int quad = lane >> 4, l16 = lane & 15;
    const int rowStart = (lb * 4 + wave) * 32;
    if (rowStart >= Nrows) return;
    short8 Afr[2][4];
    #pragma unroll
    for (int rt = 0; rt < 2; ++rt) {
        int m = rowStart + rt * 16 + l16;
        size_t base = (size_t)((m < Nrows) ? m : 0) * 128 + quad * 8;
        #pragma unroll
        for (int kc = 0; kc < 4; ++kc) {
            if (AF32) {
                const float* ap = (const float*)av + base;
                float4 f0 = *(const float4*)(ap + kc * 32);
                float4 f1 = *(const float4*)(ap + kc * 32 + 4);
                float af[8] = {f0.x, f0.y, f0.z, f0.w, f1.x, f1.y, f1.z, f1.w};
                short8 a;
                #pragma unroll
                for (int i = 0; i < 8; ++i) a[i] = (short)f2bf(af[i]);
                Afr[rt][kc] = a;
            } else if (GIN) {
                const unsigned short* ap = (const unsigned short*)av + base;
                short8 a8 = *(const short8*)(ap + kc * 32);
                short8 a;
                #pragma unroll
                for (int i = 0; i < 8; ++i)
                    a[i] = (short)f2bf(gelu_tanh(bf2f((unsigned short)a8[i])));
                Afr[rt][kc] = a;
            } else {
                const unsigned short* ap = (const unsigned short*)av + base;
                Afr[rt][kc] = *(const short8*)(ap + kc * 32);
            }
        }
    }
    float beta = 0.f, omb = 0.f;
    if (SKIP) { beta = 1.0f / (1.0f + __expf(-skipB[t])); omb = 1.0f - beta; }
    #pragma unroll
    for (int ct = 0; ct < 2; ++ct) {
        int colBase = ct * 64;
        const unsigned short* wp = Wt + (size_t)(colBase + l16) * 128 + quad * 8;
        short8 B[4][4];
        #pragma unroll
        for (int c = 0; c < 4; ++c)
            #pragma unroll
            for (int kc = 0; kc < 4; ++kc)
                B[c][kc] = *(const short8*)(wp + (size_t)c * 2048 + kc * 32);
        floatx4 acc[2][4] = {{{0,0,0,0},{0,0,0,0},{0,0,0,0},{0,0,0,0}},
                             {{0,0,0,0},{0,0,0,0},{0,0,0,0},{0,0,0,0}}};
        #pragma unroll
        for (int kc = 0; kc < 4; ++kc)
            #pragma unroll
            for (int c = 0; c < 4; ++c) {
                acc[0][c] = __builtin_amdgcn_mfma_f32_16x16x32_bf16(Afr[0][kc], B[c][kc], acc[0][c], 0, 0, 0);
                acc[1][c] = __builtin_amdgcn_mfma_f32_16x16x32_bf16(Afr[1][kc], B[c][kc], acc[1][c], 0, 0, 0);
            }
        #pragma unroll
        for (int rt = 0; rt < 2; ++rt) {
            int row0 = rowStart + rt * 16 + quad * 4;
            #pragma unroll
            for (int c = 0; c < 4; ++c) {
                int col = colBase + c * 16 + l16;
                float bv = bias[col];
                #pragma unroll
                for (int r = 0; r < 4; ++r) {
                    int row = row0 + r;
                    if (row < Nrows) {
                        float o = acc[rt][c][r] + bv;
                        if (SKIP) o = beta * o + omb * bf2f(xold[(size_t)row * 128 + col]);
                        o = fmaxf(o, 0.f);
                        out[(size_t)row * 128 + col] = f2bf(o);
                    }
                }
            }
        }
    }
}

// ---------------- output projection: one GEMM over all 96000 rows ----------
__global__ __launch_bounds__(256) void gemm_out(
    const unsigned short* __restrict__ Abf,
    const unsigned short* __restrict__ Wt,     // [64][128] bf16^T
    const float* __restrict__ bias,
    float* __restrict__ out, int Nrows)
{
    const int wave = threadIdx.x >> 6, lane = threadIdx.x & 63;
    const int quad = lane >> 4, l16 = lane & 15;
    const int rowStart = (blockIdx.x * 4 + wave) * 32;
    if (rowStart >= Nrows) return;
    const unsigned short* wp = Wt + (size_t)l16 * 128 + quad * 8;
    short8 B[4][4];
    #pragma unroll
    for (int c = 0; c < 4; ++c)
        #pragma unroll
        for (int kc = 0; kc < 4; ++kc)
            B[c][kc] = *(const short8*)(wp + (size_t)c * 2048 + kc * 32);
    #pragma unroll
    for (int rt = 0; rt < 2; ++rt) {
        int rowBase = rowStart + rt * 16;
        int m = rowBase + l16;
        const unsigned short* ap = Abf + (size_t)((m < Nrows) ? m : 0) * 128 + quad * 8;
        floatx4 acc[4] = {{0,0,0,0},{0,0,0,0},{0,0,0,0},{0,0,0,0}};
        #pragma unroll
        for (int kc = 0; kc < 4; ++kc) {
            short8 a = *(const short8*)(ap + kc * 32);
            #pragma unroll
            for (int c = 0; c < 4; ++c)
                acc[c] = __builtin_amdgcn_mfma_f32_16x16x32_bf16(a, B[c][kc], acc[c], 0, 0, 0);
        }
        int row0 = rowBase + quad * 4;
        #pragma unroll
        for (int c = 0; c < 4; ++c) {
            int col = c * 16 + l16;
            float bv = bias[col];
            #pragma unroll
            for (int r = 0; r < 4; ++r) {
                int row = row0 + r;
                if (row < Nrows)
                    out[(size_t)row * 64 + col] = acc[c][r] + bv;
            }
        }
    }
}

// ------------------------- weight prep -------------------------------------
__global__ __launch_bounds__(128) void prep_qpack(
    const float* __restrict__ qw, const float* __restrict__ qb,
    unsigned short* __restrict__ Wpack, float* __restrict__ bpack)
{
    const int pre[3] = {0, 49152, 131072};
    const int preB[3] = {0, 384, 1024};
    int n = threadIdx.x, k = blockIdx.x, t = blockIdx.y, l = blockIdx.z;
    unsigned short* Wp = Wpack + (size_t)l * 180224 + pre[t];
    Wp[(size_t)n * 128 + k] = f2bf(qw[(size_t)(l * 3 + t) * 16384 + (size_t)k * 128 + n]);
    if (k == 0) bpack[l * 1408 + preB[t] + n] = qb[(l * 3 + t) * 128 + n];
}

__global__ __launch_bounds__(128) void fold_rel_pack(
    const float* __restrict__ kw, const float* __restrict__ kb,
    const float* __restrict__ vw, const float* __restrict__ vb,
    const float* __restrict__ a_rel, const float* __restrict__ m_rel,
    unsigned short* __restrict__ Wpack, float* __restrict__ bpack)
{
    const int SIv[4] = {0, 1, 1, 2};
    const int SLOT[4] = {0, 0, 1, 0};
    const int pre[3] = {0, 49152, 131072};
    const int preB[3] = {0, 384, 1024};
    int hf = threadIdx.x, h = hf >> 4, f = hf & 15;
    int c = blockIdx.x, et = blockIdx.y, l = blockIdx.z;
    int si = SIv[et];
    const float* kwp  = kw + (size_t)(l * 3 + si) * 16384;
    const float* vwp  = vw + (size_t)(l * 3 + si) * 16384;
    const float* kbp  = kb + (size_t)(l * 3 + si) * 128;
    const float* vbp  = vb + (size_t)(l * 3 + si) * 128;
    const float* arel = a_rel + (size_t)(l * 4 + et) * 2048;
    const float* mrel = m_rel + (size_t)(l * 4 + et) * 2048;
    float sk = 0.f, sv = 0.f;
    #pragma unroll
    for (int d = 0; d < 16; ++d) {
        float ar = arel[(h * 16 + d) * 16 + f];
        float mr = mrel[(h * 16 + d) * 16 + f];
        sk = fmaf(kwp[c * 128 + h * 16 + d], ar, sk);
        sv = fmaf(vwp[c * 128 + h * 16 + d], mr, sv);
    }
    int rowoff = 128 + 256 * SLOT[et];
    unsigned short* Wp = Wpack + (size_t)l * 180224 + pre[si];
    Wp[(size_t)(rowoff + hf) * 128 + c]       = f2bf(sk);
    Wp[(size_t)(rowoff + 128 + hf) * 128 + c] = f2bf(sv);
    if (c == 0) {
        float bk = 0.f, bvv = 0.f;
        #pragma unroll
        for (int d = 0; d < 16; ++d) {
            bk  = fmaf(kbp[h * 16 + d], arel[(h * 16 + d) * 16 + f], bk);
            bvv = fmaf(vbp[h * 16 + d], mrel[(h * 16 + d) * 16 + f], bvv);
        }
        float* bp = bpack + l * 1408 + preB[si];
        bp[rowoff + hf]       = bk;
        bp[rowoff + 128 + hf] = bvv;
    }
}

// lin_w (3 mats) + aw (6 mats) transposed bf16 in one launch
__global__ __launch_bounds__(128) void prep_w9(
    const float* __restrict__ lin_w, const float* __restrict__ aw,
    unsigned short* __restrict__ lwt, unsigned short* __restrict__ awt)
{
    int n = threadIdx.x, k = blockIdx.x, mi = blockIdx.y;
    const float* w; unsigned short* wt; int m;
    if (mi < 3) { w = lin_w; wt = lwt; m = mi; }
    else        { w = aw;    wt = awt; m = mi - 3; }
    wt[(size_t)m * 16384 + (size_t)n * 128 + k] =
        f2bf(w[(size_t)m * 16384 + (size_t)k * 128 + n]);
}

__global__ __launch_bounds__(64) void prep_owt(
    const float* __restrict__ ow, unsigned short* __restrict__ owt)
{
    int n = threadIdx.x, k = blockIdx.x;
    owt[(size_t)n * 128 + k] = f2bf(ow[(size_t)k * 64 + n]);
}

// ------------------------- CSR build (fused across edge types) --------------
__global__ __launch_bounds__(256) void hist_all(
    const int* __restrict__ d0, const int* __restrict__ d1,
    const int* __restrict__ d2, const int* __restrict__ d3,
    int* __restrict__ deg4)
{
    const int Ev[4] = {200000, 300000, 200000, 100000};
    int et = blockIdx.y;
    int e = blockIdx.x * 256 + threadIdx.x;
    if (e >= Ev[et]) return;
    const int* d = et == 0 ? d0 : et == 1 ? d1 : et == 2 ? d2 : d3;
    atomicAdd(&deg4[et * 60000 + d[e]], 1);
}

__global__ __launch_bounds__(256) void scan_tile_all(
    const int* __restrict__ deg4,
    int* __restrict__ r0, int* __restrict__ r1, int* __restrict__ r2, int* __restrict__ r3,
    int* __restrict__ tsum4)
{
    const int Ndv[4] = {60000, 60000, 6000, 30000};
    __shared__ int ls[256];
    int et = blockIdx.y;
    int n = Ndv[et];
    const int* deg = deg4 + et * 60000;
    int* rowptr = et == 0 ? r0 : et == 1 ? r1 : et == 2 ? r2 : r3;
    int b = blockIdx.x, tid = threadIdx.x;
    int base = b * 1024 + tid * 4;
    int v0 = 0, v1 = 0, v2 = 0, v3 = 0;
    if (base + 3 < n) {
        int4 t = *(const int4*)(deg + base);
        v0 = t.x; v1 = t.y; v2 = t.z; v3 = t.w;
    } else {
        if (base + 0 < n) v0 = deg[base + 0];
        if (base + 1 < n) v1 = deg[base + 1];
        if (base + 2 < n) v2 = deg[base + 2];
        if (base + 3 < n) v3 = deg[base + 3];
    }
    int s = v0 + v1 + v2 + v3;
    ls[tid] = s;
    __syncthreads();
    #pragma unroll
    for (int off = 1; off < 256; off <<= 1) {
        int t = (tid >= off) ? ls[tid - off] : 0;
        __syncthreads();
        ls[tid] += t;
        __syncthreads();
    }
    int run = ls[tid] - s;
    int o0 = run; run += v0;
    int o1 = run; run += v1;
    int o2 = run; run += v2;
    int o3 = run;
    if (base + 3 < n) {
        *(int4*)(rowptr + base) = make_int4(o0, o1, o2, o3);
    } else {
        if (base + 0 < n) rowptr[base + 0] = o0;
        if (base + 1 < n) rowptr[base + 1] = o1;
        if (base + 2 < n) rowptr[base + 2] = o2;
    }
    if (tid == 255) tsum4[et * 64 + b] = ls[255];
}

__global__ __launch_bounds__(64) void scan_tsum_all(
    int* __restrict__ tsum4,
    int* __restrict__ r0, int* __restrict__ r1, int* __restrict__ r2, int* __restrict__ r3)
{
    const int Ndv[4] = {60000, 60000, 6000, 30000};
    int et = blockIdx.x;
    int n = Ndv[et];
    int nt = (n + 1023) >> 10;
    int* tileSum = tsum4 + et * 64;
    int* rowptr = et == 0 ? r0 : et == 1 ? r1 : et == 2 ? r2 : r3;
    int tid = threadIdx.x;
    int v = (tid < nt) ? tileSum[tid] : 0;
    int orig = v;
    #pragma unroll
    for (int off = 1; off < 64; off <<= 1) {
        int t = __shfl_up(v, off);
        if (tid >= off) v += t;
    }
    if (tid < nt) tileSum[tid] = v - orig;
    if (tid == nt - 1) rowptr[n] = v;
}

__global__ __launch_bounds__(256) void scan_add_all(
    int* __restrict__ r0, int* __restrict__ r1, int* __restrict__ r2, int* __restrict__ r3,
    const int* __restrict__ tsum4)
{
    const int Ndv[4] = {60000, 60000, 6000, 30000};
    int et = blockIdx.y;
    int n = Ndv[et];
    int* rowptr = et == 0 ? r0 : et == 1 ? r1 : et == 2 ? r2 : r3;
    int i = blockIdx.x * 256 + threadIdx.x;
    if (i < n) rowptr[i] += tsum4[et * 64 + (i >> 10)];
}

__global__ __launch_bounds__(256) void fill_all(
    const int* __restrict__ s0, const int* __restrict__ d0,
    const int* __restrict__ s1, const int* __restrict__ d1,
    const int* __restrict__ s2, const int* __restrict__ d2,
    const int* __restrict__ s3, const int* __restrict__ d3,
    const int* __restrict__ r0, const int* __restrict__ r1,
    const int* __restrict__ r2, const int* __restrict__ r3,
    int* __restrict__ deg4,
    int* __restrict__ c0, int* __restrict__ c1, int* __restrict__ c2, int* __restrict__ c3)
{
    const int Ev[4] = {200000, 300000, 200000, 100000};
    int et = blockIdx.y;
    int e = blockIdx.x * 256 + threadIdx.x;
    if (e >= Ev[et]) return;
    const int* src = et == 0 ? s0 : et == 1 ? s1 : et == 2 ? s2 : s3;
    const int* dst = et == 0 ? d0 : et == 1 ? d1 : et == 2 ? d2 : d3;
    const int* rowptr = et == 0 ? r0 : et == 1 ? r1 : et == 2 ? r2 : r3;
    int* csr = et == 0 ? c0 : et == 1 ? c1 : et == 2 ? c2 : c3;
    int d = dst[e];
    int pos = atomicAdd(&deg4[et * 60000 + d], 1);
    csr[rowptr[d] + pos] = src[e];
}

// --------------- fused gather-side attention aggregation (bf16 num) ---------
// SPLIT=2: two threads per (node, head) process half the edge list each and
// merge (m, l, o) via __shfl_xor(., 8); lane layout: node = t>>4, half=(t>>3)&1.
template<bool ACCUM, int SPLIT>
__global__ __launch_bounds__(256) void agg_attn_bf(
    const int* __restrict__ rowptr, const int* __restrict__ csr_src,
    const unsigned short* __restrict__ kamv, int ld_src,
    const unsigned short* __restrict__ qt, int ld_dst,
    const float* __restrict__ prel, unsigned short* __restrict__ num,
    int Ndst, int dstOff)
{
    int t = blockIdx.x * 256 + threadIdx.x;
    if (t >= Ndst * 8 * SPLIT) return;
    int node = (SPLIT == 2) ? (t >> 4) : (t >> 3);
    int h = t & 7;
    int beg = rowptr[node], end = rowptr[node + 1];
    if (SPLIT == 2) {
        int len = end - beg;
        int mid = beg + ((len + 1) >> 1);
        if (((t >> 3) & 1) == 0) end = mid; else beg = mid;
    }
    float m = -INFINITY, l = 0.f;
    float o[16];
    #pragma unroll
    for (int i = 0; i < 16; ++i) o[i] = 0.f;
    if (beg < end) {
        const uint4* qp = (const uint4*)(qt + (size_t)node * ld_dst + h * 16);
        float qf[16];
        up8(qp[0], qf); up8(qp[1], qf + 8);
        float ph = prel[h] * 0.25f;
        int s = csr_src[beg];
        for (int j = beg; j < end; ++j) {
            int sn = (j + 1 < end) ? csr_src[j + 1] : 0;
            const uint4* kp = (const uint4*)(kamv + (size_t)s * ld_src + h * 16);
            uint4 ku0 = kp[0], ku1 = kp[1];
            uint4 vu0 = kp[16], vu1 = kp[17];   // mv at +128 shorts
            float kf[16], vf[16];
            up8(ku0, kf); up8(ku1, kf + 8);
            up8(vu0, vf); up8(vu1, vf + 8);
            float a = 0.f;
            #pragma unroll
            for (int i = 0; i < 16; ++i) a = fmaf(qf[i], kf[i], a);
            a *= ph;
            float mn = fmaxf(m, a);
            float sc = __expf(m - mn);
            float w  = __expf(a - mn);
            l = l * sc + w;
            #pragma unroll
            for (int i = 0; i < 16; ++i) o[i] = o[i] * sc + w * vf[i];
            m = mn; s = sn;
        }
    } else if (ACCUM && SPLIT == 1) {
        return;   // nothing to add
    }
    if (SPLIT == 2) {
        float mp = __shfl_xor(m, 8);
        float lp = __shfl_xor(l, 8);
        float mn = fmaxf(m, mp);
        float sc  = (l  > 0.f) ? __expf(m  - mn) : 0.f;
        float scp = (lp > 0.f) ? __expf(mp - mn) : 0.f;
        l = l * sc + lp * scp;
        #pragma unroll
        for (int i = 0; i < 16; ++i) {
            float op = __shfl_xor(o[i], 8);
            o[i] = o[i] * sc + op * scp;
        }
        if (((t >> 3) & 1) != 0) return;
        if (ACCUM && l == 0.f) return;
    }
    float inv = 1.f / (l + 1e-16f);
    float r[16];
    uint4* np = (uint4*)(num + (size_t)(dstOff + node) * 128 + h * 16);
    if (ACCUM) {
        float cur[16];
        up8(np[0], cur); up8(np[1], cur + 8);
        #pragma unroll
        for (int i = 0; i < 16; ++i) r[i] = cur[i] + inv * o[i];
    } else {
        #pragma unroll
        for (int i = 0; i < 16; ++i) r[i] = inv * o[i];
    }
    np[0] = pk8(r);
    np[1] = pk8(r + 8);
}

extern "C" void kernel_launch(void* const* d_in, const int* in_sizes, int n_in,
                              void* d_out, int out_size, void* d_ws, size_t ws_size,
                              hipStream_t stream)
{
    (void)in_sizes; (void)n_in; (void)out_size; (void)ws_size;

    const float* xin[3] = {(const float*)d_in[0], (const float*)d_in[1], (const float*)d_in[2]};
    const int* esrc[4] = {(const int*)d_in[3], (const int*)d_in[5], (const int*)d_in[7], (const int*)d_in[9]};
    const int* edst[4] = {(const int*)d_in[4], (const int*)d_in[6], (const int*)d_in[8], (const int*)d_in[10]};
    const float* lin_w = (const float*)d_in[11];
    const float* lin_b = (const float*)d_in[12];
    const float* kw = (const float*)d_in[13];
    const float* qw = (const float*)d_in[14];
    const float* vw = (const float*)d_in[15];
    const float* aw = (const float*)d_in[16];
    const float* kb = (const float*)d_in[17];
    const float* qb = (const float*)d_in[18];
    const float* vb = (const float*)d_in[19];
    const float* ab = (const float*)d_in[20];
    const float* a_rel = (const float*)d_in[21];
    const float* m_rel = (const float*)d_in[22];
    const float* p_rel = (const float*)d_in[23];
    const float* skip  = (const float*)d_in[24];
    const float* out_w = (const float*)d_in[25];
    const float* out_b = (const float*)d_in[26];

    // workspace (float-index units; ~39.9M floats = 160 MB)
    float* ws = (float*)d_ws;
    unsigned short* num   = (unsigned short*)ws;                // 12,288,000 h
    unsigned short* xs_bf = (unsigned short*)(ws + 6144000);    // 12,288,000 h
    unsigned short* proj  = (unsigned short*)(ws + 12288000);   // 52,224,000 h
    unsigned short* Wpack = (unsigned short*)(ws + 38400000);   // 360,448 h
    unsigned short* lwt   = (unsigned short*)(ws + 38580224);   // 49,152 h
    unsigned short* awt   = (unsigned short*)(ws + 38604800);   // 98,304 h
    unsigned short* owt   = (unsigned short*)(ws + 38653952);   // 8,192 h
    float*          bpack = ws + 38658048;                      // 2,816 f
    int*            deg4  = (int*)(ws + 38660864);              // 240,000
    int*            tsum4 = (int*)(ws + 38900864);              // 256
    int* rp[4];
    rp[0] = (int*)(ws + 38901120);                              // 60,008
    rp[1] = (int*)(ws + 38961128);
    rp[2] = (int*)(ws + 39021136);                              // 6,008
    rp[3] = (int*)(ws + 39027144);                              // 30,008
    int* cs[4];
    cs[0] = (int*)(ws + 39057152);                              // 200,000
    cs[1] = (int*)(ws + 39257152);                              // 300,000
    cs[2] = (int*)(ws + 39557152);                              // 200,000
    cs[3] = (int*)(ws + 39757152);                              // 100,000

    const int NNv[3] = {30000, 60000, 6000};
    const int OFF[3] = {0, 30000, 90000};
    const int SI[4] = {0, 1, 1, 2};
    const int DI[4] = {1, 1, 2, 0};
    const int NCOLS[3] = {384, 640, 384};
    const int KOFF[4] = {128, 128, 384, 128};
    unsigned short* P[3];
    P[0] = proj;
    P[1] = proj + (size_t)30000 * 384;
    P[2] = proj + (size_t)30000 * 384 + (size_t)60000 * 640;

    dim3 blk(256);

    // ---- CSR build, fused across edge types ----
    hipMemsetAsync(deg4, 0, 960000, stream);
    hist_all<<<dim3(1172, 4), blk, 0, stream>>>(edst[0], edst[1], edst[2], edst[3], deg4);
    scan_tile_all<<<dim3(59, 4), blk, 0, stream>>>(deg4, rp[0], rp[1], rp[2], rp[3], tsum4);
    scan_tsum_all<<<dim3(4), dim3(64), 0, stream>>>(tsum4, rp[0], rp[1], rp[2], rp[3]);
    scan_add_all<<<dim3(235, 4), blk, 0, stream>>>(rp[0], rp[1], rp[2], rp[3], tsum4);
    hipMemsetAsync(deg4, 0, 960000, stream);
    fill_all<<<dim3(1172, 4), blk, 0, stream>>>(
        esrc[0], edst[0], esrc[1], edst[1], esrc[2], edst[2], esrc[3], edst[3],
        rp[0], rp[1], rp[2], rp[3], deg4, cs[0], cs[1], cs[2], cs[3]);

    // ---- weight prep ----
    prep_qpack<<<dim3(128, 3, 2), dim3(128), 0, stream>>>(qw, qb, Wpack, bpack);
    fold_rel_pack<<<dim3(128, 4, 2), dim3(128), 0, stream>>>(
        kw, kb, vw, vb, a_rel, m_rel, Wpack, bpack);
    prep_w9<<<dim3(128, 9), dim3(128), 0, stream>>>(lin_w, aw, lwt, awt);
    prep_owt<<<dim3(128), dim3(64), 0, stream>>>(out_w, owt);

    // ---- input linear + relu -> xs_bf (fused across types) ----
    gemm_node<true, false, false><<<dim3(751), blk, 0, stream>>>(
        xin[0], xin[1], xin[2], lwt, lin_b, nullptr, nullptr, xs_bf);

    for (int l = 0; l < 2; ++l) {
        // packed projection per node type: [q | ka|mv ...]
        const int CPB[3] = {3, 5, 2};
        const int XG[3]  = {2, 2, 3};
        for (int i = 0; i < 3; ++i) {
            dim3 g(XG[i], (NNv[i] + 127) / 128);
            gemm_proj<<<g, blk, 0, stream>>>(
                xs_bf + (size_t)OFF[i] * 128,
                Wpack + (size_t)l * 180224 + (i == 0 ? 0 : i == 1 ? 49152 : 131072),
                bpack + l * 1408 + (i == 0 ? 0 : i == 1 ? 384 : 1024),
                P[i], NCOLS[i], NNv[i], CPB[i], NCOLS[i] / 64);
        }

        for (int et = 0; et < 4; ++et) {
            int si = SI[et], di = DI[et];
            const float* pr = p_rel + (size_t)(l * 4 + et) * 8;
            if (et == 1) {
                dim3 ga((NNv[di] * 8 + 255) / 256);
                agg_attn_bf<true, 1><<<ga, blk, 0, stream>>>(
                    rp[et], cs[et], P[si] + KOFF[et], NCOLS[si], P[di], NCOLS[di],
                    pr, num, NNv[di], OFF[di]);
            } else if (et == 2) {
                dim3 ga((NNv[di] * 16 + 255) / 256);
                agg_attn_bf<false, 2><<<ga, blk, 0, stream>>>(
                    rp[et], cs[et], P[si] + KOFF[et], NCOLS[si], P[di], NCOLS[di],
                    pr, num, NNv[di], OFF[di]);
            } else {
                dim3 ga((NNv[di] * 8 + 255) / 256);
                agg_attn_bf<false, 1><<<ga, blk, 0, stream>>>(
                    rp[et], cs[et], P[si] + KOFF[et], NCOLS[si], P[di], NCOLS[di],
                    pr, num, NNv[di], OFF[di]);
            }
        }

        // node update (fused across types): xs = relu(beta*(gelu(num)@aw+ab)+(1-beta)*xs)
        gemm_node<false, true, true><<<dim3(751), blk, 0, stream>>>(
            num, num + (size_t)30000 * 128, num + (size_t)90000 * 128,
            awt + (size_t)l * 3 * 16384, ab + (size_t)l * 3 * 128,
            xs_bf, skip + l * 3, xs_bf);
    }

    // ---- output projection: single GEMM over all 96000 rows ----
    gemm_out<<<dim3(750), blk, 0, stream>>>(
        xs_bf, owt, out_b, (float*)d_out, 96000);
}

// Round 9
// 672.095 us; speedup vs baseline: 19.1232x; 1.1443x over previous
//
#include <hip/hip_runtime.h>
#include <cstddef>
#include <cstdint>

// ---------------------------------------------------------------------------
// HGT forward for MI355X. C=128, H=8, D=16, OUT=64, L=2
//   NN = {30000, 60000, 6000}, NE = {200000, 300000, 200000, 100000}
//   ETS = {(0,1),(1,1),(1,2),(2,0)}
// Round-9 changes:
//  * gemm_node: 16 rows/wave (1501 blocks, was 751/32rows), B loaded per-tile
//    (VGPR 124 -> ~60), cheap sigmoid-form gelu (1 __expf vs libm tanhf).
//    Was latency-bound: 9% HBM, 23% VALU, 14% occupancy at 67us.
//  * agg merged: ONE kernel per layer covers road(et0+et1 serial, single
//    write, no ACCUM RMW), region(et2, 2-way split) and poi(et3) sections
//    concurrently. 8 launches -> 2.
// ---------------------------------------------------------------------------

typedef __attribute__((ext_vector_type(8))) short short8;   // 8 x bf16
typedef __attribute__((ext_vector_type(4))) float floatx4;

__device__ __forceinline__ float gelu_fast(float x) {
    // 0.5x(1+tanh(c(x+0.044715x^3))) == x*sigmoid(2c x (1+0.044715x^2))
    float u = 1.5957691216057308f * x * (1.0f + 0.044715f * x * x);
    return x / (1.0f + __expf(-u));
}

__device__ __forceinline__ unsigned short f2bf(float f) {   // RNE fp32->bf16
    unsigned u = __float_as_uint(f);
    u += 0x7fffu + ((u >> 16) & 1);
    return (unsigned short)(u >> 16);
}

__device__ __forceinline__ float bf2f(unsigned short h) {
    return __uint_as_float((unsigned)h << 16);
}

__device__ __forceinline__ void up8(uint4 u, float* f) {    // 8 bf16 -> 8 fp32
    f[0] = __uint_as_float(u.x << 16); f[1] = __uint_as_float(u.x & 0xffff0000u);
    f[2] = __uint_as_float(u.y << 16); f[3] = __uint_as_float(u.y & 0xffff0000u);
    f[4] = __uint_as_float(u.z << 16); f[5] = __uint_as_float(u.z & 0xffff0000u);
    f[6] = __uint_as_float(u.w << 16); f[7] = __uint_as_float(u.w & 0xffff0000u);
}

__device__ __forceinline__ uint4 pk8(const float* f) {      // 8 fp32 -> 8 bf16
    uint4 u;
    u.x = (unsigned)f2bf(f[0]) | ((unsigned)f2bf(f[1]) << 16);
    u.y = (unsigned)f2bf(f[2]) | ((unsigned)f2bf(f[3]) << 16);
    u.z = (unsigned)f2bf(f[4]) | ((unsigned)f2bf(f[5]) << 16);
    u.w = (unsigned)f2bf(f[6]) | ((unsigned)f2bf(f[7]) << 16);
    return u;
}

// ---------------- A-resident streaming MFMA GEMM (packed proj) -------------
// Frag layouts (verified m89): A[m=lane&15][k=quad*8+j],
// B[k=quad*8+j][n=lane&15], D[row=quad*4+reg][col=lane&15].
__global__ __launch_bounds__(256) void gemm_proj(
    const unsigned short* __restrict__ Abf,
    const unsigned short* __restrict__ Wt,
    const float* __restrict__ bias,
    unsigned short* __restrict__ outbf, int ldo, int Nrows, int cpb, int nct)
{
    const int wave = threadIdx.x >> 6, lane = threadIdx.x & 63;
    const int quad = lane >> 4, l16 = lane & 15;
    const int rowStart = (blockIdx.y * 4 + wave) * 32;
    if (rowStart >= Nrows) return;
    short8 Afr[2][4];
    #pragma unroll
    for (int rt = 0; rt < 2; ++rt) {
        int m = rowStart + rt * 16 + l16;
        const unsigned short* ap = Abf + (size_t)((m < Nrows) ? m : 0) * 128 + quad * 8;
        #pragma unroll
        for (int kc = 0; kc < 4; ++kc)
            Afr[rt][kc] = *(const short8*)(ap + kc * 32);
    }
    int ct1 = blockIdx.x * cpb + cpb;
    if (ct1 > nct) ct1 = nct;
    for (int ct = blockIdx.x * cpb; ct < ct1; ++ct) {
        int colBase = ct * 64;
        const unsigned short* wp = Wt + (size_t)(colBase + l16) * 128 + quad * 8;
        short8 B[4][4];
        #pragma unroll
        for (int c = 0; c < 4; ++c)
            #pragma unroll
            for (int kc = 0; kc < 4; ++kc)
                B[c][kc] = *(const short8*)(wp + (size_t)c * 2048 + kc * 32);
        floatx4 acc[2][4] = {{{0,0,0,0},{0,0,0,0},{0,0,0,0},{0,0,0,0}},
                             {{0,0,0,0},{0,0,0,0},{0,0,0,0},{0,0,0,0}}};
        #pragma unroll
        for (int kc = 0; kc < 4; ++kc)
            #pragma unroll
            for (int c = 0; c < 4; ++c) {
                acc[0][c] = __builtin_amdgcn_mfma_f32_16x16x32_bf16(Afr[0][kc], B[c][kc], acc[0][c], 0, 0, 0);
                acc[1][c] = __builtin_amdgcn_mfma_f32_16x16x32_bf16(Afr[1][kc], B[c][kc], acc[1][c], 0, 0, 0);
            }
        #pragma unroll
        for (int rt = 0; rt < 2; ++rt) {
            int row0 = rowStart + rt * 16 + quad * 4;
            #pragma unroll
            for (int c = 0; c < 4; ++c) {
                int col = colBase + c * 16 + l16;
                float bv = bias[col];
                #pragma unroll
                for (int r = 0; r < 4; ++r) {
                    int row = row0 + r;
                    if (row < Nrows)
                        outbf[(size_t)row * ldo + col] = f2bf(acc[rt][c][r] + bv);
                }
            }
        }
    }
}

// ---------------- fused-by-type node GEMM (input linear / node update) -----
// 16 rows/wave, 64/block; stripes: poi 469 / road 938 / region 94 (1501 total)
template<bool AF32, bool GIN, bool SKIP>
__global__ __launch_bounds__(256) void gemm_node(
    const void* __restrict__ a0v, const void* __restrict__ a1v, const void* __restrict__ a2v,
    const unsigned short* __restrict__ WtB, const float* __restrict__ biasB,
    const unsigned short* __restrict__ xoldB, const float* __restrict__ skipB,
    unsigned short* __restrict__ outB)
{
    const int TN[3]   = {30000, 60000, 6000};
    const int TOFF[3] = {0, 30000, 90000};
    int by = blockIdx.x;
    int t  = (by < 469) ? 0 : (by < 1407) ? 1 : 2;
    int lb = by - ((t == 0) ? 0 : (t == 1) ? 469 : 1407);
    int Nrows = TN[t];
    const void* av = (t == 0) ? a0v : (t == 1) ? a1v : a2v;
    const unsigned short* Wt = WtB + (size_t)t * 16384;
    const float* bias = biasB + t * 128;
    const unsigned short* xold = xoldB + (size_t)TOFF[t] * 128;
    unsigned short* out = outB + (size_t)TOFF[t] * 128;
    const int wave = threadIdx.x >> 6, lane = threadIdx.x & 63;
    const int quad = lane >> 4, l16 = lane & 15;
    const int rowStart = (lb * 4 + wave) * 16;
    if (rowStart >= Nrows) return;
    int m = rowStart + l16;
    size_t base = (size_t)((m < Nrows) ? m : 0) * 128 + quad * 8;
    short8 Afr[4];
    #pragma unroll
    for (int kc = 0; kc < 4; ++kc) {
        if (AF32) {
            const float* ap = (const float*)av + base;
            float4 f0 = *(const float4*)(ap + kc * 32);
            float4 f1 = *(const float4*)(ap + kc * 32 + 4);
            float af[8] = {f0.x, f0.y, f0.z, f0.w, f1.x, f1.y, f1.z, f1.w};
            short8 a;
            #pragma unroll
            for (int i = 0; i < 8; ++i) a[i] = (short)f2bf(af[i]);
            Afr[kc] = a;
        } else if (GIN) {
            const unsigned short* ap = (const unsigned short*)av + base;
            short8 a8 = *(const short8*)(ap + kc * 32);
            short8 a;
            #pragma unroll
            for (int i = 0; i < 8; ++i)
                a[i] = (short)f2bf(gelu_fast(bf2f((unsigned short)a8[i])));
            Afr[kc] = a;
        } else {
            const unsigned short* ap = (const unsigned short*)av + base;
            Afr[kc] = *(const short8*)(ap + kc * 32);
        }
    }
    float beta = 0.f, omb = 0.f;
    if (SKIP) { beta = 1.0f / (1.0f + __expf(-skipB[t])); omb = 1.0f - beta; }
    int row0 = rowStart + quad * 4;
    #pragma unroll
    for (int ct = 0; ct < 2; ++ct) {
        int colBase = ct * 64;
        const unsigned short* wp = Wt + (size_t)(colBase + l16) * 128 + quad * 8;
        #pragma unroll
        for (int c = 0; c < 4; ++c) {
            floatx4 acc = {0, 0, 0, 0};
            #pragma unroll
            for (int kc = 0; kc < 4; ++kc) {
                short8 B = *(const short8*)(wp + (size_t)c * 2048 + kc * 32);
                acc = __builtin_amdgcn_mfma_f32_16x16x32_bf16(Afr[kc], B, acc, 0, 0, 0);
            }
            int col = colBase + c * 16 + l16;
            float bv = bias[col];
            #pragma unroll
            for (int r = 0; r < 4; ++r) {
                int row = row0 + r;
                if (row < Nrows) {
                    float o = acc[r] + bv;
                    if (SKIP) o = beta * o + omb * bf2f(xold[(size_t)row * 128 + col]);
                    o = fmaxf(o, 0.f);
                    out[(size_t)row * 128 + col] = f2bf(o);
                }
            }
        }
    }
}

// ---------------- output projection: one GEMM over all 96000 rows ----------
__global__ __launch_bounds__(256) void gemm_out(
    const unsigned short* __restrict__ Abf,
    const unsigned short* __restrict__ Wt,     // [64][128] bf16^T
    const float* __restrict__ bias,
    float* __restrict__ out, int Nrows)
{
    const int wave = threadIdx.x >> 6, lane = threadIdx.x & 63;
    const int quad = lane >> 4, l16 = lane & 15;
    const int rowBase = (blockIdx.x * 4 + wave) * 16;
    if (rowBase >= Nrows) return;
    const unsigned short* wp = Wt + (size_t)l16 * 128 + quad * 8;
    int m = rowBase + l16;
    const unsigned short* ap = Abf + (size_t)((m < Nrows) ? m : 0) * 128 + quad * 8;
    short8 Afr[4];
    #pragma unroll
    for (int kc = 0; kc < 4; ++kc) Afr[kc] = *(const short8*)(ap + kc * 32);
    int row0 = rowBase + quad * 4;
    #pragma unroll
    for (int c = 0; c < 4; ++c) {
        floatx4 acc = {0, 0, 0, 0};
        #pragma unroll
        for (int kc = 0; kc < 4; ++kc) {
            short8 B = *(const short8*)(wp + (size_t)c * 2048 + kc * 32);
            acc = __builtin_amdgcn_mfma_f32_16x16x32_bf16(Afr[kc], B, acc, 0, 0, 0);
        }
        int col = c * 16 + l16;
        float bv = bias[col];
        #pragma unroll
        for (int r = 0; r < 4; ++r) {
            int row = row0 + r;
            if (row < Nrows)
                out[(size_t)row * 64 + col] = acc[r] + bv;
        }
    }
}

// ------------------------- weight prep -------------------------------------
__global__ __launch_bounds__(128) void prep_qpack(
    const float* __restrict__ qw, const float* __restrict__ qb,
    unsigned short* __restrict__ Wpack, float* __restrict__ bpack)
{
    const int pre[3] = {0, 49152, 131072};
    const int preB[3] = {0, 384, 1024};
    int n = threadIdx.x, k = blockIdx.x, t = blockIdx.y, l = blockIdx.z;
    unsigned short* Wp = Wpack + (size_t)l * 180224 + pre[t];
    Wp[(size_t)n * 128 + k] = f2bf(qw[(size_t)(l * 3 + t) * 16384 + (size_t)k * 128 + n]);
    if (k == 0) bpack[l * 1408 + preB[t] + n] = qb[(l * 3 + t) * 128 + n];
}

__global__ __launch_bounds__(128) void fold_rel_pack(
    const float* __restrict__ kw, const float* __restrict__ kb,
    const float* __restrict__ vw, const float* __restrict__ vb,
    const float* __restrict__ a_rel, const float* __restrict__ m_rel,
    unsigned short* __restrict__ Wpack, float* __restrict__ bpack)
{
    const int SIv[4] = {0, 1, 1, 2};
    const int SLOT[4] = {0, 0, 1, 0};
    const int pre[3] = {0, 49152, 131072};
    const int preB[3] = {0, 384, 1024};
    int hf = threadIdx.x, h = hf >> 4, f = hf & 15;
    int c = blockIdx.x, et = blockIdx.y, l = blockIdx.z;
    int si = SIv[et];
    const float* kwp  = kw + (size_t)(l * 3 + si) * 16384;
    const float* vwp  = vw + (size_t)(l * 3 + si) * 16384;
    const float* kbp  = kb + (size_t)(l * 3 + si) * 128;
    const float* vbp  = vb + (size_t)(l * 3 + si) * 128;
    const float* arel = a_rel + (size_t)(l * 4 + et) * 2048;
    const float* mrel = m_rel + (size_t)(l * 4 + et) * 2048;
    float sk = 0.f, sv = 0.f;
    #pragma unroll
    for (int d = 0; d < 16; ++d) {
        float ar = arel[(h * 16 + d) * 16 + f];
        float mr = mrel[(h * 16 + d) * 16 + f];
        sk = fmaf(kwp[c * 128 + h * 16 + d], ar, sk);
        sv = fmaf(vwp[c * 128 + h * 16 + d], mr, sv);
    }
    int rowoff = 128 + 256 * SLOT[et];
    unsigned short* Wp = Wpack + (size_t)l * 180224 + pre[si];
    Wp[(size_t)(rowoff + hf) * 128 + c]       = f2bf(sk);
    Wp[(size_t)(rowoff + 128 + hf) * 128 + c] = f2bf(sv);
    if (c == 0) {
        float bk = 0.f, bvv = 0.f;
        #pragma unroll
        for (int d = 0; d < 16; ++d) {
            bk  = fmaf(kbp[h * 16 + d], arel[(h * 16 + d) * 16 + f], bk);
            bvv = fmaf(vbp[h * 16 + d], mrel[(h * 16 + d) * 16 + f], bvv);
        }
        float* bp = bpack + l * 1408 + preB[si];
        bp[rowoff + hf]       = bk;
        bp[rowoff + 128 + hf] = bvv;
    }
}

__global__ __launch_bounds__(128) void prep_w9(
    const float* __restrict__ lin_w, const float* __restrict__ aw,
    unsigned short* __restrict__ lwt, unsigned short* __restrict__ awt)
{
    int n = threadIdx.x, k = blockIdx.x, mi = blockIdx.y;
    const float* w; unsigned short* wt; int m;
    if (mi < 3) { w = lin_w; wt = lwt; m = mi; }
    else        { w = aw;    wt = awt; m = mi - 3; }
    wt[(size_t)m * 16384 + (size_t)n * 128 + k] =
        f2bf(w[(size_t)m * 16384 + (size_t)k * 128 + n]);
}

__global__ __launch_bounds__(64) void prep_owt(
    const float* __restrict__ ow, unsigned short* __restrict__ owt)
{
    int n = threadIdx.x, k = blockIdx.x;
    owt[(size_t)n * 128 + k] = f2bf(ow[(size_t)k * 64 + n]);
}

// ------------------------- CSR build (fused across edge types) --------------
__global__ __launch_bounds__(256) void hist_all(
    const int* __restrict__ d0, const int* __restrict__ d1,
    const int* __restrict__ d2, const int* __restrict__ d3,
    int* __restrict__ deg4)
{
    const int Ev[4] = {200000, 300000, 200000, 100000};
    int et = blockIdx.y;
    int e = blockIdx.x * 256 + threadIdx.x;
    if (e >= Ev[et]) return;
    const int* d = et == 0 ? d0 : et == 1 ? d1 : et == 2 ? d2 : d3;
    atomicAdd(&deg4[et * 60000 + d[e]], 1);
}

__global__ __launch_bounds__(256) void scan_tile_all(
    const int* __restrict__ deg4,
    int* __restrict__ r0, int* __restrict__ r1, int* __restrict__ r2, int* __restrict__ r3,
    int* __restrict__ tsum4)
{
    const int Ndv[4] = {60000, 60000, 6000, 30000};
    __shared__ int ls[256];
    int et = blockIdx.y;
    int n = Ndv[et];
    const int* deg = deg4 + et * 60000;
    int* rowptr = et == 0 ? r0 : et == 1 ? r1 : et == 2 ? r2 : r3;
    int b = blockIdx.x, tid = threadIdx.x;
    int base = b * 1024 + tid * 4;
    int v0 = 0, v1 = 0, v2 = 0, v3 = 0;
    if (base + 3 < n) {
        int4 t = *(const int4*)(deg + base);
        v0 = t.x; v1 = t.y; v2 = t.z; v3 = t.w;
    } else {
        if (base + 0 < n) v0 = deg[base + 0];
        if (base + 1 < n) v1 = deg[base + 1];
        if (base + 2 < n) v2 = deg[base + 2];
        if (base + 3 < n) v3 = deg[base + 3];
    }
    int s = v0 + v1 + v2 + v3;
    ls[tid] = s;
    __syncthreads();
    #pragma unroll
    for (int off = 1; off < 256; off <<= 1) {
        int t = (tid >= off) ? ls[tid - off] : 0;
        __syncthreads();
        ls[tid] += t;
        __syncthreads();
    }
    int run = ls[tid] - s;
    int o0 = run; run += v0;
    int o1 = run; run += v1;
    int o2 = run; run += v2;
    int o3 = run;
    if (base + 3 < n) {
        *(int4*)(rowptr + base) = make_int4(o0, o1, o2, o3);
    } else {
        if (base + 0 < n) rowptr[base + 0] = o0;
        if (base + 1 < n) rowptr[base + 1] = o1;
        if (base + 2 < n) rowptr[base + 2] = o2;
    }
    if (tid == 255) tsum4[et * 64 + b] = ls[255];
}

__global__ __launch_bounds__(64) void scan_tsum_all(
    int* __restrict__ tsum4,
    int* __restrict__ r0, int* __restrict__ r1, int* __restrict__ r2, int* __restrict__ r3)
{
    const int Ndv[4] = {60000, 60000, 6000, 30000};
    int et = blockIdx.x;
    int n = Ndv[et];
    int nt = (n + 1023) >> 10;
    int* tileSum = tsum4 + et * 64;
    int* rowptr = et == 0 ? r0 : et == 1 ? r1 : et == 2 ? r2 : r3;
    int tid = threadIdx.x;
    int v = (tid < nt) ? tileSum[tid] : 0;
    int orig = v;
    #pragma unroll
    for (int off = 1; off < 64; off <<= 1) {
        int t = __shfl_up(v, off);
        if (tid >= off) v += t;
    }
    if (tid < nt) tileSum[tid] = v - orig;
    if (tid == nt - 1) rowptr[n] = v;
}

__global__ __launch_bounds__(256) void scan_add_all(
    int* __restrict__ r0, int* __restrict__ r1, int* __restrict__ r2, int* __restrict__ r3,
    const int* __restrict__ tsum4)
{
    const int Ndv[4] = {60000, 60000, 6000, 30000};
    int et = blockIdx.y;
    int n = Ndv[et];
    int* rowptr = et == 0 ? r0 : et == 1 ? r1 : et == 2 ? r2 : r3;
    int i = blockIdx.x * 256 + threadIdx.x;
    if (i < n) rowptr[i] += tsum4[et * 64 + (i >> 10)];
}

__global__ __launch_bounds__(256) void fill_all(
    const int* __restrict__ s0, const int* __restrict__ d0,
    const int* __restrict__ s1, const int* __restrict__ d1,
    const int* __restrict__ s2, const int* __restrict__ d2,
    const int* __restrict__ s3, const int* __restrict__ d3,
    const int* __restrict__ r0, const int* __restrict__ r1,
    const int* __restrict__ r2, const int* __restrict__ r3,
    int* __restrict__ deg4,
    int* __restrict__ c0, int* __restrict__ c1, int* __restrict__ c2, int* __restrict__ c3)
{
    const int Ev[4] = {200000, 300000, 200000, 100000};
    int et = blockIdx.y;
    int e = blockIdx.x * 256 + threadIdx.x;
    if (e >= Ev[et]) return;
    const int* src = et == 0 ? s0 : et == 1 ? s1 : et == 2 ? s2 : s3;
    const int* dst = et == 0 ? d0 : et == 1 ? d1 : et == 2 ? d2 : d3;
    const int* rowptr = et == 0 ? r0 : et == 1 ? r1 : et == 2 ? r2 : r3;
    int* csr = et == 0 ? c0 : et == 1 ? c1 : et == 2 ? c2 : c3;
    int d = dst[e];
    int pos = atomicAdd(&deg4[et * 60000 + d], 1);
    csr[rowptr[d] + pos] = src[e];
}

// --------------- merged gather-side attention (all 4 edge types) ------------
__device__ __forceinline__ void attn_run(
    const int* __restrict__ csr, int beg, int end,
    const unsigned short* __restrict__ kbase, int ld,
    const float* qf, float ph, float& m, float& l, float* o)
{
    if (beg >= end) return;
    int s = csr[beg];
    for (int j = beg; j < end; ++j) {
        int sn = (j + 1 < end) ? csr[j + 1] : 0;
        const uint4* kp = (const uint4*)(kbase + (size_t)s * ld);
        uint4 ku0 = kp[0], ku1 = kp[1];
        uint4 vu0 = kp[16], vu1 = kp[17];   // mv at +128 shorts
        float kf[16], vf[16];
        up8(ku0, kf); up8(ku1, kf + 8);
        up8(vu0, vf); up8(vu1, vf + 8);
        float a = 0.f;
        #pragma unroll
        for (int i = 0; i < 16; ++i) a = fmaf(qf[i], kf[i], a);
        a *= ph;
        float mn = fmaxf(m, a);
        float sc = __expf(m - mn);
        float w  = __expf(a - mn);
        l = l * sc + w;
        #pragma unroll
        for (int i = 0; i < 16; ++i) o[i] = o[i] * sc + w * vf[i];
        m = mn; s = sn;
    }
}

// grid: [0,1875) road(et0+et1) / [1875,2250) region(et2, 2-way split) /
//       [2250,3188) poi(et3)
__global__ __launch_bounds__(256) void agg_all(
    const int* __restrict__ rp0, const int* __restrict__ cs0,
    const int* __restrict__ rp1, const int* __restrict__ cs1,
    const int* __restrict__ rp2, const int* __restrict__ cs2,
    const int* __restrict__ rp3, const int* __restrict__ cs3,
    const unsigned short* __restrict__ P0, const unsigned short* __restrict__ P1,
    const unsigned short* __restrict__ P2,
    const float* __restrict__ prl,      // p_rel + l*32
    unsigned short* __restrict__ num)
{
    int gb = blockIdx.x, tid = threadIdx.x;
    float qf[16], o[16], r[16];
    if (gb < 1875) {
        // ---- road: et0 (poi src) + et1 (road src), separate softmaxes ----
        int t = gb * 256 + tid;            // < 480000 exactly
        int node = t >> 3, h = t & 7;
        const uint4* qp = (const uint4*)(P1 + (size_t)node * 640 + h * 16);
        up8(qp[0], qf); up8(qp[1], qf + 8);
        float m0 = -INFINITY, l0 = 0.f;
        #pragma unroll
        for (int i = 0; i < 16; ++i) o[i] = 0.f;
        attn_run(cs0, rp0[node], rp0[node + 1], P0 + 128 + h * 16, 384,
                 qf, prl[h] * 0.25f, m0, l0, o);
        float i0 = 1.f / (l0 + 1e-16f);
        #pragma unroll
        for (int i = 0; i < 16; ++i) { r[i] = i0 * o[i]; o[i] = 0.f; }
        float m1 = -INFINITY, l1 = 0.f;
        attn_run(cs1, rp1[node], rp1[node + 1], P1 + 128 + h * 16, 640,
                 qf, prl[8 + h] * 0.25f, m1, l1, o);
        float i1 = 1.f / (l1 + 1e-16f);
        #pragma unroll
        for (int i = 0; i < 16; ++i) r[i] += i1 * o[i];
        uint4* np = (uint4*)(num + (size_t)(30000 + node) * 128 + h * 16);
        np[0] = pk8(r); np[1] = pk8(r + 8);
    } else if (gb < 2250) {
        // ---- region: et2 (road src), 2-way edge split + shuffle merge ----
        int t = (gb - 1875) * 256 + tid;   // < 96000 exactly
        int node = t >> 4, h = t & 7, half = (t >> 3) & 1;
        int beg = rp2[node], end = rp2[node + 1];
        int mid = beg + ((end - beg + 1) >> 1);
        if (half == 0) end = mid; else beg = mid;
        const uint4* qp = (const uint4*)(P2 + (size_t)node * 384 + h * 16);
        up8(qp[0], qf); up8(qp[1], qf + 8);
        float m = -INFINITY, l = 0.f;
        #pragma unroll
        for (int i = 0; i < 16; ++i) o[i] = 0.f;
        attn_run(cs2, beg, end, P1 + 384 + h * 16, 640,
                 qf, prl[16 + h] * 0.25f, m, l, o);
        float mp = __shfl_xor(m, 8);
        float lp = __shfl_xor(l, 8);
        float mn = fmaxf(m, mp);
        float sc  = (l  > 0.f) ? __expf(m  - mn) : 0.f;
        float scp = (lp > 0.f) ? __expf(mp - mn) : 0.f;
        l = l * sc + lp * scp;
        #pragma unroll
        for (int i = 0; i < 16; ++i) {
            float op = __shfl_xor(o[i], 8);
            o[i] = o[i] * sc + op * scp;
        }
        if (half) return;
        float inv = 1.f / (l + 1e-16f);
        #pragma unroll
        for (int i = 0; i < 16; ++i) r[i] = inv * o[i];
        uint4* np = (uint4*)(num + (size_t)(90000 + node) * 128 + h * 16);
        np[0] = pk8(r); np[1] = pk8(r + 8);
    } else {
        // ---- poi: et3 (region src) ----
        int t = (gb - 2250) * 256 + tid;
        if (t >= 240000) return;
        int node = t >> 3, h = t & 7;
        const uint4* qp = (const uint4*)(P0 + (size_t)node * 384 + h * 16);
        up8(qp[0], qf); up8(qp[1], qf + 8);
        float m = -INFINITY, l = 0.f;
        #pragma unroll
        for (int i = 0; i < 16; ++i) o[i] = 0.f;
        attn_run(cs3, rp3[node], rp3[node + 1], P2 + 128 + h * 16, 384,
                 qf, prl[24 + h] * 0.25f, m, l, o);
        float inv = 1.f / (l + 1e-16f);
        #pragma unroll
        for (int i = 0; i < 16; ++i) r[i] = inv * o[i];
        uint4* np = (uint4*)(num + (size_t)node * 128 + h * 16);
        np[0] = pk8(r); np[1] = pk8(r + 8);
    }
}

extern "C" void kernel_launch(void* const* d_in, const int* in_sizes, int n_in,
                              void* d_out, int out_size, void* d_ws, size_t ws_size,
                              hipStream_t stream)
{
    (void)in_sizes; (void)n_in; (void)out_size; (void)ws_size;

    const float* xin[3] = {(const float*)d_in[0], (const float*)d_in[1], (const float*)d_in[2]};
    const int* esrc[4] = {(const int*)d_in[3], (const int*)d_in[5], (const int*)d_in[7], (const int*)d_in[9]};
    const int* edst[4] = {(const int*)d_in[4], (const int*)d_in[6], (const int*)d_in[8], (const int*)d_in[10]};
    const float* lin_w = (const float*)d_in[11];
    const float* lin_b = (const float*)d_in[12];
    const float* kw = (const float*)d_in[13];
    const float* qw = (const float*)d_in[14];
    const float* vw = (const float*)d_in[15];
    const float* aw = (const float*)d_in[16];
    const float* kb = (const float*)d_in[17];
    const float* qb = (const float*)d_in[18];
    const float* vb = (const float*)d_in[19];
    const float* ab = (const float*)d_in[20];
    const float* a_rel = (const float*)d_in[21];
    const float* m_rel = (const float*)d_in[22];
    const float* p_rel = (const float*)d_in[23];
    const float* skip  = (const float*)d_in[24];
    const float* out_w = (const float*)d_in[25];
    const float* out_b = (const float*)d_in[26];

    // workspace (float-index units; ~39.9M floats = 160 MB)
    float* ws = (float*)d_ws;
    unsigned short* num   = (unsigned short*)ws;                // 12,288,000 h
    unsigned short* xs_bf = (unsigned short*)(ws + 6144000);    // 12,288,000 h
    unsigned short* proj  = (unsigned short*)(ws + 12288000);   // 52,224,000 h
    unsigned short* Wpack = (unsigned short*)(ws + 38400000);   // 360,448 h
    unsigned short* lwt   = (unsigned short*)(ws + 38580224);   // 49,152 h
    unsigned short* awt   = (unsigned short*)(ws + 38604800);   // 98,304 h
    unsigned short* owt   = (unsigned short*)(ws + 38653952);   // 8,192 h
    float*          bpack = ws + 38658048;                      // 2,816 f
    int*            deg4  = (int*)(ws + 38660864);              // 240,000
    int*            tsum4 = (int*)(ws + 38900864);              // 256
    int* rp[4];
    rp[0] = (int*)(ws + 38901120);                              // 60,008
    rp[1] = (int*)(ws + 38961128);
    rp[2] = (int*)(ws + 39021136);                              // 6,008
    rp[3] = (int*)(ws + 39027144);                              // 30,008
    int* cs[4];
    cs[0] = (int*)(ws + 39057152);                              // 200,000
    cs[1] = (int*)(ws + 39257152);                              // 300,000
    cs[2] = (int*)(ws + 39557152);                              // 200,000
    cs[3] = (int*)(ws + 39757152);                              // 100,000

    const int NNv[3] = {30000, 60000, 6000};
    const int OFF[3] = {0, 30000, 90000};
    const int NCOLS[3] = {384, 640, 384};
    unsigned short* P[3];
    P[0] = proj;
    P[1] = proj + (size_t)30000 * 384;
    P[2] = proj + (size_t)30000 * 384 + (size_t)60000 * 640;

    dim3 blk(256);

    // ---- CSR build, fused across edge types ----
    hipMemsetAsync(deg4, 0, 960000, stream);
    hist_all<<<dim3(1172, 4), blk, 0, stream>>>(edst[0], edst[1], edst[2], edst[3], deg4);
    scan_tile_all<<<dim3(59, 4), blk, 0, stream>>>(deg4, rp[0], rp[1], rp[2], rp[3], tsum4);
    scan_tsum_all<<<dim3(4), dim3(64), 0, stream>>>(tsum4, rp[0], rp[1], rp[2], rp[3]);
    scan_add_all<<<dim3(235, 4), blk, 0, stream>>>(rp[0], rp[1], rp[2], rp[3], tsum4);
    hipMemsetAsync(deg4, 0, 960000, stream);
    fill_all<<<dim3(1172, 4), blk, 0, stream>>>(
        esrc[0], edst[0], esrc[1], edst[1], esrc[2], edst[2], esrc[3], edst[3],
        rp[0], rp[1], rp[2], rp[3], deg4, cs[0], cs[1], cs[2], cs[3]);

    // ---- weight prep ----
    prep_qpack<<<dim3(128, 3, 2), dim3(128), 0, stream>>>(qw, qb, Wpack, bpack);
    fold_rel_pack<<<dim3(128, 4, 2), dim3(128), 0, stream>>>(
        kw, kb, vw, vb, a_rel, m_rel, Wpack, bpack);
    prep_w9<<<dim3(128, 9), dim3(128), 0, stream>>>(lin_w, aw, lwt, awt);
    prep_owt<<<dim3(128), dim3(64), 0, stream>>>(out_w, owt);

    // ---- input linear + relu -> xs_bf (fused across types) ----
    gemm_node<true, false, false><<<dim3(1501), blk, 0, stream>>>(
        xin[0], xin[1], xin[2], lwt, lin_b, nullptr, nullptr, xs_bf);

    for (int l = 0; l < 2; ++l) {
        // packed projection per node type: [q | ka|mv ...]
        const int CPB[3] = {3, 5, 2};
        const int XG[3]  = {2, 2, 3};
        for (int i = 0; i < 3; ++i) {
            dim3 g(XG[i], (NNv[i] + 127) / 128);
            gemm_proj<<<g, blk, 0, stream>>>(
                xs_bf + (size_t)OFF[i] * 128,
                Wpack + (size_t)l * 180224 + (i == 0 ? 0 : i == 1 ? 49152 : 131072),
                bpack + l * 1408 + (i == 0 ? 0 : i == 1 ? 384 : 1024),
                P[i], NCOLS[i], NNv[i], CPB[i], NCOLS[i] / 64);
        }

        // merged aggregation: all 4 edge types in one launch
        agg_all<<<dim3(3188), blk, 0, stream>>>(
            rp[0], cs[0], rp[1], cs[1], rp[2], cs[2], rp[3], cs[3],
            P[0], P[1], P[2], p_rel + (size_t)l * 32, num);

        // node update (fused across types)
        gemm_node<false, true, true><<<dim3(1501), blk, 0, stream>>>(
            num, num + (size_t)30000 * 128, num + (size_t)90000 * 128,
            awt + (size_t)l * 3 * 16384, ab + (size_t)l * 3 * 128,
            xs_bf, skip + l * 3, xs_bf);
    }

    // ---- output projection: single GEMM over all 96000 rows ----
    gemm_out<<<dim3(1500), blk, 0, stream>>>(
        xs_bf, owt, out_b, (float*)d_out, 96000);
}